// Round 1
// baseline (281.433 us; speedup 1.0000x reference)
//
#include <hip/hip_runtime.h>
#include <hip/hip_bf16.h>

#define N_NODES 100000
#define N_EDGES 1000000
#define DIM 64
#define NORM_INV 0.01f
#define LN_EPS 1e-5f
#define N_TILES 6250          // N_NODES/16
#define PROJ_BLOCKS 1563      // ceil(6250/4)
#define N_BUCKETS 782         // ceil(100000/128), 128 rows per bucket
#define HISTB 489             // ceil(1e6/2048)
#define L2E 1.4426950408889634f
#define LN2 0.6931471805599453f

typedef __attribute__((ext_vector_type(8))) short short8;
typedef __attribute__((ext_vector_type(4))) float f32x4;

__device__ __forceinline__ unsigned short f2bf(float f) {
    union { float f; unsigned u; } x; x.f = f;
    unsigned r = x.u + 0x7FFFu + ((x.u >> 16) & 1u);
    return (unsigned short)(r >> 16);
}
__device__ __forceinline__ float bf2f(unsigned short s) {
    union { unsigned u; float f; } x; x.u = ((unsigned)s) << 16; return x.f;
}

// ---------------------------------------------------------------------------
// P0: precompute MFMA weight fragments + per-feature epilogue table.
// tab[f] = {w2[f]*ln2, w1c[f]*log2e, b1[f]*log2e, 0}
// ---------------------------------------------------------------------------
__global__ __launch_bounds__(256) void prep_frags(
    const float* __restrict__ W, const float* __restrict__ att_W1,
    const float* __restrict__ att_b1, const float* __restrict__ att_W2,
    short8* __restrict__ whi, short8* __restrict__ wlo,
    short8* __restrict__ wa, short8* __restrict__ wb,
    float4* __restrict__ tab) {
    const int l = threadIdx.x & 63;
    const int nt = threadIdx.x >> 6;
    const int c = l & 15, q = l >> 4;
    const int n = nt * 16 + c;
#pragma unroll
    for (int ks = 0; ks < 2; ++ks) {
        const int k0 = ks * 32 + q * 8;
        short8 hi8, lo8, a8, b8;
#pragma unroll
        for (int jj = 0; jj < 8; ++jj) {
            float w = W[n * 64 + k0 + jj];
            unsigned short hh = f2bf(w);
            hi8[jj] = (short)hh;
            lo8[jj] = (short)f2bf(w - bf2f(hh));
            a8[jj] = (short)f2bf(att_W1[n * 129 + k0 + jj]);
            b8[jj] = (short)f2bf(att_W1[n * 129 + 64 + k0 + jj]);
        }
        const int idx = (nt * 2 + ks) * 64 + l;
        whi[idx] = hi8; wlo[idx] = lo8; wa[idx] = a8; wb[idx] = b8;
    }
    if (threadIdx.x < 64) {
        const int f = threadIdx.x;
        tab[f] = make_float4(att_W2[f] * LN2, att_W1[f * 129 + 128] * L2E,
                             att_b1[f] * L2E, 0.f);
    }
}

// ---------------------------------------------------------------------------
// P1 fat kernel. blocks [0,PROJ_BLOCKS): MFMA projection, 1 tile/wave.
//   x = h@W^T + b (hi/lo bf16 split), u = x@W1a^T * log2e, v = x@W1b^T * log2e
// blocks [PROJ_BLOCKS, +HISTB): row histogram (global atomics, L2-resident)
//   + bucket histogram (LDS-staged) for the two-level scan.
// ---------------------------------------------------------------------------
__global__ __launch_bounds__(256) void proj_hist(
    const float* __restrict__ h, const float* __restrict__ bl,
    const short8* __restrict__ whi, const short8* __restrict__ wlo,
    const short8* __restrict__ wa, const short8* __restrict__ wb,
    const int* __restrict__ edges, int* __restrict__ rowCnt,
    int* __restrict__ bucketCnt,
    unsigned short* __restrict__ xv, unsigned short* __restrict__ u_bf) {
    if (blockIdx.x >= PROJ_BLOCKS) {
        __shared__ int lh[N_BUCKETS];
        const int tid = threadIdx.x;
        for (int i = tid; i < N_BUCKETS; i += 256) lh[i] = 0;
        __syncthreads();
        const int e0 = (blockIdx.x - PROJ_BLOCKS) * 2048;
#pragma unroll
        for (int i = 0; i < 8; ++i) {
            const int e = e0 + tid * 8 + i;
            if (e < N_EDGES) {
                const int r = edges[e];
                atomicAdd(&lh[r >> 7], 1);
                atomicAdd(&rowCnt[r], 1);
            }
        }
        __syncthreads();
        for (int b = tid; b < N_BUCKETS; b += 256)
            if (lh[b]) atomicAdd(&bucketCnt[b], lh[b]);
        return;
    }
    __shared__ __align__(16) unsigned short lds[4][16 * 72];
    const int lane = threadIdx.x & 63;
    const int wv = threadIdx.x >> 6;
    const int c = lane & 15, q = lane >> 4;
    const int tile = blockIdx.x * 4 + wv;
    if (tile >= N_TILES) return;
    const int n0 = tile * 16;

    short8 Whi[4][2], Wlo[4][2], Wa[4][2], Wb[4][2];
    float bias[4];
#pragma unroll
    for (int nt = 0; nt < 4; ++nt) {
        bias[nt] = bl[nt * 16 + c];
#pragma unroll
        for (int ks = 0; ks < 2; ++ks) {
            const int idx = (nt * 2 + ks) * 64 + lane;
            Whi[nt][ks] = whi[idx]; Wlo[nt][ks] = wlo[idx];
            Wa[nt][ks] = wa[idx];   Wb[nt][ks] = wb[idx];
        }
    }

    short8 Ahi[2], Alo[2];
#pragma unroll
    for (int ks = 0; ks < 2; ++ks) {
        const float* hp = h + (size_t)(n0 + c) * 64 + ks * 32 + q * 8;
        f32x4 p0 = *(const f32x4*)hp;
        f32x4 p1 = *(const f32x4*)(hp + 4);
        short8 hi8, lo8;
#pragma unroll
        for (int jj = 0; jj < 4; ++jj) {
            unsigned short hh = f2bf(p0[jj]);
            hi8[jj] = (short)hh; lo8[jj] = (short)f2bf(p0[jj] - bf2f(hh));
            unsigned short h2 = f2bf(p1[jj]);
            hi8[4 + jj] = (short)h2; lo8[4 + jj] = (short)f2bf(p1[jj] - bf2f(h2));
        }
        Ahi[ks] = hi8; Alo[ks] = lo8;
    }

    f32x4 xacc[4] = {{0,0,0,0},{0,0,0,0},{0,0,0,0},{0,0,0,0}};
#pragma unroll
    for (int ks = 0; ks < 2; ++ks)
#pragma unroll
        for (int nt = 0; nt < 4; ++nt) {
            xacc[nt] = __builtin_amdgcn_mfma_f32_16x16x32_bf16(Ahi[ks], Whi[nt][ks], xacc[nt], 0, 0, 0);
            xacc[nt] = __builtin_amdgcn_mfma_f32_16x16x32_bf16(Ahi[ks], Wlo[nt][ks], xacc[nt], 0, 0, 0);
            xacc[nt] = __builtin_amdgcn_mfma_f32_16x16x32_bf16(Alo[ks], Whi[nt][ks], xacc[nt], 0, 0, 0);
        }

    unsigned short* lw = lds[wv];
#pragma unroll
    for (int r = 0; r < 4; ++r) {
        const int node = n0 + q * 4 + r;
        unsigned short xb[4];
#pragma unroll
        for (int nt = 0; nt < 4; ++nt) {
            unsigned short v16 = f2bf(xacc[nt][r] + bias[nt]);
            xb[nt] = v16;
            lw[(q * 4 + r) * 72 + nt * 16 + c] = v16;
        }
        uint2 pk;
        pk.x = (unsigned)xb[0] | ((unsigned)xb[1] << 16);
        pk.y = (unsigned)xb[2] | ((unsigned)xb[3] << 16);
        *(uint2*)(xv + (size_t)node * 128 + c * 8) = pk;
    }

    short8 Ax[2];
#pragma unroll
    for (int ks = 0; ks < 2; ++ks)
        Ax[ks] = *(const short8*)&lw[c * 72 + ks * 32 + q * 8];

    f32x4 uacc[4] = {{0,0,0,0},{0,0,0,0},{0,0,0,0},{0,0,0,0}};
    f32x4 vacc[4] = {{0,0,0,0},{0,0,0,0},{0,0,0,0},{0,0,0,0}};
#pragma unroll
    for (int ks = 0; ks < 2; ++ks)
#pragma unroll
        for (int nt = 0; nt < 4; ++nt) {
            uacc[nt] = __builtin_amdgcn_mfma_f32_16x16x32_bf16(Ax[ks], Wa[nt][ks], uacc[nt], 0, 0, 0);
            vacc[nt] = __builtin_amdgcn_mfma_f32_16x16x32_bf16(Ax[ks], Wb[nt][ks], vacc[nt], 0, 0, 0);
        }
#pragma unroll
    for (int r = 0; r < 4; ++r) {
        const int node = n0 + q * 4 + r;
        uint2 pu;
        pu.x = (unsigned)f2bf(uacc[0][r] * L2E) | ((unsigned)f2bf(uacc[1][r] * L2E) << 16);
        pu.y = (unsigned)f2bf(uacc[2][r] * L2E) | ((unsigned)f2bf(uacc[3][r] * L2E) << 16);
        *(uint2*)(u_bf + (size_t)node * 64 + c * 4) = pu;
        uint2 pk;
        pk.x = (unsigned)f2bf(vacc[0][r] * L2E) | ((unsigned)f2bf(vacc[1][r] * L2E) << 16);
        pk.y = (unsigned)f2bf(vacc[2][r] * L2E) | ((unsigned)f2bf(vacc[3][r] * L2E) << 16);
        *(uint2*)(xv + (size_t)node * 128 + c * 8 + 4) = pk;
    }
}

// ---------------------------------------------------------------------------
// scanA: exclusive scan of bucketCnt -> bucketBase.
// ---------------------------------------------------------------------------
__global__ __launch_bounds__(1024) void scanA(
    const int* __restrict__ bucketCnt, int* __restrict__ bucketBase) {
    __shared__ int wsum[16];
    const int t = threadIdx.x, lane = t & 63, w = t >> 6;
    const int v = (t < N_BUCKETS) ? bucketCnt[t] : 0;
    int sc = v;
#pragma unroll
    for (int off = 1; off < 64; off <<= 1) {
        int u = __shfl_up(sc, off);
        if (lane >= off) sc += u;
    }
    if (lane == 63) wsum[w] = sc;
    __syncthreads();
    if (w == 0) {
        int x = (lane < 16) ? wsum[lane] : 0;
#pragma unroll
        for (int off = 1; off < 16; off <<= 1) {
            int u = __shfl_up(x, off);
            if (lane >= off) x += u;
        }
        if (lane < 16) wsum[lane] = x;
    }
    __syncthreads();
    const int excl = sc - v + ((w > 0) ? wsum[w - 1] : 0);
    if (t < N_BUCKETS) bucketBase[t] = excl;
}

// ---------------------------------------------------------------------------
// rowscan: per-bucket (128 rows, 2 waves) exclusive scan of rowCnt + bucket
// base -> exact (unpadded) start[] and scatter cursors. Zeroes 16 slack recs
// past E for agg's software-pipeline prefetch.
// ---------------------------------------------------------------------------
__global__ __launch_bounds__(128) void rowscan(
    const int* __restrict__ rowCnt, const int* __restrict__ bucketBase,
    int* __restrict__ start, int* __restrict__ curs,
    uint2* __restrict__ recs) {
    __shared__ int w0sum;
    const int b = blockIdx.x;
    const int t = threadIdx.x;
    const int gr = b * 128 + t;
    const int lane = t & 63;
    const int v = (gr < N_NODES) ? rowCnt[gr] : 0;
    int sc = v;
#pragma unroll
    for (int off = 1; off < 64; off <<= 1) {
        int u = __shfl_up(sc, off);
        if (lane >= off) sc += u;
    }
    if (t == 63) w0sum = sc;
    __syncthreads();
    const int excl = sc - v + ((t >= 64) ? w0sum : 0) + bucketBase[b];
    if (gr < N_NODES) { start[gr] = excl; curs[gr] = excl; }
    if (b == 0 && t == 0) {
        start[N_NODES] = N_EDGES;
        uint2 z; z.x = 0; z.y = 0;
        for (int i = 0; i < 16; ++i) recs[N_EDGES + i] = z;
    }
}

// ---------------------------------------------------------------------------
// scatterD: single-pass direct scatter to final positions via global cursors.
// srec = {col, dist|em packed}. Writes are uncoalesced 8 B but single-pass.
// ---------------------------------------------------------------------------
__global__ __launch_bounds__(256) void scatterD(
    const int* __restrict__ edges, const float* __restrict__ dist,
    const float* __restrict__ emask, int* __restrict__ curs,
    uint2* __restrict__ recs) {
    const int e0 = blockIdx.x * 2048 + threadIdx.x * 8;
    if (e0 + 8 <= N_EDGES) {
        const int4 r0 = *(const int4*)(edges + e0);
        const int4 r1 = *(const int4*)(edges + e0 + 4);
        const int4 c0 = *(const int4*)(edges + N_EDGES + e0);
        const int4 c1 = *(const int4*)(edges + N_EDGES + e0 + 4);
        const f32x4 d0 = *(const f32x4*)(dist + e0);
        const f32x4 d1 = *(const f32x4*)(dist + e0 + 4);
        const f32x4 m0 = *(const f32x4*)(emask + e0);
        const f32x4 m1 = *(const f32x4*)(emask + e0 + 4);
        const int rows[8] = {r0.x, r0.y, r0.z, r0.w, r1.x, r1.y, r1.z, r1.w};
        const int cols[8] = {c0.x, c0.y, c0.z, c0.w, c1.x, c1.y, c1.z, c1.w};
        const float ds[8] = {d0[0], d0[1], d0[2], d0[3], d1[0], d1[1], d1[2], d1[3]};
        const float ms[8] = {m0[0], m0[1], m0[2], m0[3], m1[0], m1[1], m1[2], m1[3]};
#pragma unroll
        for (int i = 0; i < 8; ++i) {
            const int pos = atomicAdd(&curs[rows[i]], 1);
            uint2 rc;
            rc.x = (unsigned)cols[i];
            rc.y = (unsigned)f2bf(ds[i]) | ((unsigned)f2bf(ms[i] * NORM_INV) << 16);
            recs[pos] = rc;
        }
    } else {
#pragma unroll
        for (int i = 0; i < 8; ++i) {
            const int e = e0 + i;
            if (e < N_EDGES) {
                const int pos = atomicAdd(&curs[edges[e]], 1);
                uint2 rc;
                rc.x = (unsigned)edges[N_EDGES + e];
                rc.y = (unsigned)f2bf(dist[e]) |
                       ((unsigned)f2bf(emask[e] * NORM_INV) << 16);
                recs[pos] = rc;
            }
        }
    }
}

// ---------------------------------------------------------------------------
// agg: one wave/row, 4 edge-slots x 16 feature-lanes. Division-free silu /
// sigmoid via exp2+rcp with log2e folded into stored u,v and tab.
// Unpadded rows: per-slot tail mask zeroes att for slots >= e1.
// ---------------------------------------------------------------------------
__global__ __launch_bounds__(256, 8) void agg_ln_kernel(
    const int* __restrict__ start, const uint2* __restrict__ recs,
    const unsigned short* __restrict__ xv, const unsigned short* __restrict__ u_bf,
    const float4* __restrict__ tab, const float* __restrict__ att_b2,
    const float* __restrict__ ln_g, const float* __restrict__ ln_b,
    float* __restrict__ out) {
    const int lane = threadIdx.x & 63;
    const int wv = threadIdx.x >> 6;
    const int j = lane & 15;
    const int s = lane >> 4;
    const int r = blockIdx.x * 4 + wv;

    const float4 t0 = tab[j], t1 = tab[j + 16], t2 = tab[j + 32], t3 = tab[j + 48];
    const uint2 uu = *(const uint2*)(u_bf + (size_t)r * 64 + j * 4);
    const float base0 = __uint_as_float(uu.x << 16) + t0.z;
    const float base1 = __uint_as_float(uu.x & 0xffff0000u) + t1.z;
    const float base2 = __uint_as_float(uu.y << 16) + t2.z;
    const float base3 = __uint_as_float(uu.y & 0xffff0000u) + t3.z;
    const float b2L = att_b2[0] * L2E;

    const int s0 = start[r];
    const int e1 = start[r + 1];
    const unsigned* xvu = (const unsigned*)xv;

    float a0 = 0.f, a1 = 0.f, a2 = 0.f, a3 = 0.f;
    if (e1 > s0) {
        uint2 recA = recs[s0 + s];
        uint4 xvA = *(const uint4*)(xvu + (size_t)recA.x * 64 + j * 4);
        uint2 recB = recs[s0 + 4 + s];
        for (int e = s0; e < e1; e += 4) {
            const uint2 recC = recs[e + 8 + s];
            const uint4 xvB = *(const uint4*)(xvu + (size_t)recB.x * 64 + j * 4);

            const float dist = __uint_as_float(recA.y << 16);
            const float emN = __uint_as_float(recA.y & 0xffff0000u);
            const float x0 = __uint_as_float(xvA.x << 16);
            const float x1 = __uint_as_float(xvA.x & 0xffff0000u);
            const float x2 = __uint_as_float(xvA.y << 16);
            const float x3 = __uint_as_float(xvA.y & 0xffff0000u);
            const float v0 = __uint_as_float(xvA.z << 16);
            const float v1 = __uint_as_float(xvA.z & 0xffff0000u);
            const float v2 = __uint_as_float(xvA.w << 16);
            const float v3 = __uint_as_float(xvA.w & 0xffff0000u);
            float pv = 0.f, pre, sg;
            pre = fmaf(dist, t0.y, base0) + v0;
            sg = __builtin_amdgcn_rcpf(1.f + __builtin_amdgcn_exp2f(-pre));
            pv = fmaf(pre * sg, t0.x, pv);
            pre = fmaf(dist, t1.y, base1) + v1;
            sg = __builtin_amdgcn_rcpf(1.f + __builtin_amdgcn_exp2f(-pre));
            pv = fmaf(pre * sg, t1.x, pv);
            pre = fmaf(dist, t2.y, base2) + v2;
            sg = __builtin_amdgcn_rcpf(1.f + __builtin_amdgcn_exp2f(-pre));
            pv = fmaf(pre * sg, t2.x, pv);
            pre = fmaf(dist, t3.y, base3) + v3;
            sg = __builtin_amdgcn_rcpf(1.f + __builtin_amdgcn_exp2f(-pre));
            pv = fmaf(pre * sg, t3.x, pv);
            pv += __shfl_xor(pv, 1); pv += __shfl_xor(pv, 2);
            pv += __shfl_xor(pv, 4); pv += __shfl_xor(pv, 8);
            const float sp = fmaf(pv, L2E, b2L);
            const float attRaw =
                emN * __builtin_amdgcn_rcpf(1.f + __builtin_amdgcn_exp2f(-sp));
            const float att = ((e + s) < e1) ? attRaw : 0.f;
            a0 = fmaf(att, x0, a0); a1 = fmaf(att, x1, a1);
            a2 = fmaf(att, x2, a2); a3 = fmaf(att, x3, a3);
            recA = recB; xvA = xvB; recB = recC;
        }
    }
    a0 += __shfl_xor(a0, 16); a0 += __shfl_xor(a0, 32);
    a1 += __shfl_xor(a1, 16); a1 += __shfl_xor(a1, 32);
    a2 += __shfl_xor(a2, 16); a2 += __shfl_xor(a2, 32);
    a3 += __shfl_xor(a3, 16); a3 += __shfl_xor(a3, 32);

    const uint2 xr = *(const uint2*)(xvu + (size_t)r * 64 + j * 4);
    const float o0 = __uint_as_float(xr.x << 16) + a0;
    const float o1 = __uint_as_float(xr.x & 0xffff0000u) + a1;
    const float o2 = __uint_as_float(xr.y << 16) + a2;
    const float o3 = __uint_as_float(xr.y & 0xffff0000u) + a3;

    float ssum = o0 + o1 + o2 + o3;
    ssum += __shfl_xor(ssum, 1); ssum += __shfl_xor(ssum, 2);
    ssum += __shfl_xor(ssum, 4); ssum += __shfl_xor(ssum, 8);
    const float mu = ssum * (1.f / 64.f);
    const float d0 = o0 - mu, d1 = o1 - mu, d2 = o2 - mu, d3 = o3 - mu;
    float vs = d0 * d0 + d1 * d1 + d2 * d2 + d3 * d3;
    vs += __shfl_xor(vs, 1); vs += __shfl_xor(vs, 2);
    vs += __shfl_xor(vs, 4); vs += __shfl_xor(vs, 8);
    const float rstd = rsqrtf(vs * (1.f / 64.f) + LN_EPS);

    const int f = j + 16 * s;
    const float dk = (s == 0) ? d0 : (s == 1) ? d1 : (s == 2) ? d2 : d3;
    const float y = fmaf(dk * rstd, ln_g[f], ln_b[f]);
    out[(size_t)r * 64 + lane] =
        y * __builtin_amdgcn_rcpf(1.f + __builtin_amdgcn_exp2f(-y * L2E));
}

extern "C" void kernel_launch(void* const* d_in, const int* in_sizes, int n_in,
                              void* d_out, int out_size, void* d_ws, size_t ws_size,
                              hipStream_t stream) {
    const float* h      = (const float*)d_in[0];
    const float* dist   = (const float*)d_in[1];
    const int*   edges  = (const int*)d_in[2];
    const float* emask  = (const float*)d_in[4];
    const float* W_lin  = (const float*)d_in[5];
    const float* b_lin  = (const float*)d_in[6];
    const float* att_W1 = (const float*)d_in[7];
    const float* att_b1 = (const float*)d_in[8];
    const float* att_W2 = (const float*)d_in[9];
    const float* att_b2 = (const float*)d_in[10];
    const float* ln_g   = (const float*)d_in[11];
    const float* ln_b   = (const float*)d_in[12];
    float* out = (float*)d_out;

    char* ws = (char*)d_ws;
    unsigned short* xv   = (unsigned short*)ws;                  // 25,600,000
    unsigned short* u_bf = (unsigned short*)(ws + 25600000);     // 12,800,000
    uint2* recs          = (uint2*)(ws + 38400000);              // 8,000,256
    int* rowCnt          = (int*)(ws + 46400256);                // 400,000
    int* bucketCnt       = (int*)(ws + 46800256);                // 3,200 (memset w/ rowCnt)
    int* curs            = (int*)(ws + 46803456);                // 400,128
    int* start           = (int*)(ws + 47203584);                // 400,128
    int* bucketBase      = (int*)(ws + 47603712);                // 3,200
    float4* tab          = (float4*)(ws + 47606912);             // 1,024
    short8* whi          = (short8*)(ws + 47607936);             // 8,192
    short8* wlo          = (short8*)(ws + 47616128);             // 8,192
    short8* wa           = (short8*)(ws + 47624320);             // 8,192
    short8* wb           = (short8*)(ws + 47632512);             // 8,192

    hipMemsetAsync(rowCnt, 0, 403200, stream);  // rowCnt + bucketCnt
    prep_frags<<<1, 256, 0, stream>>>(W_lin, att_W1, att_b1, att_W2,
                                      whi, wlo, wa, wb, tab);
    proj_hist<<<PROJ_BLOCKS + HISTB, 256, 0, stream>>>(
        h, b_lin, whi, wlo, wa, wb, edges, rowCnt, bucketCnt, xv, u_bf);
    scanA<<<1, 1024, 0, stream>>>(bucketCnt, bucketBase);
    rowscan<<<N_BUCKETS, 128, 0, stream>>>(rowCnt, bucketBase, start, curs, recs);
    scatterD<<<HISTB, 256, 0, stream>>>(edges, dist, emask, curs, recs);
    agg_ln_kernel<<<N_NODES / 4, 256, 0, stream>>>(start, recs, xv, u_bf,
                                                   tab, att_b2, ln_g, ln_b, out);
}

// Round 2
// 237.604 us; speedup vs baseline: 1.1845x; 1.1845x over previous
//
#include <hip/hip_runtime.h>
#include <hip/hip_bf16.h>

#define N_NODES 100000
#define N_EDGES 1000000
#define DIM 64
#define NORM_INV 0.01f
#define LN_EPS 1e-5f
#define N_TILES 6250          // N_NODES/16
#define PROJ_BLOCKS 1563      // ceil(6250/4)
#define N_BUCKETS 782         // ceil(100000/128), 128 rows per bucket
#define HISTB 489             // ceil(1e6/2048)
#define L2E 1.4426950408889634f
#define LN2 0.6931471805599453f
#define CAP 2560              // LDS record capacity/bucket (mean padded ~1470, +30 sigma)
#define RPT 5                 // CAP / 512 register-staged records per thread

typedef __attribute__((ext_vector_type(8))) short short8;
typedef __attribute__((ext_vector_type(4))) float f32x4;

__device__ __forceinline__ unsigned short f2bf(float f) {
    union { float f; unsigned u; } x; x.f = f;
    unsigned r = x.u + 0x7FFFu + ((x.u >> 16) & 1u);
    return (unsigned short)(r >> 16);
}
__device__ __forceinline__ float bf2f(unsigned short s) {
    union { unsigned u; float f; } x; x.u = ((unsigned)s) << 16; return x.f;
}

// ---------------------------------------------------------------------------
// P0: precompute MFMA weight fragments + per-feature epilogue table.
// tab[f] = {w2[f]*ln2, w1c[f]*log2e, b1[f]*log2e, 0}
// ---------------------------------------------------------------------------
__global__ __launch_bounds__(256) void prep_frags(
    const float* __restrict__ W, const float* __restrict__ att_W1,
    const float* __restrict__ att_b1, const float* __restrict__ att_W2,
    short8* __restrict__ whi, short8* __restrict__ wlo,
    short8* __restrict__ wa, short8* __restrict__ wb,
    float4* __restrict__ tab) {
    const int l = threadIdx.x & 63;
    const int nt = threadIdx.x >> 6;
    const int c = l & 15, q = l >> 4;
    const int n = nt * 16 + c;
#pragma unroll
    for (int ks = 0; ks < 2; ++ks) {
        const int k0 = ks * 32 + q * 8;
        short8 hi8, lo8, a8, b8;
#pragma unroll
        for (int jj = 0; jj < 8; ++jj) {
            float w = W[n * 64 + k0 + jj];
            unsigned short hh = f2bf(w);
            hi8[jj] = (short)hh;
            lo8[jj] = (short)f2bf(w - bf2f(hh));
            a8[jj] = (short)f2bf(att_W1[n * 129 + k0 + jj]);
            b8[jj] = (short)f2bf(att_W1[n * 129 + 64 + k0 + jj]);
        }
        const int idx = (nt * 2 + ks) * 64 + l;
        whi[idx] = hi8; wlo[idx] = lo8; wa[idx] = a8; wb[idx] = b8;
    }
    if (threadIdx.x < 64) {
        const int f = threadIdx.x;
        tab[f] = make_float4(att_W2[f] * LN2, att_W1[f * 129 + 128] * L2E,
                             att_b1[f] * L2E, 0.f);
    }
}

// ---------------------------------------------------------------------------
// P1 fat kernel. blocks [0,PROJ_BLOCKS): MFMA projection, 1 tile/wave.
//   x = h@W^T + b (hi/lo bf16 split), u = x@W1a^T * log2e, v = x@W1b^T * log2e
// blocks [PROJ_BLOCKS, +HISTB): bucket histogram (LDS-staged, 1 atomic/bucket).
// ---------------------------------------------------------------------------
__global__ __launch_bounds__(256) void proj_hist(
    const float* __restrict__ h, const float* __restrict__ bl,
    const short8* __restrict__ whi, const short8* __restrict__ wlo,
    const short8* __restrict__ wa, const short8* __restrict__ wb,
    const int* __restrict__ edges, int* __restrict__ bucketCnt,
    unsigned short* __restrict__ xv, unsigned short* __restrict__ u_bf) {
    if (blockIdx.x >= PROJ_BLOCKS) {
        __shared__ int lh[N_BUCKETS];
        const int tid = threadIdx.x;
        for (int i = tid; i < N_BUCKETS; i += 256) lh[i] = 0;
        __syncthreads();
        const int e0 = (blockIdx.x - PROJ_BLOCKS) * 2048;
#pragma unroll
        for (int i = 0; i < 8; ++i) {
            const int e = e0 + tid * 8 + i;
            if (e < N_EDGES) atomicAdd(&lh[edges[e] >> 7], 1);
        }
        __syncthreads();
        for (int b = tid; b < N_BUCKETS; b += 256)
            if (lh[b]) atomicAdd(&bucketCnt[b], lh[b]);
        return;
    }
    __shared__ __align__(16) unsigned short lds[4][16 * 72];
    const int lane = threadIdx.x & 63;
    const int wv = threadIdx.x >> 6;
    const int c = lane & 15, q = lane >> 4;
    const int tile = blockIdx.x * 4 + wv;
    if (tile >= N_TILES) return;
    const int n0 = tile * 16;

    short8 Whi[4][2], Wlo[4][2], Wa[4][2], Wb[4][2];
    float bias[4];
#pragma unroll
    for (int nt = 0; nt < 4; ++nt) {
        bias[nt] = bl[nt * 16 + c];
#pragma unroll
        for (int ks = 0; ks < 2; ++ks) {
            const int idx = (nt * 2 + ks) * 64 + lane;
            Whi[nt][ks] = whi[idx]; Wlo[nt][ks] = wlo[idx];
            Wa[nt][ks] = wa[idx];   Wb[nt][ks] = wb[idx];
        }
    }

    short8 Ahi[2], Alo[2];
#pragma unroll
    for (int ks = 0; ks < 2; ++ks) {
        const float* hp = h + (size_t)(n0 + c) * 64 + ks * 32 + q * 8;
        f32x4 p0 = *(const f32x4*)hp;
        f32x4 p1 = *(const f32x4*)(hp + 4);
        short8 hi8, lo8;
#pragma unroll
        for (int jj = 0; jj < 4; ++jj) {
            unsigned short hh = f2bf(p0[jj]);
            hi8[jj] = (short)hh; lo8[jj] = (short)f2bf(p0[jj] - bf2f(hh));
            unsigned short h2 = f2bf(p1[jj]);
            hi8[4 + jj] = (short)h2; lo8[4 + jj] = (short)f2bf(p1[jj] - bf2f(h2));
        }
        Ahi[ks] = hi8; Alo[ks] = lo8;
    }

    f32x4 xacc[4] = {{0,0,0,0},{0,0,0,0},{0,0,0,0},{0,0,0,0}};
#pragma unroll
    for (int ks = 0; ks < 2; ++ks)
#pragma unroll
        for (int nt = 0; nt < 4; ++nt) {
            xacc[nt] = __builtin_amdgcn_mfma_f32_16x16x32_bf16(Ahi[ks], Whi[nt][ks], xacc[nt], 0, 0, 0);
            xacc[nt] = __builtin_amdgcn_mfma_f32_16x16x32_bf16(Ahi[ks], Wlo[nt][ks], xacc[nt], 0, 0, 0);
            xacc[nt] = __builtin_amdgcn_mfma_f32_16x16x32_bf16(Alo[ks], Whi[nt][ks], xacc[nt], 0, 0, 0);
        }

    unsigned short* lw = lds[wv];
#pragma unroll
    for (int r = 0; r < 4; ++r) {
        const int node = n0 + q * 4 + r;
        unsigned short xb[4];
#pragma unroll
        for (int nt = 0; nt < 4; ++nt) {
            unsigned short v16 = f2bf(xacc[nt][r] + bias[nt]);
            xb[nt] = v16;
            lw[(q * 4 + r) * 72 + nt * 16 + c] = v16;
        }
        uint2 pk;
        pk.x = (unsigned)xb[0] | ((unsigned)xb[1] << 16);
        pk.y = (unsigned)xb[2] | ((unsigned)xb[3] << 16);
        *(uint2*)(xv + (size_t)node * 128 + c * 8) = pk;
    }

    short8 Ax[2];
#pragma unroll
    for (int ks = 0; ks < 2; ++ks)
        Ax[ks] = *(const short8*)&lw[c * 72 + ks * 32 + q * 8];

    f32x4 uacc[4] = {{0,0,0,0},{0,0,0,0},{0,0,0,0},{0,0,0,0}};
    f32x4 vacc[4] = {{0,0,0,0},{0,0,0,0},{0,0,0,0},{0,0,0,0}};
#pragma unroll
    for (int ks = 0; ks < 2; ++ks)
#pragma unroll
        for (int nt = 0; nt < 4; ++nt) {
            uacc[nt] = __builtin_amdgcn_mfma_f32_16x16x32_bf16(Ax[ks], Wa[nt][ks], uacc[nt], 0, 0, 0);
            vacc[nt] = __builtin_amdgcn_mfma_f32_16x16x32_bf16(Ax[ks], Wb[nt][ks], vacc[nt], 0, 0, 0);
        }
#pragma unroll
    for (int r = 0; r < 4; ++r) {
        const int node = n0 + q * 4 + r;
        uint2 pu;
        pu.x = (unsigned)f2bf(uacc[0][r] * L2E) | ((unsigned)f2bf(uacc[1][r] * L2E) << 16);
        pu.y = (unsigned)f2bf(uacc[2][r] * L2E) | ((unsigned)f2bf(uacc[3][r] * L2E) << 16);
        *(uint2*)(u_bf + (size_t)node * 64 + c * 4) = pu;
        uint2 pk;
        pk.x = (unsigned)f2bf(vacc[0][r] * L2E) | ((unsigned)f2bf(vacc[1][r] * L2E) << 16);
        pk.y = (unsigned)f2bf(vacc[2][r] * L2E) | ((unsigned)f2bf(vacc[3][r] * L2E) << 16);
        *(uint2*)(xv + (size_t)node * 128 + c * 8 + 4) = pk;
    }
}

// ---------------------------------------------------------------------------
// scanA: exclusive scan of bucketCnt -> baseA (staging bases) + cursA.
// ---------------------------------------------------------------------------
__global__ __launch_bounds__(1024) void scanA(
    const int* __restrict__ bucketCnt, int* __restrict__ baseA,
    int* __restrict__ cursA) {
    __shared__ int wsum[16];
    const int t = threadIdx.x, lane = t & 63, w = t >> 6;
    const int v = (t < N_BUCKETS) ? bucketCnt[t] : 0;
    int sc = v;
#pragma unroll
    for (int off = 1; off < 64; off <<= 1) {
        int u = __shfl_up(sc, off);
        if (lane >= off) sc += u;
    }
    if (lane == 63) wsum[w] = sc;
    __syncthreads();
    if (w == 0) {
        int x = (lane < 16) ? wsum[lane] : 0;
#pragma unroll
        for (int off = 1; off < 16; off <<= 1) {
            int u = __shfl_up(x, off);
            if (lane >= off) x += u;
        }
        if (lane < 16) wsum[lane] = x;
    }
    __syncthreads();
    const int excl = sc - v + ((w > 0) ? wsum[w - 1] : 0);
    if (t < N_BUCKETS) { baseA[t] = excl; cursA[t] = excl; }
    if (t == N_BUCKETS - 1) baseA[N_BUCKETS] = excl + v;
}

// ---------------------------------------------------------------------------
// scatterA: stage edges into bucket regions. 2048 edges/block, LDS-ranked so
// writes to each bucket region are block-bursts. srec = {col, dist|em packed},
// lrowS = row & 127 (1 B).
// ---------------------------------------------------------------------------
__global__ __launch_bounds__(256) void scatterA(
    const int* __restrict__ edges, const float* __restrict__ dist,
    const float* __restrict__ emask, int* __restrict__ cursA,
    uint2* __restrict__ srec, unsigned char* __restrict__ lrowS) {
    __shared__ int lh[N_BUCKETS];
    __shared__ int lb[N_BUCKETS];
    const int tid = threadIdx.x;
    for (int i = tid; i < N_BUCKETS; i += 256) lh[i] = 0;
    __syncthreads();

    const int e0 = blockIdx.x * 2048 + tid * 8;
    int row[8], col[8];
    unsigned de[8];
#pragma unroll
    for (int i = 0; i < 8; ++i) {
        const int e = e0 + i;
        if (e < N_EDGES) {
            row[i] = edges[e];
            col[i] = edges[N_EDGES + e];
            de[i] = (unsigned)f2bf(dist[e]) | ((unsigned)f2bf(emask[e] * NORM_INV) << 16);
            atomicAdd(&lh[row[i] >> 7], 1);
        } else {
            row[i] = -1;
        }
    }
    __syncthreads();
    for (int b = tid; b < N_BUCKETS; b += 256) {
        const int c = lh[b];
        lb[b] = c ? atomicAdd(&cursA[b], c) : 0;
    }
    __syncthreads();
    for (int i = tid; i < N_BUCKETS; i += 256) lh[i] = 0;
    __syncthreads();
#pragma unroll
    for (int i = 0; i < 8; ++i) {
        if (row[i] >= 0) {
            const int bk = row[i] >> 7;
            const int rk = atomicAdd(&lh[bk], 1);
            const int pos = lb[bk] + rk;
            uint2 rc; rc.x = (unsigned)col[i]; rc.y = de[i];
            srec[pos] = rc;
            lrowS[pos] = (unsigned char)(row[i] & 127);
        }
    }
}

// ---------------------------------------------------------------------------
// agg_fused: one block (512 thr, 8 waves) per 128-row bucket.
// Phase 1: register-stage bucket records, LDS histogram by local row.
// Phase 2: padded (x4) exclusive scan over 128 rows -> LDS row starts.
// Phase 3: counting-sort records into LDS (zero recs pad; emN=0 => att=0).
// Phase 4: each wave aggregates 16 rows (4 edge-slots x 16 feature-lanes),
//          then LN + silu, identical math to the verified agg_ln_kernel.
// ---------------------------------------------------------------------------
__global__ __launch_bounds__(512, 4) void agg_fused(
    const int* __restrict__ baseA, const unsigned char* __restrict__ lrowS,
    const uint2* __restrict__ srec,
    const unsigned short* __restrict__ xv, const unsigned short* __restrict__ u_bf,
    const float4* __restrict__ tab, const float* __restrict__ att_b2,
    const float* __restrict__ ln_g, const float* __restrict__ ln_b,
    float* __restrict__ out) {
    __shared__ __align__(16) uint2 lrecs[CAP + 16];
    __shared__ int hist[128];
    __shared__ int rst[129];
    __shared__ int cur[128];
    __shared__ int wtot;

    const int b = blockIdx.x;
    const int tid = threadIdx.x;
    const int lane = tid & 63;
    const int wv = tid >> 6;
    const int s0g = baseA[b];
    const int cnt = baseA[b + 1] - s0g;

    if (tid < 128) hist[tid] = 0;
    __syncthreads();

    // Phase 1: register staging + histogram (statically indexed regs).
    uint2 rec0, rec1, rec2, rec3, rec4;
    int lr0 = -1, lr1 = -1, lr2 = -1, lr3 = -1, lr4 = -1;
    {
        int idx = tid;
        if (idx < cnt) { rec0 = srec[s0g + idx]; lr0 = lrowS[s0g + idx]; atomicAdd(&hist[lr0], 1); }
        idx += 512;
        if (idx < cnt) { rec1 = srec[s0g + idx]; lr1 = lrowS[s0g + idx]; atomicAdd(&hist[lr1], 1); }
        idx += 512;
        if (idx < cnt) { rec2 = srec[s0g + idx]; lr2 = lrowS[s0g + idx]; atomicAdd(&hist[lr2], 1); }
        idx += 512;
        if (idx < cnt) { rec3 = srec[s0g + idx]; lr3 = lrowS[s0g + idx]; atomicAdd(&hist[lr3], 1); }
        idx += 512;
        if (idx < cnt) { rec4 = srec[s0g + idx]; lr4 = lrowS[s0g + idx]; atomicAdd(&hist[lr4], 1); }
    }
    __syncthreads();

    // Phase 2: padded scan over 128 rows (waves 0 and 1).
    int c = 0, p = 0, sc = 0;
    if (tid < 128) {
        c = hist[tid];
        p = (c + 3) & ~3;
        sc = p;
#pragma unroll
        for (int off = 1; off < 64; off <<= 1) {
            int u = __shfl_up(sc, off);
            if (lane >= off) sc += u;
        }
        if (tid == 63) wtot = sc;
    }
    __syncthreads();
    if (tid < 128) {
        if (tid >= 64) sc += wtot;
        const int excl = sc - p;
        rst[tid] = excl;
        cur[tid] = excl;
        uint2 z; z.x = 0; z.y = 0;
        for (int i = c; i < p; ++i) lrecs[excl + i] = z;
        if (tid == 127) {
            rst[128] = excl + p;
            for (int i = 0; i < 16; ++i) lrecs[excl + p + i] = z;
        }
    }
    __syncthreads();

    // Phase 3: counting-sort into LDS.
    if (lr0 >= 0) lrecs[atomicAdd(&cur[lr0], 1)] = rec0;
    if (lr1 >= 0) lrecs[atomicAdd(&cur[lr1], 1)] = rec1;
    if (lr2 >= 0) lrecs[atomicAdd(&cur[lr2], 1)] = rec2;
    if (lr3 >= 0) lrecs[atomicAdd(&cur[lr3], 1)] = rec3;
    if (lr4 >= 0) lrecs[atomicAdd(&cur[lr4], 1)] = rec4;
    __syncthreads();

    // Phase 4: aggregation. Wave wv handles local rows wv, wv+8, ..., wv+120.
    const int j = lane & 15;
    const int sl = lane >> 4;
    const float4 t0 = tab[j], t1 = tab[j + 16], t2 = tab[j + 32], t3 = tab[j + 48];
    const float b2L = att_b2[0] * L2E;
    const float gg = ln_g[lane], bb = ln_b[lane];
    const unsigned* xvu = (const unsigned*)xv;

#pragma unroll 1
    for (int k = 0; k < 16; ++k) {
        const int lrw = wv + 8 * k;
        const int r = b * 128 + lrw;
        if (r >= N_NODES) break;

        const uint2 uu = *(const uint2*)(u_bf + (size_t)r * 64 + j * 4);
        const float base0 = __uint_as_float(uu.x << 16) + t0.z;
        const float base1 = __uint_as_float(uu.x & 0xffff0000u) + t1.z;
        const float base2 = __uint_as_float(uu.y << 16) + t2.z;
        const float base3 = __uint_as_float(uu.y & 0xffff0000u) + t3.z;

        const int s0 = rst[lrw];
        const int e1 = rst[lrw + 1];

        float a0 = 0.f, a1 = 0.f, a2 = 0.f, a3 = 0.f;
        if (e1 > s0) {
            uint2 recA = lrecs[s0 + sl];
            uint4 xvA = *(const uint4*)(xvu + (size_t)recA.x * 64 + j * 4);
            for (int e = s0; e < e1; e += 4) {
                const uint2 recB = lrecs[e + 4 + sl];
                const uint4 xvB = *(const uint4*)(xvu + (size_t)recB.x * 64 + j * 4);

                const float dist = __uint_as_float(recA.y << 16);
                const float emN = __uint_as_float(recA.y & 0xffff0000u);
                const float x0 = __uint_as_float(xvA.x << 16);
                const float x1 = __uint_as_float(xvA.x & 0xffff0000u);
                const float x2 = __uint_as_float(xvA.y << 16);
                const float x3 = __uint_as_float(xvA.y & 0xffff0000u);
                const float v0 = __uint_as_float(xvA.z << 16);
                const float v1 = __uint_as_float(xvA.z & 0xffff0000u);
                const float v2 = __uint_as_float(xvA.w << 16);
                const float v3 = __uint_as_float(xvA.w & 0xffff0000u);
                float pv = 0.f, pre, sg;
                pre = fmaf(dist, t0.y, base0) + v0;
                sg = __builtin_amdgcn_rcpf(1.f + __builtin_amdgcn_exp2f(-pre));
                pv = fmaf(pre * sg, t0.x, pv);
                pre = fmaf(dist, t1.y, base1) + v1;
                sg = __builtin_amdgcn_rcpf(1.f + __builtin_amdgcn_exp2f(-pre));
                pv = fmaf(pre * sg, t1.x, pv);
                pre = fmaf(dist, t2.y, base2) + v2;
                sg = __builtin_amdgcn_rcpf(1.f + __builtin_amdgcn_exp2f(-pre));
                pv = fmaf(pre * sg, t2.x, pv);
                pre = fmaf(dist, t3.y, base3) + v3;
                sg = __builtin_amdgcn_rcpf(1.f + __builtin_amdgcn_exp2f(-pre));
                pv = fmaf(pre * sg, t3.x, pv);
                pv += __shfl_xor(pv, 1); pv += __shfl_xor(pv, 2);
                pv += __shfl_xor(pv, 4); pv += __shfl_xor(pv, 8);
                const float sp = fmaf(pv, L2E, b2L);
                const float att =
                    emN * __builtin_amdgcn_rcpf(1.f + __builtin_amdgcn_exp2f(-sp));
                a0 = fmaf(att, x0, a0); a1 = fmaf(att, x1, a1);
                a2 = fmaf(att, x2, a2); a3 = fmaf(att, x3, a3);
                recA = recB; xvA = xvB;
            }
        }
        a0 += __shfl_xor(a0, 16); a0 += __shfl_xor(a0, 32);
        a1 += __shfl_xor(a1, 16); a1 += __shfl_xor(a1, 32);
        a2 += __shfl_xor(a2, 16); a2 += __shfl_xor(a2, 32);
        a3 += __shfl_xor(a3, 16); a3 += __shfl_xor(a3, 32);

        const uint2 xr = *(const uint2*)(xvu + (size_t)r * 64 + j * 4);
        const float o0 = __uint_as_float(xr.x << 16) + a0;
        const float o1 = __uint_as_float(xr.x & 0xffff0000u) + a1;
        const float o2 = __uint_as_float(xr.y << 16) + a2;
        const float o3 = __uint_as_float(xr.y & 0xffff0000u) + a3;

        float ssum = o0 + o1 + o2 + o3;
        ssum += __shfl_xor(ssum, 1); ssum += __shfl_xor(ssum, 2);
        ssum += __shfl_xor(ssum, 4); ssum += __shfl_xor(ssum, 8);
        const float mu = ssum * (1.f / 64.f);
        const float d0 = o0 - mu, d1 = o1 - mu, d2 = o2 - mu, d3 = o3 - mu;
        float vs = d0 * d0 + d1 * d1 + d2 * d2 + d3 * d3;
        vs += __shfl_xor(vs, 1); vs += __shfl_xor(vs, 2);
        vs += __shfl_xor(vs, 4); vs += __shfl_xor(vs, 8);
        const float rstd = rsqrtf(vs * (1.f / 64.f) + LN_EPS);

        const float dk = (sl == 0) ? d0 : (sl == 1) ? d1 : (sl == 2) ? d2 : d3;
        const float y = fmaf(dk * rstd, gg, bb);
        out[(size_t)r * 64 + lane] =
            y * __builtin_amdgcn_rcpf(1.f + __builtin_amdgcn_exp2f(-y * L2E));
    }
}

extern "C" void kernel_launch(void* const* d_in, const int* in_sizes, int n_in,
                              void* d_out, int out_size, void* d_ws, size_t ws_size,
                              hipStream_t stream) {
    const float* h      = (const float*)d_in[0];
    const float* dist   = (const float*)d_in[1];
    const int*   edges  = (const int*)d_in[2];
    const float* emask  = (const float*)d_in[4];
    const float* W_lin  = (const float*)d_in[5];
    const float* b_lin  = (const float*)d_in[6];
    const float* att_W1 = (const float*)d_in[7];
    const float* att_b1 = (const float*)d_in[8];
    const float* att_W2 = (const float*)d_in[9];
    const float* att_b2 = (const float*)d_in[10];
    const float* ln_g   = (const float*)d_in[11];
    const float* ln_b   = (const float*)d_in[12];
    float* out = (float*)d_out;

    char* ws = (char*)d_ws;
    unsigned short* xv   = (unsigned short*)ws;                  // 25,600,000
    unsigned short* u_bf = (unsigned short*)(ws + 25600000);     // 12,800,000
    uint2* srec          = (uint2*)(ws + 38400000);              //  8,000,000
    unsigned char* lrowS = (unsigned char*)(ws + 46400000);      //  1,000,000
    int* bucketCnt       = (int*)(ws + 47400000);                //  3,200
    int* baseA           = (int*)(ws + 47403200);                //  3,200
    int* cursA           = (int*)(ws + 47406400);                //  3,200
    float4* tab          = (float4*)(ws + 47409600);             //  1,024
    short8* whi          = (short8*)(ws + 47410624);             //  8,192
    short8* wlo          = (short8*)(ws + 47418816);             //  8,192
    short8* wa           = (short8*)(ws + 47427008);             //  8,192
    short8* wb           = (short8*)(ws + 47435200);             //  8,192

    hipMemsetAsync(bucketCnt, 0, N_BUCKETS * sizeof(int), stream);
    prep_frags<<<1, 256, 0, stream>>>(W_lin, att_W1, att_b1, att_W2,
                                      whi, wlo, wa, wb, tab);
    proj_hist<<<PROJ_BLOCKS + HISTB, 256, 0, stream>>>(
        h, b_lin, whi, wlo, wa, wb, edges, bucketCnt, xv, u_bf);
    scanA<<<1, 1024, 0, stream>>>(bucketCnt, baseA, cursA);
    scatterA<<<HISTB, 256, 0, stream>>>(edges, dist, emask, cursA, srec, lrowS);
    agg_fused<<<N_BUCKETS, 512, 0, stream>>>(baseA, lrowS, srec, xv, u_bf,
                                             tab, att_b2, ln_g, ln_b, out);
}

// Round 3
// 232.891 us; speedup vs baseline: 1.2084x; 1.0202x over previous
//
#include <hip/hip_runtime.h>
#include <hip/hip_bf16.h>

#define N_NODES 100000
#define N_EDGES 1000000
#define DIM 64
#define NORM_INV 0.01f
#define LN_EPS 1e-5f
#define N_TILES 6250          // N_NODES/16
#define PROJ_BLOCKS 1563      // ceil(6250/4)
#define N_BUCKETS 782         // ceil(100000/128), 128 rows per bucket
#define NB_PAD 800            // padded bin count for 4-per-thread scan
#define HISTB 489             // ceil(1e6/2048)
#define SC_EDGES 4096         // edges per scatter block
#define SC_BLOCKS 245         // ceil(1e6/4096)
#define L2E 1.4426950408889634f
#define LN2 0.6931471805599453f
#define CAP 2560              // LDS record capacity/bucket

typedef __attribute__((ext_vector_type(8))) short short8;
typedef __attribute__((ext_vector_type(4))) float f32x4;

__device__ __forceinline__ unsigned short f2bf(float f) {
    union { float f; unsigned u; } x; x.f = f;
    unsigned r = x.u + 0x7FFFu + ((x.u >> 16) & 1u);
    return (unsigned short)(r >> 16);
}
__device__ __forceinline__ float bf2f(unsigned short s) {
    union { unsigned u; float f; } x; x.u = ((unsigned)s) << 16; return x.f;
}

// ---------------------------------------------------------------------------
// P0: precompute MFMA weight fragments + per-feature epilogue table.
// tab[f] = {w2[f]*ln2, w1c[f]*log2e, b1[f]*log2e, 0}
// ---------------------------------------------------------------------------
__global__ __launch_bounds__(256) void prep_frags(
    const float* __restrict__ W, const float* __restrict__ att_W1,
    const float* __restrict__ att_b1, const float* __restrict__ att_W2,
    short8* __restrict__ whi, short8* __restrict__ wlo,
    short8* __restrict__ wa, short8* __restrict__ wb,
    float4* __restrict__ tab) {
    const int l = threadIdx.x & 63;
    const int nt = threadIdx.x >> 6;
    const int c = l & 15, q = l >> 4;
    const int n = nt * 16 + c;
#pragma unroll
    for (int ks = 0; ks < 2; ++ks) {
        const int k0 = ks * 32 + q * 8;
        short8 hi8, lo8, a8, b8;
#pragma unroll
        for (int jj = 0; jj < 8; ++jj) {
            float w = W[n * 64 + k0 + jj];
            unsigned short hh = f2bf(w);
            hi8[jj] = (short)hh;
            lo8[jj] = (short)f2bf(w - bf2f(hh));
            a8[jj] = (short)f2bf(att_W1[n * 129 + k0 + jj]);
            b8[jj] = (short)f2bf(att_W1[n * 129 + 64 + k0 + jj]);
        }
        const int idx = (nt * 2 + ks) * 64 + l;
        whi[idx] = hi8; wlo[idx] = lo8; wa[idx] = a8; wb[idx] = b8;
    }
    if (threadIdx.x < 64) {
        const int f = threadIdx.x;
        tab[f] = make_float4(att_W2[f] * LN2, att_W1[f * 129 + 128] * L2E,
                             att_b1[f] * L2E, 0.f);
    }
}

// ---------------------------------------------------------------------------
// P1 fat kernel. blocks [0,PROJ_BLOCKS): MFMA projection, 1 tile/wave.
//   x = h@W^T + b (hi/lo bf16 split), u = x@W1a^T * log2e, v = x@W1b^T * log2e
// blocks [PROJ_BLOCKS, +HISTB): bucket histogram (LDS-staged, 1 atomic/bucket).
// ---------------------------------------------------------------------------
__global__ __launch_bounds__(256) void proj_hist(
    const float* __restrict__ h, const float* __restrict__ bl,
    const short8* __restrict__ whi, const short8* __restrict__ wlo,
    const short8* __restrict__ wa, const short8* __restrict__ wb,
    const int* __restrict__ edges, int* __restrict__ bucketCnt,
    unsigned short* __restrict__ xv, unsigned short* __restrict__ u_bf) {
    if (blockIdx.x >= PROJ_BLOCKS) {
        __shared__ int lh[N_BUCKETS];
        const int tid = threadIdx.x;
        for (int i = tid; i < N_BUCKETS; i += 256) lh[i] = 0;
        __syncthreads();
        const int e0 = (blockIdx.x - PROJ_BLOCKS) * 2048;
#pragma unroll
        for (int i = 0; i < 8; ++i) {
            const int e = e0 + tid * 8 + i;
            if (e < N_EDGES) atomicAdd(&lh[edges[e] >> 7], 1);
        }
        __syncthreads();
        for (int b = tid; b < N_BUCKETS; b += 256)
            if (lh[b]) atomicAdd(&bucketCnt[b], lh[b]);
        return;
    }
    __shared__ __align__(16) unsigned short lds[4][16 * 72];
    const int lane = threadIdx.x & 63;
    const int wv = threadIdx.x >> 6;
    const int c = lane & 15, q = lane >> 4;
    const int tile = blockIdx.x * 4 + wv;
    if (tile >= N_TILES) return;
    const int n0 = tile * 16;

    short8 Whi[4][2], Wlo[4][2], Wa[4][2], Wb[4][2];
    float bias[4];
#pragma unroll
    for (int nt = 0; nt < 4; ++nt) {
        bias[nt] = bl[nt * 16 + c];
#pragma unroll
        for (int ks = 0; ks < 2; ++ks) {
            const int idx = (nt * 2 + ks) * 64 + lane;
            Whi[nt][ks] = whi[idx]; Wlo[nt][ks] = wlo[idx];
            Wa[nt][ks] = wa[idx];   Wb[nt][ks] = wb[idx];
        }
    }

    short8 Ahi[2], Alo[2];
#pragma unroll
    for (int ks = 0; ks < 2; ++ks) {
        const float* hp = h + (size_t)(n0 + c) * 64 + ks * 32 + q * 8;
        f32x4 p0 = *(const f32x4*)hp;
        f32x4 p1 = *(const f32x4*)(hp + 4);
        short8 hi8, lo8;
#pragma unroll
        for (int jj = 0; jj < 4; ++jj) {
            unsigned short hh = f2bf(p0[jj]);
            hi8[jj] = (short)hh; lo8[jj] = (short)f2bf(p0[jj] - bf2f(hh));
            unsigned short h2 = f2bf(p1[jj]);
            hi8[4 + jj] = (short)h2; lo8[4 + jj] = (short)f2bf(p1[jj] - bf2f(h2));
        }
        Ahi[ks] = hi8; Alo[ks] = lo8;
    }

    f32x4 xacc[4] = {{0,0,0,0},{0,0,0,0},{0,0,0,0},{0,0,0,0}};
#pragma unroll
    for (int ks = 0; ks < 2; ++ks)
#pragma unroll
        for (int nt = 0; nt < 4; ++nt) {
            xacc[nt] = __builtin_amdgcn_mfma_f32_16x16x32_bf16(Ahi[ks], Whi[nt][ks], xacc[nt], 0, 0, 0);
            xacc[nt] = __builtin_amdgcn_mfma_f32_16x16x32_bf16(Ahi[ks], Wlo[nt][ks], xacc[nt], 0, 0, 0);
            xacc[nt] = __builtin_amdgcn_mfma_f32_16x16x32_bf16(Alo[ks], Whi[nt][ks], xacc[nt], 0, 0, 0);
        }

    unsigned short* lw = lds[wv];
#pragma unroll
    for (int r = 0; r < 4; ++r) {
        const int node = n0 + q * 4 + r;
        unsigned short xb[4];
#pragma unroll
        for (int nt = 0; nt < 4; ++nt) {
            unsigned short v16 = f2bf(xacc[nt][r] + bias[nt]);
            xb[nt] = v16;
            lw[(q * 4 + r) * 72 + nt * 16 + c] = v16;
        }
        uint2 pk;
        pk.x = (unsigned)xb[0] | ((unsigned)xb[1] << 16);
        pk.y = (unsigned)xb[2] | ((unsigned)xb[3] << 16);
        *(uint2*)(xv + (size_t)node * 128 + c * 8) = pk;
    }

    short8 Ax[2];
#pragma unroll
    for (int ks = 0; ks < 2; ++ks)
        Ax[ks] = *(const short8*)&lw[c * 72 + ks * 32 + q * 8];

    f32x4 uacc[4] = {{0,0,0,0},{0,0,0,0},{0,0,0,0},{0,0,0,0}};
    f32x4 vacc[4] = {{0,0,0,0},{0,0,0,0},{0,0,0,0},{0,0,0,0}};
#pragma unroll
    for (int ks = 0; ks < 2; ++ks)
#pragma unroll
        for (int nt = 0; nt < 4; ++nt) {
            uacc[nt] = __builtin_amdgcn_mfma_f32_16x16x32_bf16(Ax[ks], Wa[nt][ks], uacc[nt], 0, 0, 0);
            vacc[nt] = __builtin_amdgcn_mfma_f32_16x16x32_bf16(Ax[ks], Wb[nt][ks], vacc[nt], 0, 0, 0);
        }
#pragma unroll
    for (int r = 0; r < 4; ++r) {
        const int node = n0 + q * 4 + r;
        uint2 pu;
        pu.x = (unsigned)f2bf(uacc[0][r] * L2E) | ((unsigned)f2bf(uacc[1][r] * L2E) << 16);
        pu.y = (unsigned)f2bf(uacc[2][r] * L2E) | ((unsigned)f2bf(uacc[3][r] * L2E) << 16);
        *(uint2*)(u_bf + (size_t)node * 64 + c * 4) = pu;
        uint2 pk;
        pk.x = (unsigned)f2bf(vacc[0][r] * L2E) | ((unsigned)f2bf(vacc[1][r] * L2E) << 16);
        pk.y = (unsigned)f2bf(vacc[2][r] * L2E) | ((unsigned)f2bf(vacc[3][r] * L2E) << 16);
        *(uint2*)(xv + (size_t)node * 128 + c * 8 + 4) = pk;
    }
}

// ---------------------------------------------------------------------------
// scanA: exclusive scan of bucketCnt -> baseA (region bases) + cursA.
// ---------------------------------------------------------------------------
__global__ __launch_bounds__(1024) void scanA(
    const int* __restrict__ bucketCnt, int* __restrict__ baseA,
    int* __restrict__ cursA) {
    __shared__ int wsum[16];
    const int t = threadIdx.x, lane = t & 63, w = t >> 6;
    const int v = (t < N_BUCKETS) ? bucketCnt[t] : 0;
    int sc = v;
#pragma unroll
    for (int off = 1; off < 64; off <<= 1) {
        int u = __shfl_up(sc, off);
        if (lane >= off) sc += u;
    }
    if (lane == 63) wsum[w] = sc;
    __syncthreads();
    if (w == 0) {
        int x = (lane < 16) ? wsum[lane] : 0;
#pragma unroll
        for (int off = 1; off < 16; off <<= 1) {
            int u = __shfl_up(x, off);
            if (lane >= off) x += u;
        }
        if (lane < 16) wsum[lane] = x;
    }
    __syncthreads();
    const int excl = sc - v + ((w > 0) ? wsum[w - 1] : 0);
    if (t < N_BUCKETS) { baseA[t] = excl; cursA[t] = excl; }
    if (t == N_BUCKETS - 1) baseA[N_BUCKETS] = excl + v;
}

// ---------------------------------------------------------------------------
// scatterB: in-LDS counting sort by bucket, then run-coalesced write-out.
// 4096 edges/block. Consecutive threads write consecutive global addresses
// within each per-bucket run => full 64B lines from a single XCD (kills the
// ~8x partial-line write amplification of per-record scatter).
// srec.x = col | (lrow << 24); srec.y = {dist bf16 | emN bf16}.
// ---------------------------------------------------------------------------
__global__ __launch_bounds__(256) void scatterB(
    const int* __restrict__ edges, const float* __restrict__ dist,
    const float* __restrict__ emask, int* __restrict__ cursA,
    uint2* __restrict__ srec) {
    __shared__ int lh[NB_PAD];            // per-bin count
    __shared__ int lofs[NB_PAD];          // per-bin local exclusive offset
    __shared__ int lb[NB_PAD];            // per-bin global base (reserved)
    __shared__ __align__(16) uint2 lsort[SC_EDGES];
    __shared__ unsigned short gb[SC_EDGES];  // bucket id per sorted slot
    __shared__ int wsum[4];

    const int tid = threadIdx.x;
    const int lane = tid & 63;
    const int w = tid >> 6;
    for (int i = tid; i < NB_PAD; i += 256) lh[i] = 0;
    __syncthreads();

    const int eb = blockIdx.x * SC_EDGES;
    const int total = min(SC_EDGES, N_EDGES - eb);

    // Phase A: load 16 edges/thread, histogram with rank capture.
    int rows[16], rank[16];
    uint2 recs[16];
    const int e0 = eb + tid * 16;
#pragma unroll
    for (int g = 0; g < 4; ++g) {
        const int e = e0 + g * 4;
        if (e + 4 <= N_EDGES) {
            const int4 rr = *(const int4*)(edges + e);
            const int4 cc = *(const int4*)(edges + N_EDGES + e);
            const float4 dd = *(const float4*)(dist + e);
            const float4 mm = *(const float4*)(emask + e);
            rows[g*4+0] = rr.x; rows[g*4+1] = rr.y; rows[g*4+2] = rr.z; rows[g*4+3] = rr.w;
            const int c4[4] = {cc.x, cc.y, cc.z, cc.w};
            const float d4[4] = {dd.x, dd.y, dd.z, dd.w};
            const float m4[4] = {mm.x, mm.y, mm.z, mm.w};
#pragma unroll
            for (int i = 0; i < 4; ++i) {
                const int ii = g * 4 + i;
                recs[ii].x = (unsigned)c4[i] | ((unsigned)(rows[ii] & 127) << 24);
                recs[ii].y = (unsigned)f2bf(d4[i]) |
                             ((unsigned)f2bf(m4[i] * NORM_INV) << 16);
                rank[ii] = atomicAdd(&lh[rows[ii] >> 7], 1);
            }
        } else {
#pragma unroll
            for (int i = 0; i < 4; ++i) {
                const int ii = g * 4 + i;
                const int ee = e + i;
                if (ee < N_EDGES) {
                    rows[ii] = edges[ee];
                    recs[ii].x = (unsigned)edges[N_EDGES + ee] |
                                 ((unsigned)(rows[ii] & 127) << 24);
                    recs[ii].y = (unsigned)f2bf(dist[ee]) |
                                 ((unsigned)f2bf(emask[ee] * NORM_INV) << 16);
                    rank[ii] = atomicAdd(&lh[rows[ii] >> 7], 1);
                } else {
                    rows[ii] = -1;
                }
            }
        }
    }
    __syncthreads();

    // Phase B: 4-bins/thread scan over 800 padded bins + global reservation.
    const int b0 = tid * 4;
    int c0 = 0, c1 = 0, c2 = 0, c3 = 0;
    if (b0 < NB_PAD) { c0 = lh[b0]; c1 = lh[b0+1]; c2 = lh[b0+2]; c3 = lh[b0+3]; }
    const int S = c0 + c1 + c2 + c3;
    int sc = S;
#pragma unroll
    for (int off = 1; off < 64; off <<= 1) {
        int u = __shfl_up(sc, off);
        if (lane >= off) sc += u;
    }
    if (lane == 63) wsum[w] = sc;
    __syncthreads();
    int wbase = 0;
    if (w > 0) wbase = wsum[0];
    if (w > 1) wbase += wsum[1];
    if (w > 2) wbase += wsum[2];
    int excl = sc - S + wbase;
    if (b0 < N_BUCKETS) {
        lofs[b0] = excl;
        lofs[b0+1] = excl + c0;
        lofs[b0+2] = excl + c0 + c1;
        lofs[b0+3] = excl + c0 + c1 + c2;
        if (c0) lb[b0]   = atomicAdd(&cursA[b0],   c0);
        if (c1 && b0+1 < N_BUCKETS) lb[b0+1] = atomicAdd(&cursA[b0+1], c1);
        if (c2 && b0+2 < N_BUCKETS) lb[b0+2] = atomicAdd(&cursA[b0+2], c2);
        if (c3 && b0+3 < N_BUCKETS) lb[b0+3] = atomicAdd(&cursA[b0+3], c3);
    }
    __syncthreads();

    // Phase C: place into LDS sorted by bucket.
#pragma unroll
    for (int i = 0; i < 16; ++i) {
        if (rows[i] >= 0) {
            const int bk = rows[i] >> 7;
            const int pos = lofs[bk] + rank[i];
            lsort[pos] = recs[i];
            gb[pos] = (unsigned short)bk;
        }
    }
    __syncthreads();

    // Phase D: run-coalesced write-out.
    for (int s = tid; s < total; s += 256) {
        const int bk = gb[s];
        const uint2 rc = lsort[s];
        srec[lb[bk] + (s - lofs[bk])] = rc;
    }
}

// ---------------------------------------------------------------------------
// agg_fused: one block (512 thr, 8 waves) per 128-row bucket.
// Phase 1: register-stage bucket records (lrow in rec.x>>24), LDS histogram.
// Phase 2: padded (x4) exclusive scan over 128 rows -> LDS row starts.
// Phase 3: counting-sort records into LDS (strip lrow; zero pad => att=0).
// Phase 4: each wave aggregates 16 rows (4 edge-slots x 16 feature-lanes),
//          then LN + silu.
// ---------------------------------------------------------------------------
__global__ __launch_bounds__(512, 4) void agg_fused(
    const int* __restrict__ baseA, const uint2* __restrict__ srec,
    const unsigned short* __restrict__ xv, const unsigned short* __restrict__ u_bf,
    const float4* __restrict__ tab, const float* __restrict__ att_b2,
    const float* __restrict__ ln_g, const float* __restrict__ ln_b,
    float* __restrict__ out) {
    __shared__ __align__(16) uint2 lrecs[CAP + 16];
    __shared__ int hist[128];
    __shared__ int rst[129];
    __shared__ int cur[128];
    __shared__ int wtot;

    const int b = blockIdx.x;
    const int tid = threadIdx.x;
    const int lane = tid & 63;
    const int wv = tid >> 6;
    const int s0g = baseA[b];
    const int cnt = baseA[b + 1] - s0g;

    if (tid < 128) hist[tid] = 0;
    __syncthreads();

    // Phase 1: register staging + histogram (statically indexed regs).
    uint2 rec0, rec1, rec2, rec3, rec4;
    int lr0 = -1, lr1 = -1, lr2 = -1, lr3 = -1, lr4 = -1;
    {
        int idx = tid;
        if (idx < cnt) { rec0 = srec[s0g + idx]; lr0 = (int)(rec0.x >> 24); rec0.x &= 0x00FFFFFFu; atomicAdd(&hist[lr0], 1); }
        idx += 512;
        if (idx < cnt) { rec1 = srec[s0g + idx]; lr1 = (int)(rec1.x >> 24); rec1.x &= 0x00FFFFFFu; atomicAdd(&hist[lr1], 1); }
        idx += 512;
        if (idx < cnt) { rec2 = srec[s0g + idx]; lr2 = (int)(rec2.x >> 24); rec2.x &= 0x00FFFFFFu; atomicAdd(&hist[lr2], 1); }
        idx += 512;
        if (idx < cnt) { rec3 = srec[s0g + idx]; lr3 = (int)(rec3.x >> 24); rec3.x &= 0x00FFFFFFu; atomicAdd(&hist[lr3], 1); }
        idx += 512;
        if (idx < cnt) { rec4 = srec[s0g + idx]; lr4 = (int)(rec4.x >> 24); rec4.x &= 0x00FFFFFFu; atomicAdd(&hist[lr4], 1); }
    }
    __syncthreads();

    // Phase 2: padded scan over 128 rows.
    int c = 0, p = 0, sc = 0;
    if (tid < 128) {
        c = hist[tid];
        p = (c + 3) & ~3;
        sc = p;
#pragma unroll
        for (int off = 1; off < 64; off <<= 1) {
            int u = __shfl_up(sc, off);
            if (lane >= off) sc += u;
        }
        if (tid == 63) wtot = sc;
    }
    __syncthreads();
    if (tid < 128) {
        if (tid >= 64) sc += wtot;
        const int excl = sc - p;
        rst[tid] = excl;
        cur[tid] = excl;
        uint2 z; z.x = 0; z.y = 0;
        for (int i = c; i < p; ++i) lrecs[excl + i] = z;
        if (tid == 127) {
            rst[128] = excl + p;
            for (int i = 0; i < 16; ++i) lrecs[excl + p + i] = z;
        }
    }
    __syncthreads();

    // Phase 3: counting-sort into LDS.
    if (lr0 >= 0) lrecs[atomicAdd(&cur[lr0], 1)] = rec0;
    if (lr1 >= 0) lrecs[atomicAdd(&cur[lr1], 1)] = rec1;
    if (lr2 >= 0) lrecs[atomicAdd(&cur[lr2], 1)] = rec2;
    if (lr3 >= 0) lrecs[atomicAdd(&cur[lr3], 1)] = rec3;
    if (lr4 >= 0) lrecs[atomicAdd(&cur[lr4], 1)] = rec4;
    __syncthreads();

    // Phase 4: aggregation. Wave wv handles local rows wv, wv+8, ..., wv+120.
    const int j = lane & 15;
    const int sl = lane >> 4;
    const float4 t0 = tab[j], t1 = tab[j + 16], t2 = tab[j + 32], t3 = tab[j + 48];
    const float b2L = att_b2[0] * L2E;
    const float gg = ln_g[lane], bb = ln_b[lane];
    const unsigned* xvu = (const unsigned*)xv;

#pragma unroll 1
    for (int k = 0; k < 16; ++k) {
        const int lrw = wv + 8 * k;
        const int r = b * 128 + lrw;
        if (r >= N_NODES) break;

        const uint2 uu = *(const uint2*)(u_bf + (size_t)r * 64 + j * 4);
        const float base0 = __uint_as_float(uu.x << 16) + t0.z;
        const float base1 = __uint_as_float(uu.x & 0xffff0000u) + t1.z;
        const float base2 = __uint_as_float(uu.y << 16) + t2.z;
        const float base3 = __uint_as_float(uu.y & 0xffff0000u) + t3.z;

        const int s0 = rst[lrw];
        const int e1 = rst[lrw + 1];

        float a0 = 0.f, a1 = 0.f, a2 = 0.f, a3 = 0.f;
        if (e1 > s0) {
            uint2 recA = lrecs[s0 + sl];
            uint4 xvA = *(const uint4*)(xvu + (size_t)recA.x * 64 + j * 4);
            for (int e = s0; e < e1; e += 4) {
                const uint2 recB = lrecs[e + 4 + sl];
                const uint4 xvB = *(const uint4*)(xvu + (size_t)recB.x * 64 + j * 4);

                const float dist = __uint_as_float(recA.y << 16);
                const float emN = __uint_as_float(recA.y & 0xffff0000u);
                const float x0 = __uint_as_float(xvA.x << 16);
                const float x1 = __uint_as_float(xvA.x & 0xffff0000u);
                const float x2 = __uint_as_float(xvA.y << 16);
                const float x3 = __uint_as_float(xvA.y & 0xffff0000u);
                const float v0 = __uint_as_float(xvA.z << 16);
                const float v1 = __uint_as_float(xvA.z & 0xffff0000u);
                const float v2 = __uint_as_float(xvA.w << 16);
                const float v3 = __uint_as_float(xvA.w & 0xffff0000u);
                float pv = 0.f, pre, sg;
                pre = fmaf(dist, t0.y, base0) + v0;
                sg = __builtin_amdgcn_rcpf(1.f + __builtin_amdgcn_exp2f(-pre));
                pv = fmaf(pre * sg, t0.x, pv);
                pre = fmaf(dist, t1.y, base1) + v1;
                sg = __builtin_amdgcn_rcpf(1.f + __builtin_amdgcn_exp2f(-pre));
                pv = fmaf(pre * sg, t1.x, pv);
                pre = fmaf(dist, t2.y, base2) + v2;
                sg = __builtin_amdgcn_rcpf(1.f + __builtin_amdgcn_exp2f(-pre));
                pv = fmaf(pre * sg, t2.x, pv);
                pre = fmaf(dist, t3.y, base3) + v3;
                sg = __builtin_amdgcn_rcpf(1.f + __builtin_amdgcn_exp2f(-pre));
                pv = fmaf(pre * sg, t3.x, pv);
                pv += __shfl_xor(pv, 1); pv += __shfl_xor(pv, 2);
                pv += __shfl_xor(pv, 4); pv += __shfl_xor(pv, 8);
                const float sp = fmaf(pv, L2E, b2L);
                const float att =
                    emN * __builtin_amdgcn_rcpf(1.f + __builtin_amdgcn_exp2f(-sp));
                a0 = fmaf(att, x0, a0); a1 = fmaf(att, x1, a1);
                a2 = fmaf(att, x2, a2); a3 = fmaf(att, x3, a3);
                recA = recB; xvA = xvB;
            }
        }
        a0 += __shfl_xor(a0, 16); a0 += __shfl_xor(a0, 32);
        a1 += __shfl_xor(a1, 16); a1 += __shfl_xor(a1, 32);
        a2 += __shfl_xor(a2, 16); a2 += __shfl_xor(a2, 32);
        a3 += __shfl_xor(a3, 16); a3 += __shfl_xor(a3, 32);

        const uint2 xr = *(const uint2*)(xvu + (size_t)r * 64 + j * 4);
        const float o0 = __uint_as_float(xr.x << 16) + a0;
        const float o1 = __uint_as_float(xr.x & 0xffff0000u) + a1;
        const float o2 = __uint_as_float(xr.y << 16) + a2;
        const float o3 = __uint_as_float(xr.y & 0xffff0000u) + a3;

        float ssum = o0 + o1 + o2 + o3;
        ssum += __shfl_xor(ssum, 1); ssum += __shfl_xor(ssum, 2);
        ssum += __shfl_xor(ssum, 4); ssum += __shfl_xor(ssum, 8);
        const float mu = ssum * (1.f / 64.f);
        const float d0 = o0 - mu, d1 = o1 - mu, d2 = o2 - mu, d3 = o3 - mu;
        float vs = d0 * d0 + d1 * d1 + d2 * d2 + d3 * d3;
        vs += __shfl_xor(vs, 1); vs += __shfl_xor(vs, 2);
        vs += __shfl_xor(vs, 4); vs += __shfl_xor(vs, 8);
        const float rstd = rsqrtf(vs * (1.f / 64.f) + LN_EPS);

        const float dk = (sl == 0) ? d0 : (sl == 1) ? d1 : (sl == 2) ? d2 : d3;
        const float y = fmaf(dk * rstd, gg, bb);
        out[(size_t)r * 64 + lane] =
            y * __builtin_amdgcn_rcpf(1.f + __builtin_amdgcn_exp2f(-y * L2E));
    }
}

extern "C" void kernel_launch(void* const* d_in, const int* in_sizes, int n_in,
                              void* d_out, int out_size, void* d_ws, size_t ws_size,
                              hipStream_t stream) {
    const float* h      = (const float*)d_in[0];
    const float* dist   = (const float*)d_in[1];
    const int*   edges  = (const int*)d_in[2];
    const float* emask  = (const float*)d_in[4];
    const float* W_lin  = (const float*)d_in[5];
    const float* b_lin  = (const float*)d_in[6];
    const float* att_W1 = (const float*)d_in[7];
    const float* att_b1 = (const float*)d_in[8];
    const float* att_W2 = (const float*)d_in[9];
    const float* att_b2 = (const float*)d_in[10];
    const float* ln_g   = (const float*)d_in[11];
    const float* ln_b   = (const float*)d_in[12];
    float* out = (float*)d_out;

    char* ws = (char*)d_ws;
    unsigned short* xv   = (unsigned short*)ws;                  // 25,600,000
    unsigned short* u_bf = (unsigned short*)(ws + 25600000);     // 12,800,000
    uint2* srec          = (uint2*)(ws + 38400000);              //  8,000,000
    int* bucketCnt       = (int*)(ws + 46400000);                //  3,200
    int* baseA           = (int*)(ws + 46403200);                //  3,200
    int* cursA           = (int*)(ws + 46406400);                //  3,200
    float4* tab          = (float4*)(ws + 46409600);             //  1,024
    short8* whi          = (short8*)(ws + 46410624);             //  8,192
    short8* wlo          = (short8*)(ws + 46418816);             //  8,192
    short8* wa           = (short8*)(ws + 46427008);             //  8,192
    short8* wb           = (short8*)(ws + 46435200);             //  8,192

    hipMemsetAsync(bucketCnt, 0, N_BUCKETS * sizeof(int), stream);
    prep_frags<<<1, 256, 0, stream>>>(W_lin, att_W1, att_b1, att_W2,
                                      whi, wlo, wa, wb, tab);
    proj_hist<<<PROJ_BLOCKS + HISTB, 256, 0, stream>>>(
        h, b_lin, whi, wlo, wa, wb, edges, bucketCnt, xv, u_bf);
    scanA<<<1, 1024, 0, stream>>>(bucketCnt, baseA, cursA);
    scatterB<<<SC_BLOCKS, 256, 0, stream>>>(edges, dist, emask, cursA, srec);
    agg_fused<<<N_BUCKETS, 512, 0, stream>>>(baseA, srec, xv, u_bf,
                                             tab, att_b2, ln_g, ln_b, out);
}

// Round 4
// 211.506 us; speedup vs baseline: 1.3306x; 1.1011x over previous
//
#include <hip/hip_runtime.h>
#include <hip/hip_bf16.h>

#define N_NODES 100000
#define N_EDGES 1000000
#define DIM 64
#define NORM_INV 0.01f
#define LN_EPS 1e-5f
#define N_TILES 6250          // N_NODES/16
#define PROJ_BLOCKS 1563      // ceil(6250/4)
#define N_BUCKETS 782         // ceil(100000/128), 128 rows per bucket
#define NB_PAD 800            // padded bin count for 4-per-thread scan
#define SC_EDGES 4096         // edges per scatter slice
#define SC_BLOCKS 245         // ceil(1e6/4096)
#define OFS_STRIDE 784        // ints per ofsT row (783 used, padded)
#define L2E 1.4426950408889634f
#define LN2 0.6931471805599453f
#define CAP 2560              // LDS record capacity/bucket

typedef __attribute__((ext_vector_type(8))) short short8;
typedef __attribute__((ext_vector_type(4))) float f32x4;

__device__ __forceinline__ unsigned short f2bf(float f) {
    union { float f; unsigned u; } x; x.f = f;
    unsigned r = x.u + 0x7FFFu + ((x.u >> 16) & 1u);
    return (unsigned short)(r >> 16);
}
__device__ __forceinline__ float bf2f(unsigned short s) {
    union { unsigned u; float f; } x; x.u = ((unsigned)s) << 16; return x.f;
}

// ---------------------------------------------------------------------------
// P0: precompute MFMA weight fragments + per-feature epilogue table.
// tab[f] = {w2[f]*ln2, w1c[f]*log2e, b1[f]*log2e, 0}
// ---------------------------------------------------------------------------
__global__ __launch_bounds__(256) void prep_frags(
    const float* __restrict__ W, const float* __restrict__ att_W1,
    const float* __restrict__ att_b1, const float* __restrict__ att_W2,
    short8* __restrict__ whi, short8* __restrict__ wlo,
    short8* __restrict__ wa, short8* __restrict__ wb,
    float4* __restrict__ tab) {
    const int l = threadIdx.x & 63;
    const int nt = threadIdx.x >> 6;
    const int c = l & 15, q = l >> 4;
    const int n = nt * 16 + c;
#pragma unroll
    for (int ks = 0; ks < 2; ++ks) {
        const int k0 = ks * 32 + q * 8;
        short8 hi8, lo8, a8, b8;
#pragma unroll
        for (int jj = 0; jj < 8; ++jj) {
            float w = W[n * 64 + k0 + jj];
            unsigned short hh = f2bf(w);
            hi8[jj] = (short)hh;
            lo8[jj] = (short)f2bf(w - bf2f(hh));
            a8[jj] = (short)f2bf(att_W1[n * 129 + k0 + jj]);
            b8[jj] = (short)f2bf(att_W1[n * 129 + 64 + k0 + jj]);
        }
        const int idx = (nt * 2 + ks) * 64 + l;
        whi[idx] = hi8; wlo[idx] = lo8; wa[idx] = a8; wb[idx] = b8;
    }
    if (threadIdx.x < 64) {
        const int f = threadIdx.x;
        tab[f] = make_float4(att_W2[f] * LN2, att_W1[f * 129 + 128] * L2E,
                             att_b1[f] * L2E, 0.f);
    }
}

// ---------------------------------------------------------------------------
// proj_scatter fat kernel — no global atomics anywhere.
// blocks [0,PROJ_BLOCKS): MFMA projection, 1 tile/wave.
//   x = h@W^T + b (hi/lo bf16 split), u = x@W1a^T * log2e, v = x@W1b^T * log2e
// blocks [PROJ_BLOCKS, +SC_BLOCKS): fixed-slice scatter. Each block owns
//   srec[blk*4096 .. +4096): loads 4096 edges, LDS counting-sort by bucket,
//   writes its slice fully coalesced + one ofsT row (local bucket offsets,
//   row[782] = slice length sentinel). srec.x = col | lrow<<24.
// ---------------------------------------------------------------------------
__global__ __launch_bounds__(256) void proj_scatter(
    const float* __restrict__ h, const float* __restrict__ bl,
    const short8* __restrict__ whi, const short8* __restrict__ wlo,
    const short8* __restrict__ wa, const short8* __restrict__ wb,
    const int* __restrict__ edges, const float* __restrict__ dist,
    const float* __restrict__ emask,
    uint2* __restrict__ srec, int* __restrict__ ofsT,
    unsigned short* __restrict__ xv, unsigned short* __restrict__ u_bf) {
    __shared__ __align__(16) char pool[39168];
    __shared__ int wsum[4];

    if (blockIdx.x >= PROJ_BLOCKS) {
        // ------------------- scatter personality -------------------
        int* lh = (int*)pool;                       // [NB_PAD]
        int* lofs = (int*)pool + NB_PAD;            // [NB_PAD]
        uint2* lsort = (uint2*)(pool + 6400);       // [SC_EDGES]
        const int blk = blockIdx.x - PROJ_BLOCKS;
        const int tid = threadIdx.x;
        const int lane = tid & 63;
        const int w = tid >> 6;
        for (int i = tid; i < NB_PAD; i += 256) lh[i] = 0;
        __syncthreads();

        const int eb = blk * SC_EDGES;
        const int total = min(SC_EDGES, N_EDGES - eb);

        // Phase A: load 16 edges/thread, histogram with rank capture.
        int rows[16], rank[16];
        uint2 recs[16];
        const int e0 = eb + tid * 16;
#pragma unroll
        for (int g = 0; g < 4; ++g) {
            const int e = e0 + g * 4;
            if (e + 4 <= N_EDGES) {
                const int4 rr = *(const int4*)(edges + e);
                const int4 cc = *(const int4*)(edges + N_EDGES + e);
                const float4 dd = *(const float4*)(dist + e);
                const float4 mm = *(const float4*)(emask + e);
                rows[g*4+0] = rr.x; rows[g*4+1] = rr.y; rows[g*4+2] = rr.z; rows[g*4+3] = rr.w;
                const int c4[4] = {cc.x, cc.y, cc.z, cc.w};
                const float d4[4] = {dd.x, dd.y, dd.z, dd.w};
                const float m4[4] = {mm.x, mm.y, mm.z, mm.w};
#pragma unroll
                for (int i = 0; i < 4; ++i) {
                    const int ii = g * 4 + i;
                    recs[ii].x = (unsigned)c4[i] | ((unsigned)(rows[ii] & 127) << 24);
                    recs[ii].y = (unsigned)f2bf(d4[i]) |
                                 ((unsigned)f2bf(m4[i] * NORM_INV) << 16);
                    rank[ii] = atomicAdd(&lh[rows[ii] >> 7], 1);
                }
            } else {
#pragma unroll
                for (int i = 0; i < 4; ++i) {
                    const int ii = g * 4 + i;
                    const int ee = e + i;
                    if (ee < N_EDGES) {
                        rows[ii] = edges[ee];
                        recs[ii].x = (unsigned)edges[N_EDGES + ee] |
                                     ((unsigned)(rows[ii] & 127) << 24);
                        recs[ii].y = (unsigned)f2bf(dist[ee]) |
                                     ((unsigned)f2bf(emask[ee] * NORM_INV) << 16);
                        rank[ii] = atomicAdd(&lh[rows[ii] >> 7], 1);
                    } else {
                        rows[ii] = -1;
                    }
                }
            }
        }
        __syncthreads();

        // Phase B: 4-bins/thread exclusive scan over 800 padded bins.
        const int b0 = tid * 4;
        int c0 = 0, c1 = 0, c2 = 0, c3 = 0;
        if (b0 < NB_PAD) { c0 = lh[b0]; c1 = lh[b0+1]; c2 = lh[b0+2]; c3 = lh[b0+3]; }
        const int S = c0 + c1 + c2 + c3;
        int sc = S;
#pragma unroll
        for (int off = 1; off < 64; off <<= 1) {
            int u = __shfl_up(sc, off);
            if (lane >= off) sc += u;
        }
        if (lane == 63) wsum[w] = sc;
        __syncthreads();
        int wbase = 0;
        if (w > 0) wbase = wsum[0];
        if (w > 1) wbase += wsum[1];
        if (w > 2) wbase += wsum[2];
        const int excl = sc - S + wbase;
        if (b0 < NB_PAD) {
            lofs[b0] = excl;
            lofs[b0+1] = excl + c0;
            lofs[b0+2] = excl + c0 + c1;
            lofs[b0+3] = excl + c0 + c1 + c2;
        }
        __syncthreads();

        // Phase C: place into LDS sorted by bucket.
#pragma unroll
        for (int i = 0; i < 16; ++i) {
            if (rows[i] >= 0) {
                const int bk = rows[i] >> 7;
                lsort[lofs[bk] + rank[i]] = recs[i];
            }
        }
        __syncthreads();

        // Phase D: fully-coalesced slice write-out + ofsT row.
        for (int s = tid; s < total; s += 256)
            srec[(size_t)blk * SC_EDGES + s] = lsort[s];
        for (int b = tid; b < 783; b += 256)
            ofsT[blk * OFS_STRIDE + b] = lofs[b];   // lofs[782] == total
        return;
    }

    // ------------------- projection personality -------------------
    const int lane = threadIdx.x & 63;
    const int wv = threadIdx.x >> 6;
    const int c = lane & 15, q = lane >> 4;
    const int tile = blockIdx.x * 4 + wv;
    if (tile >= N_TILES) return;
    const int n0 = tile * 16;

    short8 Whi[4][2], Wlo[4][2], Wa[4][2], Wb[4][2];
    float bias[4];
#pragma unroll
    for (int nt = 0; nt < 4; ++nt) {
        bias[nt] = bl[nt * 16 + c];
#pragma unroll
        for (int ks = 0; ks < 2; ++ks) {
            const int idx = (nt * 2 + ks) * 64 + lane;
            Whi[nt][ks] = whi[idx]; Wlo[nt][ks] = wlo[idx];
            Wa[nt][ks] = wa[idx];   Wb[nt][ks] = wb[idx];
        }
    }

    short8 Ahi[2], Alo[2];
#pragma unroll
    for (int ks = 0; ks < 2; ++ks) {
        const float* hp = h + (size_t)(n0 + c) * 64 + ks * 32 + q * 8;
        f32x4 p0 = *(const f32x4*)hp;
        f32x4 p1 = *(const f32x4*)(hp + 4);
        short8 hi8, lo8;
#pragma unroll
        for (int jj = 0; jj < 4; ++jj) {
            unsigned short hh = f2bf(p0[jj]);
            hi8[jj] = (short)hh; lo8[jj] = (short)f2bf(p0[jj] - bf2f(hh));
            unsigned short h2 = f2bf(p1[jj]);
            hi8[4 + jj] = (short)h2; lo8[4 + jj] = (short)f2bf(p1[jj] - bf2f(h2));
        }
        Ahi[ks] = hi8; Alo[ks] = lo8;
    }

    f32x4 xacc[4] = {{0,0,0,0},{0,0,0,0},{0,0,0,0},{0,0,0,0}};
#pragma unroll
    for (int ks = 0; ks < 2; ++ks)
#pragma unroll
        for (int nt = 0; nt < 4; ++nt) {
            xacc[nt] = __builtin_amdgcn_mfma_f32_16x16x32_bf16(Ahi[ks], Whi[nt][ks], xacc[nt], 0, 0, 0);
            xacc[nt] = __builtin_amdgcn_mfma_f32_16x16x32_bf16(Ahi[ks], Wlo[nt][ks], xacc[nt], 0, 0, 0);
            xacc[nt] = __builtin_amdgcn_mfma_f32_16x16x32_bf16(Alo[ks], Whi[nt][ks], xacc[nt], 0, 0, 0);
        }

    unsigned short* lw = (unsigned short*)pool + wv * (16 * 72);
#pragma unroll
    for (int r = 0; r < 4; ++r) {
        const int node = n0 + q * 4 + r;
        unsigned short xb[4];
#pragma unroll
        for (int nt = 0; nt < 4; ++nt) {
            unsigned short v16 = f2bf(xacc[nt][r] + bias[nt]);
            xb[nt] = v16;
            lw[(q * 4 + r) * 72 + nt * 16 + c] = v16;
        }
        uint2 pk;
        pk.x = (unsigned)xb[0] | ((unsigned)xb[1] << 16);
        pk.y = (unsigned)xb[2] | ((unsigned)xb[3] << 16);
        *(uint2*)(xv + (size_t)node * 128 + c * 8) = pk;
    }

    short8 Ax[2];
#pragma unroll
    for (int ks = 0; ks < 2; ++ks)
        Ax[ks] = *(const short8*)&lw[c * 72 + ks * 32 + q * 8];

    f32x4 uacc[4] = {{0,0,0,0},{0,0,0,0},{0,0,0,0},{0,0,0,0}};
    f32x4 vacc[4] = {{0,0,0,0},{0,0,0,0},{0,0,0,0},{0,0,0,0}};
#pragma unroll
    for (int ks = 0; ks < 2; ++ks)
#pragma unroll
        for (int nt = 0; nt < 4; ++nt) {
            uacc[nt] = __builtin_amdgcn_mfma_f32_16x16x32_bf16(Ax[ks], Wa[nt][ks], uacc[nt], 0, 0, 0);
            vacc[nt] = __builtin_amdgcn_mfma_f32_16x16x32_bf16(Ax[ks], Wb[nt][ks], vacc[nt], 0, 0, 0);
        }
#pragma unroll
    for (int r = 0; r < 4; ++r) {
        const int node = n0 + q * 4 + r;
        uint2 pu;
        pu.x = (unsigned)f2bf(uacc[0][r] * L2E) | ((unsigned)f2bf(uacc[1][r] * L2E) << 16);
        pu.y = (unsigned)f2bf(uacc[2][r] * L2E) | ((unsigned)f2bf(uacc[3][r] * L2E) << 16);
        *(uint2*)(u_bf + (size_t)node * 64 + c * 4) = pu;
        uint2 pk;
        pk.x = (unsigned)f2bf(vacc[0][r] * L2E) | ((unsigned)f2bf(vacc[1][r] * L2E) << 16);
        pk.y = (unsigned)f2bf(vacc[2][r] * L2E) | ((unsigned)f2bf(vacc[3][r] * L2E) << 16);
        *(uint2*)(xv + (size_t)node * 128 + c * 8 + 4) = pk;
    }
}

// ---------------------------------------------------------------------------
// agg_fused: one block (512 thr, 8 waves) per 128-row bucket.
// Phase 1: gather bucket b's records from the 245 slice-extents (thread t
//          owns slice t; extent from ofsT[t][b]..ofsT[t][b+1]); LDS histogram.
// Phase 2: padded (x4) exclusive scan over 128 rows -> LDS row starts.
// Phase 3: re-read extents, counting-sort records into LDS (strip lrow;
//          zero pad => att=0). srec extents are L2-hot on second pass.
// Phase 4: each wave aggregates 16 rows (4 edge-slots x 16 feature-lanes),
//          then LN + silu.
// ---------------------------------------------------------------------------
__global__ __launch_bounds__(512, 4) void agg_fused(
    const uint2* __restrict__ srec, const int* __restrict__ ofsT,
    const unsigned short* __restrict__ xv, const unsigned short* __restrict__ u_bf,
    const float4* __restrict__ tab, const float* __restrict__ att_b2,
    const float* __restrict__ ln_g, const float* __restrict__ ln_b,
    float* __restrict__ out) {
    __shared__ __align__(16) uint2 lrecs[CAP + 16];
    __shared__ int hist[128];
    __shared__ int rst[129];
    __shared__ int cur[128];
    __shared__ int wtot;

    const int b = blockIdx.x;
    const int tid = threadIdx.x;
    const int lane = tid & 63;
    const int wv = tid >> 6;

    if (tid < 128) hist[tid] = 0;
    __syncthreads();

    // Phase 1: slice-gather histogram (keys only).
    int st = 0, en = 0;
    if (tid < SC_BLOCKS) {
        st = ofsT[tid * OFS_STRIDE + b];
        en = ofsT[tid * OFS_STRIDE + b + 1];
        const unsigned* sx = (const unsigned*)srec;
        const size_t gb = (size_t)tid * SC_EDGES;
        for (int i = st; i < en; ++i)
            atomicAdd(&hist[sx[2 * (gb + i)] >> 24], 1);
    }
    __syncthreads();

    // Phase 2: padded scan over 128 rows.
    int c = 0, p = 0, sc = 0;
    if (tid < 128) {
        c = hist[tid];
        p = (c + 3) & ~3;
        sc = p;
#pragma unroll
        for (int off = 1; off < 64; off <<= 1) {
            int u = __shfl_up(sc, off);
            if (lane >= off) sc += u;
        }
        if (tid == 63) wtot = sc;
    }
    __syncthreads();
    if (tid < 128) {
        if (tid >= 64) sc += wtot;
        const int excl = sc - p;
        rst[tid] = excl;
        cur[tid] = excl;
        uint2 z; z.x = 0; z.y = 0;
        for (int i = c; i < p; ++i) lrecs[excl + i] = z;
        if (tid == 127) {
            rst[128] = excl + p;
            for (int i = 0; i < 16; ++i) lrecs[excl + p + i] = z;
        }
    }
    __syncthreads();

    // Phase 3: re-read extents, counting-sort into LDS.
    if (tid < SC_BLOCKS) {
        const size_t gb = (size_t)tid * SC_EDGES;
        for (int i = st; i < en; ++i) {
            uint2 rec = srec[gb + i];
            const int lr = (int)(rec.x >> 24);
            rec.x &= 0x00FFFFFFu;
            lrecs[atomicAdd(&cur[lr], 1)] = rec;
        }
    }
    __syncthreads();

    // Phase 4: aggregation. Wave wv handles local rows wv, wv+8, ..., wv+120.
    const int j = lane & 15;
    const int sl = lane >> 4;
    const float4 t0 = tab[j], t1 = tab[j + 16], t2 = tab[j + 32], t3 = tab[j + 48];
    const float b2L = att_b2[0] * L2E;
    const float gg = ln_g[lane], bb = ln_b[lane];
    const unsigned* xvu = (const unsigned*)xv;

#pragma unroll 1
    for (int k = 0; k < 16; ++k) {
        const int lrw = wv + 8 * k;
        const int r = b * 128 + lrw;
        if (r >= N_NODES) break;

        const uint2 uu = *(const uint2*)(u_bf + (size_t)r * 64 + j * 4);
        const float base0 = __uint_as_float(uu.x << 16) + t0.z;
        const float base1 = __uint_as_float(uu.x & 0xffff0000u) + t1.z;
        const float base2 = __uint_as_float(uu.y << 16) + t2.z;
        const float base3 = __uint_as_float(uu.y & 0xffff0000u) + t3.z;

        const int s0 = rst[lrw];
        const int e1 = rst[lrw + 1];

        float a0 = 0.f, a1 = 0.f, a2 = 0.f, a3 = 0.f;
        if (e1 > s0) {
            uint2 recA = lrecs[s0 + sl];
            uint4 xvA = *(const uint4*)(xvu + (size_t)recA.x * 64 + j * 4);
            for (int e = s0; e < e1; e += 4) {
                const uint2 recB = lrecs[e + 4 + sl];
                const uint4 xvB = *(const uint4*)(xvu + (size_t)recB.x * 64 + j * 4);

                const float dist = __uint_as_float(recA.y << 16);
                const float emN = __uint_as_float(recA.y & 0xffff0000u);
                const float x0 = __uint_as_float(xvA.x << 16);
                const float x1 = __uint_as_float(xvA.x & 0xffff0000u);
                const float x2 = __uint_as_float(xvA.y << 16);
                const float x3 = __uint_as_float(xvA.y & 0xffff0000u);
                const float v0 = __uint_as_float(xvA.z << 16);
                const float v1 = __uint_as_float(xvA.z & 0xffff0000u);
                const float v2 = __uint_as_float(xvA.w << 16);
                const float v3 = __uint_as_float(xvA.w & 0xffff0000u);
                float pv = 0.f, pre, sg;
                pre = fmaf(dist, t0.y, base0) + v0;
                sg = __builtin_amdgcn_rcpf(1.f + __builtin_amdgcn_exp2f(-pre));
                pv = fmaf(pre * sg, t0.x, pv);
                pre = fmaf(dist, t1.y, base1) + v1;
                sg = __builtin_amdgcn_rcpf(1.f + __builtin_amdgcn_exp2f(-pre));
                pv = fmaf(pre * sg, t1.x, pv);
                pre = fmaf(dist, t2.y, base2) + v2;
                sg = __builtin_amdgcn_rcpf(1.f + __builtin_amdgcn_exp2f(-pre));
                pv = fmaf(pre * sg, t2.x, pv);
                pre = fmaf(dist, t3.y, base3) + v3;
                sg = __builtin_amdgcn_rcpf(1.f + __builtin_amdgcn_exp2f(-pre));
                pv = fmaf(pre * sg, t3.x, pv);
                pv += __shfl_xor(pv, 1); pv += __shfl_xor(pv, 2);
                pv += __shfl_xor(pv, 4); pv += __shfl_xor(pv, 8);
                const float sp = fmaf(pv, L2E, b2L);
                const float att =
                    emN * __builtin_amdgcn_rcpf(1.f + __builtin_amdgcn_exp2f(-sp));
                a0 = fmaf(att, x0, a0); a1 = fmaf(att, x1, a1);
                a2 = fmaf(att, x2, a2); a3 = fmaf(att, x3, a3);
                recA = recB; xvA = xvB;
            }
        }
        a0 += __shfl_xor(a0, 16); a0 += __shfl_xor(a0, 32);
        a1 += __shfl_xor(a1, 16); a1 += __shfl_xor(a1, 32);
        a2 += __shfl_xor(a2, 16); a2 += __shfl_xor(a2, 32);
        a3 += __shfl_xor(a3, 16); a3 += __shfl_xor(a3, 32);

        const uint2 xr = *(const uint2*)(xvu + (size_t)r * 64 + j * 4);
        const float o0 = __uint_as_float(xr.x << 16) + a0;
        const float o1 = __uint_as_float(xr.x & 0xffff0000u) + a1;
        const float o2 = __uint_as_float(xr.y << 16) + a2;
        const float o3 = __uint_as_float(xr.y & 0xffff0000u) + a3;

        float ssum = o0 + o1 + o2 + o3;
        ssum += __shfl_xor(ssum, 1); ssum += __shfl_xor(ssum, 2);
        ssum += __shfl_xor(ssum, 4); ssum += __shfl_xor(ssum, 8);
        const float mu = ssum * (1.f / 64.f);
        const float d0 = o0 - mu, d1 = o1 - mu, d2 = o2 - mu, d3 = o3 - mu;
        float vs = d0 * d0 + d1 * d1 + d2 * d2 + d3 * d3;
        vs += __shfl_xor(vs, 1); vs += __shfl_xor(vs, 2);
        vs += __shfl_xor(vs, 4); vs += __shfl_xor(vs, 8);
        const float rstd = rsqrtf(vs * (1.f / 64.f) + LN_EPS);

        const float dk = (sl == 0) ? d0 : (sl == 1) ? d1 : (sl == 2) ? d2 : d3;
        const float y = fmaf(dk * rstd, gg, bb);
        out[(size_t)r * 64 + lane] =
            y * __builtin_amdgcn_rcpf(1.f + __builtin_amdgcn_exp2f(-y * L2E));
    }
}

extern "C" void kernel_launch(void* const* d_in, const int* in_sizes, int n_in,
                              void* d_out, int out_size, void* d_ws, size_t ws_size,
                              hipStream_t stream) {
    const float* h      = (const float*)d_in[0];
    const float* dist   = (const float*)d_in[1];
    const int*   edges  = (const int*)d_in[2];
    const float* emask  = (const float*)d_in[4];
    const float* W_lin  = (const float*)d_in[5];
    const float* b_lin  = (const float*)d_in[6];
    const float* att_W1 = (const float*)d_in[7];
    const float* att_b1 = (const float*)d_in[8];
    const float* att_W2 = (const float*)d_in[9];
    const float* att_b2 = (const float*)d_in[10];
    const float* ln_g   = (const float*)d_in[11];
    const float* ln_b   = (const float*)d_in[12];
    float* out = (float*)d_out;

    char* ws = (char*)d_ws;
    unsigned short* xv   = (unsigned short*)ws;                  // 25,600,000
    unsigned short* u_bf = (unsigned short*)(ws + 25600000);     // 12,800,000
    uint2* srec          = (uint2*)(ws + 38400000);              //  8,028,160 (245*4096*8)
    int* ofsT            = (int*)(ws + 46428160);                //    768,320 (245*784*4)
    float4* tab          = (float4*)(ws + 47196480);             //      1,024
    short8* whi          = (short8*)(ws + 47197504);             //      8,192
    short8* wlo          = (short8*)(ws + 47205696);             //      8,192
    short8* wa           = (short8*)(ws + 47213888);             //      8,192
    short8* wb           = (short8*)(ws + 47222080);             //      8,192

    prep_frags<<<1, 256, 0, stream>>>(W_lin, att_W1, att_b1, att_W2,
                                      whi, wlo, wa, wb, tab);
    proj_scatter<<<PROJ_BLOCKS + SC_BLOCKS, 256, 0, stream>>>(
        h, b_lin, whi, wlo, wa, wb, edges, dist, emask, srec, ofsT, xv, u_bf);
    agg_fused<<<N_BUCKETS, 512, 0, stream>>>(srec, ofsT, xv, u_bf,
                                             tab, att_b2, ln_g, ln_b, out);
}

// Round 5
// 201.007 us; speedup vs baseline: 1.4001x; 1.0522x over previous
//
#include <hip/hip_runtime.h>
#include <hip/hip_bf16.h>

#define N_NODES 100000
#define N_EDGES 1000000
#define DIM 64
#define NORM_INV 0.01f
#define LN_EPS 1e-5f
#define N_TILES 6250          // N_NODES/16
#define PROJ_BLOCKS 1563      // ceil(6250/4)
#define N_BUCKETS 782         // ceil(100000/128), 128 rows per bucket
#define NB_PAD 800            // padded bin count for 4-per-thread scan
#define SC_EDGES 4096         // edges per scatter slice
#define SC_BLOCKS 245         // ceil(1e6/4096)
#define OFS_STRIDE 784        // ints per ofsT row (783 used, padded)
#define L2E 1.4426950408889634f
#define LN2 0.6931471805599453f
#define CAP 2560              // LDS record capacity/bucket

typedef __attribute__((ext_vector_type(8))) short short8;
typedef __attribute__((ext_vector_type(4))) float f32x4;

__device__ __forceinline__ unsigned short f2bf(float f) {
    union { float f; unsigned u; } x; x.f = f;
    unsigned r = x.u + 0x7FFFu + ((x.u >> 16) & 1u);
    return (unsigned short)(r >> 16);
}
__device__ __forceinline__ float bf2f(unsigned short s) {
    union { unsigned u; float f; } x; x.u = ((unsigned)s) << 16; return x.f;
}

// ---------------------------------------------------------------------------
// P0: precompute MFMA weight fragments + per-feature epilogue table.
// tab[f] = {w2[f]*ln2, w1c[f]*log2e, b1[f]*log2e, 0}
// ---------------------------------------------------------------------------
__global__ __launch_bounds__(256) void prep_frags(
    const float* __restrict__ W, const float* __restrict__ att_W1,
    const float* __restrict__ att_b1, const float* __restrict__ att_W2,
    short8* __restrict__ whi, short8* __restrict__ wlo,
    short8* __restrict__ wa, short8* __restrict__ wb,
    float4* __restrict__ tab) {
    const int l = threadIdx.x & 63;
    const int nt = threadIdx.x >> 6;
    const int c = l & 15, q = l >> 4;
    const int n = nt * 16 + c;
#pragma unroll
    for (int ks = 0; ks < 2; ++ks) {
        const int k0 = ks * 32 + q * 8;
        short8 hi8, lo8, a8, b8;
#pragma unroll
        for (int jj = 0; jj < 8; ++jj) {
            float w = W[n * 64 + k0 + jj];
            unsigned short hh = f2bf(w);
            hi8[jj] = (short)hh;
            lo8[jj] = (short)f2bf(w - bf2f(hh));
            a8[jj] = (short)f2bf(att_W1[n * 129 + k0 + jj]);
            b8[jj] = (short)f2bf(att_W1[n * 129 + 64 + k0 + jj]);
        }
        const int idx = (nt * 2 + ks) * 64 + l;
        whi[idx] = hi8; wlo[idx] = lo8; wa[idx] = a8; wb[idx] = b8;
    }
    if (threadIdx.x < 64) {
        const int f = threadIdx.x;
        tab[f] = make_float4(att_W2[f] * LN2, att_W1[f * 129 + 128] * L2E,
                             att_b1[f] * L2E, 0.f);
    }
}

// ---------------------------------------------------------------------------
// proj_scatter fat kernel — no global atomics anywhere.
// blocks [0,PROJ_BLOCKS): MFMA projection, 1 tile/wave. Weight fragments are
//   staged in LDS once per block (frees ~128 VGPRs/wave -> higher occupancy).
//   LDS layout: [0:8K) whi, [8K:16K) wlo, [16K:24K) wa, [24K:32K) wb.
//   After phase-1 MFMAs + barrier, whi/wlo region is reused for lw staging.
// blocks [PROJ_BLOCKS, +SC_BLOCKS): fixed-slice scatter. Each block owns
//   srec[blk*4096 .. +4096): loads 4096 edges, LDS counting-sort by bucket,
//   writes its slice fully coalesced + one ofsT row (local bucket offsets,
//   row[782] = slice length sentinel). srec.x = col | lrow<<24.
// ---------------------------------------------------------------------------
__global__ __launch_bounds__(256) void proj_scatter(
    const float* __restrict__ h, const float* __restrict__ bl,
    const short8* __restrict__ whi, const short8* __restrict__ wlo,
    const short8* __restrict__ wa, const short8* __restrict__ wb,
    const int* __restrict__ edges, const float* __restrict__ dist,
    const float* __restrict__ emask,
    uint2* __restrict__ srec, int* __restrict__ ofsT,
    unsigned short* __restrict__ xv, unsigned short* __restrict__ u_bf) {
    __shared__ __align__(16) char pool[39168];
    __shared__ int wsum[4];

    if (blockIdx.x >= PROJ_BLOCKS) {
        // ------------------- scatter personality -------------------
        int* lh = (int*)pool;                       // [NB_PAD]
        int* lofs = (int*)pool + NB_PAD;            // [NB_PAD]
        uint2* lsort = (uint2*)(pool + 6400);       // [SC_EDGES]
        const int blk = blockIdx.x - PROJ_BLOCKS;
        const int tid = threadIdx.x;
        const int lane = tid & 63;
        const int w = tid >> 6;
        for (int i = tid; i < NB_PAD; i += 256) lh[i] = 0;
        __syncthreads();

        const int eb = blk * SC_EDGES;
        const int total = min(SC_EDGES, N_EDGES - eb);

        // Phase A: load 16 edges/thread, histogram with rank capture.
        int rows[16], rank[16];
        uint2 recs[16];
        const int e0 = eb + tid * 16;
#pragma unroll
        for (int g = 0; g < 4; ++g) {
            const int e = e0 + g * 4;
            if (e + 4 <= N_EDGES) {
                const int4 rr = *(const int4*)(edges + e);
                const int4 cc = *(const int4*)(edges + N_EDGES + e);
                const float4 dd = *(const float4*)(dist + e);
                const float4 mm = *(const float4*)(emask + e);
                rows[g*4+0] = rr.x; rows[g*4+1] = rr.y; rows[g*4+2] = rr.z; rows[g*4+3] = rr.w;
                const int c4[4] = {cc.x, cc.y, cc.z, cc.w};
                const float d4[4] = {dd.x, dd.y, dd.z, dd.w};
                const float m4[4] = {mm.x, mm.y, mm.z, mm.w};
#pragma unroll
                for (int i = 0; i < 4; ++i) {
                    const int ii = g * 4 + i;
                    recs[ii].x = (unsigned)c4[i] | ((unsigned)(rows[ii] & 127) << 24);
                    recs[ii].y = (unsigned)f2bf(d4[i]) |
                                 ((unsigned)f2bf(m4[i] * NORM_INV) << 16);
                    rank[ii] = atomicAdd(&lh[rows[ii] >> 7], 1);
                }
            } else {
#pragma unroll
                for (int i = 0; i < 4; ++i) {
                    const int ii = g * 4 + i;
                    const int ee = e + i;
                    if (ee < N_EDGES) {
                        rows[ii] = edges[ee];
                        recs[ii].x = (unsigned)edges[N_EDGES + ee] |
                                     ((unsigned)(rows[ii] & 127) << 24);
                        recs[ii].y = (unsigned)f2bf(dist[ee]) |
                                     ((unsigned)f2bf(emask[ee] * NORM_INV) << 16);
                        rank[ii] = atomicAdd(&lh[rows[ii] >> 7], 1);
                    } else {
                        rows[ii] = -1;
                    }
                }
            }
        }
        __syncthreads();

        // Phase B: 4-bins/thread exclusive scan over 800 padded bins.
        const int b0 = tid * 4;
        int c0 = 0, c1 = 0, c2 = 0, c3 = 0;
        if (b0 < NB_PAD) { c0 = lh[b0]; c1 = lh[b0+1]; c2 = lh[b0+2]; c3 = lh[b0+3]; }
        const int S = c0 + c1 + c2 + c3;
        int sc = S;
#pragma unroll
        for (int off = 1; off < 64; off <<= 1) {
            int u = __shfl_up(sc, off);
            if (lane >= off) sc += u;
        }
        if (lane == 63) wsum[w] = sc;
        __syncthreads();
        int wbase = 0;
        if (w > 0) wbase = wsum[0];
        if (w > 1) wbase += wsum[1];
        if (w > 2) wbase += wsum[2];
        const int excl = sc - S + wbase;
        if (b0 < NB_PAD) {
            lofs[b0] = excl;
            lofs[b0+1] = excl + c0;
            lofs[b0+2] = excl + c0 + c1;
            lofs[b0+3] = excl + c0 + c1 + c2;
        }
        __syncthreads();

        // Phase C: place into LDS sorted by bucket.
#pragma unroll
        for (int i = 0; i < 16; ++i) {
            if (rows[i] >= 0) {
                const int bk = rows[i] >> 7;
                lsort[lofs[bk] + rank[i]] = recs[i];
            }
        }
        __syncthreads();

        // Phase D: fully-coalesced slice write-out + ofsT row.
        for (int s = tid; s < total; s += 256)
            srec[(size_t)blk * SC_EDGES + s] = lsort[s];
        for (int b = tid; b < 783; b += 256)
            ofsT[blk * OFS_STRIDE + b] = lofs[b];   // lofs[782] == total
        return;
    }

    // ------------------- projection personality -------------------
    const int tid = threadIdx.x;
    // Cooperative weight stage: 32 KB global -> LDS (L2-hot source).
    {
        uint4* l4 = (uint4*)pool;
        const uint4* g0 = (const uint4*)whi;
        const uint4* g1 = (const uint4*)wlo;
        const uint4* g2 = (const uint4*)wa;
        const uint4* g3 = (const uint4*)wb;
        l4[tid]        = g0[tid];       l4[256 + tid]  = g0[256 + tid];
        l4[512 + tid]  = g1[tid];       l4[768 + tid]  = g1[256 + tid];
        l4[1024 + tid] = g2[tid];       l4[1280 + tid] = g2[256 + tid];
        l4[1536 + tid] = g3[tid];       l4[1792 + tid] = g3[256 + tid];
    }
    __syncthreads();
    const short8* Lwhi = (const short8*)pool;
    const short8* Lwlo = Lwhi + 512;
    const short8* Lwa  = Lwhi + 1024;
    const short8* Lwb  = Lwhi + 1536;

    const int lane = tid & 63;
    const int wv = tid >> 6;
    const int c = lane & 15, q = lane >> 4;
    const int tile = blockIdx.x * 4 + wv;
    const bool valid = (tile < N_TILES);
    const int n0 = valid ? tile * 16 : 0;

    float bias[4];
#pragma unroll
    for (int nt = 0; nt < 4; ++nt) bias[nt] = bl[nt * 16 + c];

    short8 Ahi[2], Alo[2];
#pragma unroll
    for (int ks = 0; ks < 2; ++ks) {
        const float* hp = h + (size_t)(n0 + c) * 64 + ks * 32 + q * 8;
        f32x4 p0 = *(const f32x4*)hp;
        f32x4 p1 = *(const f32x4*)(hp + 4);
        short8 hi8, lo8;
#pragma unroll
        for (int jj = 0; jj < 4; ++jj) {
            unsigned short hh = f2bf(p0[jj]);
            hi8[jj] = (short)hh; lo8[jj] = (short)f2bf(p0[jj] - bf2f(hh));
            unsigned short h2 = f2bf(p1[jj]);
            hi8[4 + jj] = (short)h2; lo8[4 + jj] = (short)f2bf(p1[jj] - bf2f(h2));
        }
        Ahi[ks] = hi8; Alo[ks] = lo8;
    }

    f32x4 xacc[4] = {{0,0,0,0},{0,0,0,0},{0,0,0,0},{0,0,0,0}};
#pragma unroll
    for (int ks = 0; ks < 2; ++ks)
#pragma unroll
        for (int nt = 0; nt < 4; ++nt) {
            const short8 fhi = Lwhi[(nt * 2 + ks) * 64 + lane];
            const short8 flo = Lwlo[(nt * 2 + ks) * 64 + lane];
            xacc[nt] = __builtin_amdgcn_mfma_f32_16x16x32_bf16(Ahi[ks], fhi, xacc[nt], 0, 0, 0);
            xacc[nt] = __builtin_amdgcn_mfma_f32_16x16x32_bf16(Ahi[ks], flo, xacc[nt], 0, 0, 0);
            xacc[nt] = __builtin_amdgcn_mfma_f32_16x16x32_bf16(Alo[ks], fhi, xacc[nt], 0, 0, 0);
        }

    // whi/wlo fragments are dead from here; reuse [0:9216) of pool for lw.
    __syncthreads();

    unsigned short* lw = (unsigned short*)pool + wv * (16 * 72);
#pragma unroll
    for (int r = 0; r < 4; ++r) {
        const int node = n0 + q * 4 + r;
        unsigned short xb[4];
#pragma unroll
        for (int nt = 0; nt < 4; ++nt) {
            unsigned short v16 = f2bf(xacc[nt][r] + bias[nt]);
            xb[nt] = v16;
            lw[(q * 4 + r) * 72 + nt * 16 + c] = v16;
        }
        if (valid) {
            uint2 pk;
            pk.x = (unsigned)xb[0] | ((unsigned)xb[1] << 16);
            pk.y = (unsigned)xb[2] | ((unsigned)xb[3] << 16);
            *(uint2*)(xv + (size_t)node * 128 + c * 8) = pk;
        }
    }

    short8 Ax[2];
#pragma unroll
    for (int ks = 0; ks < 2; ++ks)
        Ax[ks] = *(const short8*)&lw[c * 72 + ks * 32 + q * 8];

    f32x4 uacc[4] = {{0,0,0,0},{0,0,0,0},{0,0,0,0},{0,0,0,0}};
    f32x4 vacc[4] = {{0,0,0,0},{0,0,0,0},{0,0,0,0},{0,0,0,0}};
#pragma unroll
    for (int ks = 0; ks < 2; ++ks)
#pragma unroll
        for (int nt = 0; nt < 4; ++nt) {
            const short8 fa = Lwa[(nt * 2 + ks) * 64 + lane];
            const short8 fb = Lwb[(nt * 2 + ks) * 64 + lane];
            uacc[nt] = __builtin_amdgcn_mfma_f32_16x16x32_bf16(Ax[ks], fa, uacc[nt], 0, 0, 0);
            vacc[nt] = __builtin_amdgcn_mfma_f32_16x16x32_bf16(Ax[ks], fb, vacc[nt], 0, 0, 0);
        }
    if (valid) {
#pragma unroll
        for (int r = 0; r < 4; ++r) {
            const int node = n0 + q * 4 + r;
            uint2 pu;
            pu.x = (unsigned)f2bf(uacc[0][r] * L2E) | ((unsigned)f2bf(uacc[1][r] * L2E) << 16);
            pu.y = (unsigned)f2bf(uacc[2][r] * L2E) | ((unsigned)f2bf(uacc[3][r] * L2E) << 16);
            *(uint2*)(u_bf + (size_t)node * 64 + c * 4) = pu;
            uint2 pk;
            pk.x = (unsigned)f2bf(vacc[0][r] * L2E) | ((unsigned)f2bf(vacc[1][r] * L2E) << 16);
            pk.y = (unsigned)f2bf(vacc[2][r] * L2E) | ((unsigned)f2bf(vacc[3][r] * L2E) << 16);
            *(uint2*)(xv + (size_t)node * 128 + c * 8 + 4) = pk;
        }
    }
}

// ---------------------------------------------------------------------------
// agg_fused: one block (512 thr, 8 waves) per 128-row bucket.
// Phase 0: scan the 245 slice-extent lengths -> dbase[] (record-index bases).
// Phase 1: ALL 512 threads gather records by global index m (binary search
//          m -> slice), LDS histogram by local row.
// Phase 2: padded (x4) exclusive scan over 128 rows -> LDS row starts.
// Phase 3: second distributed pass (srec L2-hot), counting-sort into LDS
//          (strip lrow; zero pad => att=0).
// Phase 4: each wave aggregates 16 rows (4 edge-slots x 16 feature-lanes),
//          then LN + silu.
// ---------------------------------------------------------------------------
__global__ __launch_bounds__(512, 4) void agg_fused(
    const uint2* __restrict__ srec, const int* __restrict__ ofsT,
    const unsigned short* __restrict__ xv, const unsigned short* __restrict__ u_bf,
    const float4* __restrict__ tab, const float* __restrict__ att_b2,
    const float* __restrict__ ln_g, const float* __restrict__ ln_b,
    float* __restrict__ out) {
    __shared__ __align__(16) uint2 lrecs[CAP + 16];
    __shared__ int hist[128];
    __shared__ int rst[129];
    __shared__ int cur[128];
    __shared__ int sst[256];
    __shared__ int dbase[257];
    __shared__ int wsum4[4];
    __shared__ int wtot;

    const int b = blockIdx.x;
    const int tid = threadIdx.x;
    const int lane = tid & 63;
    const int wv = tid >> 6;

    if (tid < 128) hist[tid] = 0;

    // Phase 0: extent lengths + exclusive scan (threads 0..255).
    int stv = 0, len = 0, sc0 = 0;
    if (tid < 256) {
        if (tid < SC_BLOCKS) {
            stv = ofsT[tid * OFS_STRIDE + b];
            len = ofsT[tid * OFS_STRIDE + b + 1] - stv;
        }
        sst[tid] = stv;
        sc0 = len;
#pragma unroll
        for (int off = 1; off < 64; off <<= 1) {
            int u = __shfl_up(sc0, off);
            if (lane >= off) sc0 += u;
        }
        if (lane == 63) wsum4[wv] = sc0;
    }
    __syncthreads();
    if (tid < 256) {
        int wbase = 0;
        if (wv > 0) wbase = wsum4[0];
        if (wv > 1) wbase += wsum4[1];
        if (wv > 2) wbase += wsum4[2];
        dbase[tid] = wbase + sc0 - len;
        if (tid == 255) dbase[256] = wbase + sc0;
    }
    __syncthreads();
    const int cnt = dbase[245];

    // Phase 1: distributed gather + histogram.
    for (int m = tid; m < cnt; m += 512) {
        int lo = 0, hi = 245;
        while (hi - lo > 1) {
            const int mid = (lo + hi) >> 1;
            if (dbase[mid] <= m) lo = mid; else hi = mid;
        }
        const unsigned key =
            ((const unsigned*)srec)[2 * ((size_t)lo * SC_EDGES + sst[lo] + (m - dbase[lo]))];
        atomicAdd(&hist[key >> 24], 1);
    }
    __syncthreads();

    // Phase 2: padded scan over 128 rows.
    int c = 0, p = 0, sc = 0;
    if (tid < 128) {
        c = hist[tid];
        p = (c + 3) & ~3;
        sc = p;
#pragma unroll
        for (int off = 1; off < 64; off <<= 1) {
            int u = __shfl_up(sc, off);
            if (lane >= off) sc += u;
        }
        if (tid == 63) wtot = sc;
    }
    __syncthreads();
    if (tid < 128) {
        if (tid >= 64) sc += wtot;
        const int excl = sc - p;
        rst[tid] = excl;
        cur[tid] = excl;
        uint2 z; z.x = 0; z.y = 0;
        for (int i = c; i < p; ++i) lrecs[excl + i] = z;
        if (tid == 127) {
            rst[128] = excl + p;
            for (int i = 0; i < 16; ++i) lrecs[excl + p + i] = z;
        }
    }
    __syncthreads();

    // Phase 3: second distributed pass (L2-hot), counting-sort into LDS.
    for (int m = tid; m < cnt; m += 512) {
        int lo = 0, hi = 245;
        while (hi - lo > 1) {
            const int mid = (lo + hi) >> 1;
            if (dbase[mid] <= m) lo = mid; else hi = mid;
        }
        uint2 rec = srec[(size_t)lo * SC_EDGES + sst[lo] + (m - dbase[lo])];
        const int lr = (int)(rec.x >> 24);
        rec.x &= 0x00FFFFFFu;
        lrecs[atomicAdd(&cur[lr], 1)] = rec;
    }
    __syncthreads();

    // Phase 4: aggregation. Wave wv handles local rows wv, wv+8, ..., wv+120.
    const int j = lane & 15;
    const int sl = lane >> 4;
    const float4 t0 = tab[j], t1 = tab[j + 16], t2 = tab[j + 32], t3 = tab[j + 48];
    const float b2L = att_b2[0] * L2E;
    const float gg = ln_g[lane], bb = ln_b[lane];
    const unsigned* xvu = (const unsigned*)xv;

#pragma unroll 1
    for (int k = 0; k < 16; ++k) {
        const int lrw = wv + 8 * k;
        const int r = b * 128 + lrw;
        if (r >= N_NODES) break;

        const uint2 uu = *(const uint2*)(u_bf + (size_t)r * 64 + j * 4);
        const float base0 = __uint_as_float(uu.x << 16) + t0.z;
        const float base1 = __uint_as_float(uu.x & 0xffff0000u) + t1.z;
        const float base2 = __uint_as_float(uu.y << 16) + t2.z;
        const float base3 = __uint_as_float(uu.y & 0xffff0000u) + t3.z;

        const int s0 = rst[lrw];
        const int e1 = rst[lrw + 1];

        float a0 = 0.f, a1 = 0.f, a2 = 0.f, a3 = 0.f;
        if (e1 > s0) {
            uint2 recA = lrecs[s0 + sl];
            uint4 xvA = *(const uint4*)(xvu + (size_t)recA.x * 64 + j * 4);
            for (int e = s0; e < e1; e += 4) {
                const uint2 recB = lrecs[e + 4 + sl];
                const uint4 xvB = *(const uint4*)(xvu + (size_t)recB.x * 64 + j * 4);

                const float dist = __uint_as_float(recA.y << 16);
                const float emN = __uint_as_float(recA.y & 0xffff0000u);
                const float x0 = __uint_as_float(xvA.x << 16);
                const float x1 = __uint_as_float(xvA.x & 0xffff0000u);
                const float x2 = __uint_as_float(xvA.y << 16);
                const float x3 = __uint_as_float(xvA.y & 0xffff0000u);
                const float v0 = __uint_as_float(xvA.z << 16);
                const float v1 = __uint_as_float(xvA.z & 0xffff0000u);
                const float v2 = __uint_as_float(xvA.w << 16);
                const float v3 = __uint_as_float(xvA.w & 0xffff0000u);
                float pv = 0.f, pre, sg;
                pre = fmaf(dist, t0.y, base0) + v0;
                sg = __builtin_amdgcn_rcpf(1.f + __builtin_amdgcn_exp2f(-pre));
                pv = fmaf(pre * sg, t0.x, pv);
                pre = fmaf(dist, t1.y, base1) + v1;
                sg = __builtin_amdgcn_rcpf(1.f + __builtin_amdgcn_exp2f(-pre));
                pv = fmaf(pre * sg, t1.x, pv);
                pre = fmaf(dist, t2.y, base2) + v2;
                sg = __builtin_amdgcn_rcpf(1.f + __builtin_amdgcn_exp2f(-pre));
                pv = fmaf(pre * sg, t2.x, pv);
                pre = fmaf(dist, t3.y, base3) + v3;
                sg = __builtin_amdgcn_rcpf(1.f + __builtin_amdgcn_exp2f(-pre));
                pv = fmaf(pre * sg, t3.x, pv);
                pv += __shfl_xor(pv, 1); pv += __shfl_xor(pv, 2);
                pv += __shfl_xor(pv, 4); pv += __shfl_xor(pv, 8);
                const float sp = fmaf(pv, L2E, b2L);
                const float att =
                    emN * __builtin_amdgcn_rcpf(1.f + __builtin_amdgcn_exp2f(-sp));
                a0 = fmaf(att, x0, a0); a1 = fmaf(att, x1, a1);
                a2 = fmaf(att, x2, a2); a3 = fmaf(att, x3, a3);
                recA = recB; xvA = xvB;
            }
        }
        a0 += __shfl_xor(a0, 16); a0 += __shfl_xor(a0, 32);
        a1 += __shfl_xor(a1, 16); a1 += __shfl_xor(a1, 32);
        a2 += __shfl_xor(a2, 16); a2 += __shfl_xor(a2, 32);
        a3 += __shfl_xor(a3, 16); a3 += __shfl_xor(a3, 32);

        const uint2 xr = *(const uint2*)(xvu + (size_t)r * 64 + j * 4);
        const float o0 = __uint_as_float(xr.x << 16) + a0;
        const float o1 = __uint_as_float(xr.x & 0xffff0000u) + a1;
        const float o2 = __uint_as_float(xr.y << 16) + a2;
        const float o3 = __uint_as_float(xr.y & 0xffff0000u) + a3;

        float ssum = o0 + o1 + o2 + o3;
        ssum += __shfl_xor(ssum, 1); ssum += __shfl_xor(ssum, 2);
        ssum += __shfl_xor(ssum, 4); ssum += __shfl_xor(ssum, 8);
        const float mu = ssum * (1.f / 64.f);
        const float d0 = o0 - mu, d1 = o1 - mu, d2 = o2 - mu, d3 = o3 - mu;
        float vs = d0 * d0 + d1 * d1 + d2 * d2 + d3 * d3;
        vs += __shfl_xor(vs, 1); vs += __shfl_xor(vs, 2);
        vs += __shfl_xor(vs, 4); vs += __shfl_xor(vs, 8);
        const float rstd = rsqrtf(vs * (1.f / 64.f) + LN_EPS);

        const float dk = (sl == 0) ? d0 : (sl == 1) ? d1 : (sl == 2) ? d2 : d3;
        const float y = fmaf(dk * rstd, gg, bb);
        out[(size_t)r * 64 + lane] =
            y * __builtin_amdgcn_rcpf(1.f + __builtin_amdgcn_exp2f(-y * L2E));
    }
}

extern "C" void kernel_launch(void* const* d_in, const int* in_sizes, int n_in,
                              void* d_out, int out_size, void* d_ws, size_t ws_size,
                              hipStream_t stream) {
    const float* h      = (const float*)d_in[0];
    const float* dist   = (const float*)d_in[1];
    const int*   edges  = (const int*)d_in[2];
    const float* emask  = (const float*)d_in[4];
    const float* W_lin  = (const float*)d_in[5];
    const float* b_lin  = (const float*)d_in[6];
    const float* att_W1 = (const float*)d_in[7];
    const float* att_b1 = (const float*)d_in[8];
    const float* att_W2 = (const float*)d_in[9];
    const float* att_b2 = (const float*)d_in[10];
    const float* ln_g   = (const float*)d_in[11];
    const float* ln_b   = (const float*)d_in[12];
    float* out = (float*)d_out;

    char* ws = (char*)d_ws;
    unsigned short* xv   = (unsigned short*)ws;                  // 25,600,000
    unsigned short* u_bf = (unsigned short*)(ws + 25600000);     // 12,800,000
    uint2* srec          = (uint2*)(ws + 38400000);              //  8,028,160 (245*4096*8)
    int* ofsT            = (int*)(ws + 46428160);                //    768,320 (245*784*4)
    float4* tab          = (float4*)(ws + 47196480);             //      1,024
    short8* whi          = (short8*)(ws + 47197504);             //      8,192
    short8* wlo          = (short8*)(ws + 47205696);             //      8,192
    short8* wa           = (short8*)(ws + 47213888);             //      8,192
    short8* wb           = (short8*)(ws + 47222080);             //      8,192

    prep_frags<<<1, 256, 0, stream>>>(W_lin, att_W1, att_b1, att_W2,
                                      whi, wlo, wa, wb, tab);
    proj_scatter<<<PROJ_BLOCKS + SC_BLOCKS, 256, 0, stream>>>(
        h, b_lin, whi, wlo, wa, wb, edges, dist, emask, srec, ofsT, xv, u_bf);
    agg_fused<<<N_BUCKETS, 512, 0, stream>>>(srec, ofsT, xv, u_bf,
                                             tab, att_b2, ln_g, ln_b, out);
}

// Round 6
// 197.424 us; speedup vs baseline: 1.4255x; 1.0182x over previous
//
#include <hip/hip_runtime.h>
#include <hip/hip_bf16.h>

#define N_NODES 100000
#define N_EDGES 1000000
#define DIM 64
#define NORM_INV 0.01f
#define LN_EPS 1e-5f
#define N_TILES 6250          // N_NODES/16
#define PROJ_BLOCKS 1563      // ceil(6250/4)
#define N_BUCKETS 782         // ceil(100000/128), 128 rows per bucket
#define NB_PAD 800            // padded bin count for 4-per-thread scan
#define SC_EDGES 4096         // edges per scatter slice
#define SC_BLOCKS 245         // ceil(1e6/4096)
#define OFS_STRIDE 784        // ints per ofsT row (783 used, padded)
#define L2E 1.4426950408889634f
#define LN2 0.6931471805599453f
#define CAP 2560              // LDS record capacity/bucket

typedef __attribute__((ext_vector_type(8))) short short8;
typedef __attribute__((ext_vector_type(4))) float f32x4;

__device__ __forceinline__ unsigned short f2bf(float f) {
    union { float f; unsigned u; } x; x.f = f;
    unsigned r = x.u + 0x7FFFu + ((x.u >> 16) & 1u);
    return (unsigned short)(r >> 16);
}
__device__ __forceinline__ float bf2f(unsigned short s) {
    union { unsigned u; float f; } x; x.u = ((unsigned)s) << 16; return x.f;
}

// ---------------------------------------------------------------------------
// proj_scatter fat kernel — no global atomics, no prep kernel.
// blocks [0, SC_BLOCKS): fixed-slice scatter (dispatched FIRST so it overlaps
//   the proj wavefront instead of trailing it). Each block owns
//   srec[blk*4096 .. +4096): loads 4096 edges, LDS counting-sort by bucket,
//   writes its slice fully coalesced + one ofsT row (local bucket offsets,
//   row[782] = slice length sentinel). srec.x = col | lrow<<24.
// blocks [SC_BLOCKS, +PROJ_BLOCKS): MFMA projection, 1 tile/wave. Weight
//   fragments are built IN-BLOCK from W_lin/att_W1 straight into LDS
//   (32 KB; L2-hot sources), freeing ~128 VGPRs/wave and the prep kernel.
//   After phase-1 MFMAs + barrier, the whi/wlo LDS region is reused for lw.
// ---------------------------------------------------------------------------
__global__ __launch_bounds__(256) void proj_scatter(
    const float* __restrict__ h, const float* __restrict__ bl,
    const float* __restrict__ W, const float* __restrict__ att_W1,
    const int* __restrict__ edges, const float* __restrict__ dist,
    const float* __restrict__ emask,
    uint2* __restrict__ srec, int* __restrict__ ofsT,
    unsigned short* __restrict__ xv, unsigned short* __restrict__ u_bf) {
    __shared__ __align__(16) char pool[39168];
    __shared__ int wsum[4];

    if (blockIdx.x < SC_BLOCKS) {
        // ------------------- scatter personality -------------------
        int* lh = (int*)pool;                       // [NB_PAD]
        int* lofs = (int*)pool + NB_PAD;            // [NB_PAD]
        uint2* lsort = (uint2*)(pool + 6400);       // [SC_EDGES]
        const int blk = blockIdx.x;
        const int tid = threadIdx.x;
        const int lane = tid & 63;
        const int w = tid >> 6;
        for (int i = tid; i < NB_PAD; i += 256) lh[i] = 0;
        __syncthreads();

        const int eb = blk * SC_EDGES;
        const int total = min(SC_EDGES, N_EDGES - eb);

        // Phase A: load 16 edges/thread, histogram with rank capture.
        int rows[16], rank[16];
        uint2 recs[16];
        const int e0 = eb + tid * 16;
#pragma unroll
        for (int g = 0; g < 4; ++g) {
            const int e = e0 + g * 4;
            if (e + 4 <= N_EDGES) {
                const int4 rr = *(const int4*)(edges + e);
                const int4 cc = *(const int4*)(edges + N_EDGES + e);
                const float4 dd = *(const float4*)(dist + e);
                const float4 mm = *(const float4*)(emask + e);
                rows[g*4+0] = rr.x; rows[g*4+1] = rr.y; rows[g*4+2] = rr.z; rows[g*4+3] = rr.w;
                const int c4[4] = {cc.x, cc.y, cc.z, cc.w};
                const float d4[4] = {dd.x, dd.y, dd.z, dd.w};
                const float m4[4] = {mm.x, mm.y, mm.z, mm.w};
#pragma unroll
                for (int i = 0; i < 4; ++i) {
                    const int ii = g * 4 + i;
                    recs[ii].x = (unsigned)c4[i] | ((unsigned)(rows[ii] & 127) << 24);
                    recs[ii].y = (unsigned)f2bf(d4[i]) |
                                 ((unsigned)f2bf(m4[i] * NORM_INV) << 16);
                    rank[ii] = atomicAdd(&lh[rows[ii] >> 7], 1);
                }
            } else {
#pragma unroll
                for (int i = 0; i < 4; ++i) {
                    const int ii = g * 4 + i;
                    const int ee = e + i;
                    if (ee < N_EDGES) {
                        rows[ii] = edges[ee];
                        recs[ii].x = (unsigned)edges[N_EDGES + ee] |
                                     ((unsigned)(rows[ii] & 127) << 24);
                        recs[ii].y = (unsigned)f2bf(dist[ee]) |
                                     ((unsigned)f2bf(emask[ee] * NORM_INV) << 16);
                        rank[ii] = atomicAdd(&lh[rows[ii] >> 7], 1);
                    } else {
                        rows[ii] = -1;
                    }
                }
            }
        }
        __syncthreads();

        // Phase B: 4-bins/thread exclusive scan over 800 padded bins.
        const int b0 = tid * 4;
        int c0 = 0, c1 = 0, c2 = 0, c3 = 0;
        if (b0 < NB_PAD) { c0 = lh[b0]; c1 = lh[b0+1]; c2 = lh[b0+2]; c3 = lh[b0+3]; }
        const int S = c0 + c1 + c2 + c3;
        int sc = S;
#pragma unroll
        for (int off = 1; off < 64; off <<= 1) {
            int u = __shfl_up(sc, off);
            if (lane >= off) sc += u;
        }
        if (lane == 63) wsum[w] = sc;
        __syncthreads();
        int wbase = 0;
        if (w > 0) wbase = wsum[0];
        if (w > 1) wbase += wsum[1];
        if (w > 2) wbase += wsum[2];
        const int excl = sc - S + wbase;
        if (b0 < NB_PAD) {
            lofs[b0] = excl;
            lofs[b0+1] = excl + c0;
            lofs[b0+2] = excl + c0 + c1;
            lofs[b0+3] = excl + c0 + c1 + c2;
        }
        __syncthreads();

        // Phase C: place into LDS sorted by bucket.
#pragma unroll
        for (int i = 0; i < 16; ++i) {
            if (rows[i] >= 0) {
                const int bk = rows[i] >> 7;
                lsort[lofs[bk] + rank[i]] = recs[i];
            }
        }
        __syncthreads();

        // Phase D: fully-coalesced slice write-out + ofsT row.
        for (int s = tid; s < total; s += 256)
            srec[(size_t)blk * SC_EDGES + s] = lsort[s];
        for (int b = tid; b < 783; b += 256)
            ofsT[blk * OFS_STRIDE + b] = lofs[b];   // lofs[782] == total
        return;
    }

    // ------------------- projection personality -------------------
    const int tid = threadIdx.x;
    const int lane = tid & 63;
    const int wv = tid >> 6;
    const int c = lane & 15, q = lane >> 4;

    // In-block fragment build: W hi/lo split + att_W1 a/b fragments -> LDS.
    // Identical value map to the old prep_frags kernel.
    {
        short8* Lwhi_w = (short8*)pool;
        short8* Lwlo_w = Lwhi_w + 512;
        short8* Lwa_w  = Lwhi_w + 1024;
        short8* Lwb_w  = Lwhi_w + 1536;
        const int nt_b = tid >> 6;
        const int n_b = nt_b * 16 + c;
#pragma unroll
        for (int ks = 0; ks < 2; ++ks) {
            const int k0 = ks * 32 + q * 8;
            short8 hi8, lo8, a8, b8;
#pragma unroll
            for (int jj = 0; jj < 8; ++jj) {
                float w = W[n_b * 64 + k0 + jj];
                unsigned short hh = f2bf(w);
                hi8[jj] = (short)hh;
                lo8[jj] = (short)f2bf(w - bf2f(hh));
                a8[jj] = (short)f2bf(att_W1[n_b * 129 + k0 + jj]);
                b8[jj] = (short)f2bf(att_W1[n_b * 129 + 64 + k0 + jj]);
            }
            const int idx = (nt_b * 2 + ks) * 64 + lane;
            Lwhi_w[idx] = hi8; Lwlo_w[idx] = lo8; Lwa_w[idx] = a8; Lwb_w[idx] = b8;
        }
    }
    __syncthreads();
    const short8* Lwhi = (const short8*)pool;
    const short8* Lwlo = Lwhi + 512;
    const short8* Lwa  = Lwhi + 1024;
    const short8* Lwb  = Lwhi + 1536;

    const int tile = (blockIdx.x - SC_BLOCKS) * 4 + wv;
    const bool valid = (tile < N_TILES);
    const int n0 = valid ? tile * 16 : 0;

    float bias[4];
#pragma unroll
    for (int nt = 0; nt < 4; ++nt) bias[nt] = bl[nt * 16 + c];

    short8 Ahi[2], Alo[2];
#pragma unroll
    for (int ks = 0; ks < 2; ++ks) {
        const float* hp = h + (size_t)(n0 + c) * 64 + ks * 32 + q * 8;
        f32x4 p0 = *(const f32x4*)hp;
        f32x4 p1 = *(const f32x4*)(hp + 4);
        short8 hi8, lo8;
#pragma unroll
        for (int jj = 0; jj < 4; ++jj) {
            unsigned short hh = f2bf(p0[jj]);
            hi8[jj] = (short)hh; lo8[jj] = (short)f2bf(p0[jj] - bf2f(hh));
            unsigned short h2 = f2bf(p1[jj]);
            hi8[4 + jj] = (short)h2; lo8[4 + jj] = (short)f2bf(p1[jj] - bf2f(h2));
        }
        Ahi[ks] = hi8; Alo[ks] = lo8;
    }

    f32x4 xacc[4] = {{0,0,0,0},{0,0,0,0},{0,0,0,0},{0,0,0,0}};
#pragma unroll
    for (int ks = 0; ks < 2; ++ks)
#pragma unroll
        for (int nt = 0; nt < 4; ++nt) {
            const short8 fhi = Lwhi[(nt * 2 + ks) * 64 + lane];
            const short8 flo = Lwlo[(nt * 2 + ks) * 64 + lane];
            xacc[nt] = __builtin_amdgcn_mfma_f32_16x16x32_bf16(Ahi[ks], fhi, xacc[nt], 0, 0, 0);
            xacc[nt] = __builtin_amdgcn_mfma_f32_16x16x32_bf16(Ahi[ks], flo, xacc[nt], 0, 0, 0);
            xacc[nt] = __builtin_amdgcn_mfma_f32_16x16x32_bf16(Alo[ks], fhi, xacc[nt], 0, 0, 0);
        }

    // whi/wlo fragments are dead from here; reuse [0:9216) of pool for lw.
    __syncthreads();

    unsigned short* lw = (unsigned short*)pool + wv * (16 * 72);
#pragma unroll
    for (int r = 0; r < 4; ++r) {
        const int node = n0 + q * 4 + r;
        unsigned short xb[4];
#pragma unroll
        for (int nt = 0; nt < 4; ++nt) {
            unsigned short v16 = f2bf(xacc[nt][r] + bias[nt]);
            xb[nt] = v16;
            lw[(q * 4 + r) * 72 + nt * 16 + c] = v16;
        }
        if (valid) {
            uint2 pk;
            pk.x = (unsigned)xb[0] | ((unsigned)xb[1] << 16);
            pk.y = (unsigned)xb[2] | ((unsigned)xb[3] << 16);
            *(uint2*)(xv + (size_t)node * 128 + c * 8) = pk;
        }
    }

    short8 Ax[2];
#pragma unroll
    for (int ks = 0; ks < 2; ++ks)
        Ax[ks] = *(const short8*)&lw[c * 72 + ks * 32 + q * 8];

    f32x4 uacc[4] = {{0,0,0,0},{0,0,0,0},{0,0,0,0},{0,0,0,0}};
    f32x4 vacc[4] = {{0,0,0,0},{0,0,0,0},{0,0,0,0},{0,0,0,0}};
#pragma unroll
    for (int ks = 0; ks < 2; ++ks)
#pragma unroll
        for (int nt = 0; nt < 4; ++nt) {
            const short8 fa = Lwa[(nt * 2 + ks) * 64 + lane];
            const short8 fb = Lwb[(nt * 2 + ks) * 64 + lane];
            uacc[nt] = __builtin_amdgcn_mfma_f32_16x16x32_bf16(Ax[ks], fa, uacc[nt], 0, 0, 0);
            vacc[nt] = __builtin_amdgcn_mfma_f32_16x16x32_bf16(Ax[ks], fb, vacc[nt], 0, 0, 0);
        }
    if (valid) {
#pragma unroll
        for (int r = 0; r < 4; ++r) {
            const int node = n0 + q * 4 + r;
            uint2 pu;
            pu.x = (unsigned)f2bf(uacc[0][r] * L2E) | ((unsigned)f2bf(uacc[1][r] * L2E) << 16);
            pu.y = (unsigned)f2bf(uacc[2][r] * L2E) | ((unsigned)f2bf(uacc[3][r] * L2E) << 16);
            *(uint2*)(u_bf + (size_t)node * 64 + c * 4) = pu;
            uint2 pk;
            pk.x = (unsigned)f2bf(vacc[0][r] * L2E) | ((unsigned)f2bf(vacc[1][r] * L2E) << 16);
            pk.y = (unsigned)f2bf(vacc[2][r] * L2E) | ((unsigned)f2bf(vacc[3][r] * L2E) << 16);
            *(uint2*)(xv + (size_t)node * 128 + c * 8 + 4) = pk;
        }
    }
}

// ---------------------------------------------------------------------------
// agg_fused: one block (512 thr, 8 waves) per 128-row bucket.
// Phase 0: scan the 245 slice-extent lengths -> dbase[]; build ltab in LDS.
// Phase 1: single distributed gather — each thread binary-searches and HOLDS
//          its <=5 records in statically-named registers; LDS histogram.
// Phase 2: padded (x4) exclusive scan over 128 rows -> LDS row starts.
// Phase 3: place held records via cur atomics (no second srec pass).
// Phase 4: each wave aggregates 16 rows (4 edge-slots x 16 feature-lanes),
//          then LN + silu.
// ---------------------------------------------------------------------------
__global__ __launch_bounds__(512, 4) void agg_fused(
    const uint2* __restrict__ srec, const int* __restrict__ ofsT,
    const unsigned short* __restrict__ xv, const unsigned short* __restrict__ u_bf,
    const float* __restrict__ att_W1, const float* __restrict__ att_b1,
    const float* __restrict__ att_W2, const float* __restrict__ att_b2,
    const float* __restrict__ ln_g, const float* __restrict__ ln_b,
    float* __restrict__ out) {
    __shared__ __align__(16) uint2 lrecs[CAP + 16];
    __shared__ float4 ltab[64];
    __shared__ int hist[128];
    __shared__ int rst[129];
    __shared__ int cur[128];
    __shared__ int sst[256];
    __shared__ int dbase[257];
    __shared__ int wsum4[4];
    __shared__ int wtot;

    const int b = blockIdx.x;
    const int tid = threadIdx.x;
    const int lane = tid & 63;
    const int wv = tid >> 6;

    if (tid < 128) hist[tid] = 0;
    if (tid >= 448) {
        const int f = tid - 448;
        ltab[f] = make_float4(att_W2[f] * LN2, att_W1[f * 129 + 128] * L2E,
                              att_b1[f] * L2E, 0.f);
    }

    // Phase 0: extent lengths + exclusive scan (threads 0..255).
    int stv = 0, len = 0, sc0 = 0;
    if (tid < 256) {
        if (tid < SC_BLOCKS) {
            stv = ofsT[tid * OFS_STRIDE + b];
            len = ofsT[tid * OFS_STRIDE + b + 1] - stv;
        }
        sst[tid] = stv;
        sc0 = len;
#pragma unroll
        for (int off = 1; off < 64; off <<= 1) {
            int u = __shfl_up(sc0, off);
            if (lane >= off) sc0 += u;
        }
        if (lane == 63) wsum4[wv] = sc0;
    }
    __syncthreads();
    if (tid < 256) {
        int wbase = 0;
        if (wv > 0) wbase = wsum4[0];
        if (wv > 1) wbase += wsum4[1];
        if (wv > 2) wbase += wsum4[2];
        dbase[tid] = wbase + sc0 - len;
        if (tid == 255) dbase[256] = wbase + sc0;
    }
    __syncthreads();
    const int cnt = dbase[245];

    // Phase 1: distributed gather into registers + histogram.
    uint2 rec0, rec1, rec2, rec3, rec4;
    int lr0 = -1, lr1 = -1, lr2 = -1, lr3 = -1, lr4 = -1;
#define GATHER(I, RC, LR)                                                     \
    {                                                                         \
        const int m = tid + I * 512;                                          \
        if (m < cnt) {                                                        \
            int lo = 0, hi = 245;                                             \
            while (hi - lo > 1) {                                             \
                const int mid = (lo + hi) >> 1;                               \
                if (dbase[mid] <= m) lo = mid; else hi = mid;                 \
            }                                                                 \
            RC = srec[(size_t)lo * SC_EDGES + sst[lo] + (m - dbase[lo])];     \
            LR = (int)(RC.x >> 24);                                           \
            RC.x &= 0x00FFFFFFu;                                              \
            atomicAdd(&hist[LR], 1);                                          \
        }                                                                     \
    }
    GATHER(0, rec0, lr0)
    GATHER(1, rec1, lr1)
    GATHER(2, rec2, lr2)
    GATHER(3, rec3, lr3)
    GATHER(4, rec4, lr4)
#undef GATHER
    __syncthreads();

    // Phase 2: padded scan over 128 rows.
    int c = 0, p = 0, sc = 0;
    if (tid < 128) {
        c = hist[tid];
        p = (c + 3) & ~3;
        sc = p;
#pragma unroll
        for (int off = 1; off < 64; off <<= 1) {
            int u = __shfl_up(sc, off);
            if (lane >= off) sc += u;
        }
        if (tid == 63) wtot = sc;
    }
    __syncthreads();
    if (tid < 128) {
        if (tid >= 64) sc += wtot;
        const int excl = sc - p;
        rst[tid] = excl;
        cur[tid] = excl;
        uint2 z; z.x = 0; z.y = 0;
        for (int i = c; i < p; ++i) lrecs[excl + i] = z;
        if (tid == 127) {
            rst[128] = excl + p;
            for (int i = 0; i < 16; ++i) lrecs[excl + p + i] = z;
        }
    }
    __syncthreads();

    // Phase 3: place held records (counting-sort into LDS).
    if (lr0 >= 0) lrecs[atomicAdd(&cur[lr0], 1)] = rec0;
    if (lr1 >= 0) lrecs[atomicAdd(&cur[lr1], 1)] = rec1;
    if (lr2 >= 0) lrecs[atomicAdd(&cur[lr2], 1)] = rec2;
    if (lr3 >= 0) lrecs[atomicAdd(&cur[lr3], 1)] = rec3;
    if (lr4 >= 0) lrecs[atomicAdd(&cur[lr4], 1)] = rec4;
    __syncthreads();

    // Phase 4: aggregation. Wave wv handles local rows wv, wv+8, ..., wv+120.
    const int j = lane & 15;
    const int sl = lane >> 4;
    const float4 t0 = ltab[j], t1 = ltab[j + 16], t2 = ltab[j + 32], t3 = ltab[j + 48];
    const float b2L = att_b2[0] * L2E;
    const float gg = ln_g[lane], bb = ln_b[lane];
    const unsigned* xvu = (const unsigned*)xv;

#pragma unroll 1
    for (int k = 0; k < 16; ++k) {
        const int lrw = wv + 8 * k;
        const int r = b * 128 + lrw;
        if (r >= N_NODES) break;

        const uint2 uu = *(const uint2*)(u_bf + (size_t)r * 64 + j * 4);
        const float base0 = __uint_as_float(uu.x << 16) + t0.z;
        const float base1 = __uint_as_float(uu.x & 0xffff0000u) + t1.z;
        const float base2 = __uint_as_float(uu.y << 16) + t2.z;
        const float base3 = __uint_as_float(uu.y & 0xffff0000u) + t3.z;

        const int s0 = rst[lrw];
        const int e1 = rst[lrw + 1];

        float a0 = 0.f, a1 = 0.f, a2 = 0.f, a3 = 0.f;
        if (e1 > s0) {
            uint2 recA = lrecs[s0 + sl];
            uint4 xvA = *(const uint4*)(xvu + (size_t)recA.x * 64 + j * 4);
            for (int e = s0; e < e1; e += 4) {
                const uint2 recB = lrecs[e + 4 + sl];
                const uint4 xvB = *(const uint4*)(xvu + (size_t)recB.x * 64 + j * 4);

                const float dist = __uint_as_float(recA.y << 16);
                const float emN = __uint_as_float(recA.y & 0xffff0000u);
                const float x0 = __uint_as_float(xvA.x << 16);
                const float x1 = __uint_as_float(xvA.x & 0xffff0000u);
                const float x2 = __uint_as_float(xvA.y << 16);
                const float x3 = __uint_as_float(xvA.y & 0xffff0000u);
                const float v0 = __uint_as_float(xvA.z << 16);
                const float v1 = __uint_as_float(xvA.z & 0xffff0000u);
                const float v2 = __uint_as_float(xvA.w << 16);
                const float v3 = __uint_as_float(xvA.w & 0xffff0000u);
                float pv = 0.f, pre, sg;
                pre = fmaf(dist, t0.y, base0) + v0;
                sg = __builtin_amdgcn_rcpf(1.f + __builtin_amdgcn_exp2f(-pre));
                pv = fmaf(pre * sg, t0.x, pv);
                pre = fmaf(dist, t1.y, base1) + v1;
                sg = __builtin_amdgcn_rcpf(1.f + __builtin_amdgcn_exp2f(-pre));
                pv = fmaf(pre * sg, t1.x, pv);
                pre = fmaf(dist, t2.y, base2) + v2;
                sg = __builtin_amdgcn_rcpf(1.f + __builtin_amdgcn_exp2f(-pre));
                pv = fmaf(pre * sg, t2.x, pv);
                pre = fmaf(dist, t3.y, base3) + v3;
                sg = __builtin_amdgcn_rcpf(1.f + __builtin_amdgcn_exp2f(-pre));
                pv = fmaf(pre * sg, t3.x, pv);
                pv += __shfl_xor(pv, 1); pv += __shfl_xor(pv, 2);
                pv += __shfl_xor(pv, 4); pv += __shfl_xor(pv, 8);
                const float sp = fmaf(pv, L2E, b2L);
                const float att =
                    emN * __builtin_amdgcn_rcpf(1.f + __builtin_amdgcn_exp2f(-sp));
                a0 = fmaf(att, x0, a0); a1 = fmaf(att, x1, a1);
                a2 = fmaf(att, x2, a2); a3 = fmaf(att, x3, a3);
                recA = recB; xvA = xvB;
            }
        }
        a0 += __shfl_xor(a0, 16); a0 += __shfl_xor(a0, 32);
        a1 += __shfl_xor(a1, 16); a1 += __shfl_xor(a1, 32);
        a2 += __shfl_xor(a2, 16); a2 += __shfl_xor(a2, 32);
        a3 += __shfl_xor(a3, 16); a3 += __shfl_xor(a3, 32);

        const uint2 xr = *(const uint2*)(xvu + (size_t)r * 64 + j * 4);
        const float o0 = __uint_as_float(xr.x << 16) + a0;
        const float o1 = __uint_as_float(xr.x & 0xffff0000u) + a1;
        const float o2 = __uint_as_float(xr.y << 16) + a2;
        const float o3 = __uint_as_float(xr.y & 0xffff0000u) + a3;

        float ssum = o0 + o1 + o2 + o3;
        ssum += __shfl_xor(ssum, 1); ssum += __shfl_xor(ssum, 2);
        ssum += __shfl_xor(ssum, 4); ssum += __shfl_xor(ssum, 8);
        const float mu = ssum * (1.f / 64.f);
        const float d0 = o0 - mu, d1 = o1 - mu, d2 = o2 - mu, d3 = o3 - mu;
        float vs = d0 * d0 + d1 * d1 + d2 * d2 + d3 * d3;
        vs += __shfl_xor(vs, 1); vs += __shfl_xor(vs, 2);
        vs += __shfl_xor(vs, 4); vs += __shfl_xor(vs, 8);
        const float rstd = rsqrtf(vs * (1.f / 64.f) + LN_EPS);

        const float dk = (sl == 0) ? d0 : (sl == 1) ? d1 : (sl == 2) ? d2 : d3;
        const float y = fmaf(dk * rstd, gg, bb);
        out[(size_t)r * 64 + lane] =
            y * __builtin_amdgcn_rcpf(1.f + __builtin_amdgcn_exp2f(-y * L2E));
    }
}

extern "C" void kernel_launch(void* const* d_in, const int* in_sizes, int n_in,
                              void* d_out, int out_size, void* d_ws, size_t ws_size,
                              hipStream_t stream) {
    const float* h      = (const float*)d_in[0];
    const float* dist   = (const float*)d_in[1];
    const int*   edges  = (const int*)d_in[2];
    const float* emask  = (const float*)d_in[4];
    const float* W_lin  = (const float*)d_in[5];
    const float* b_lin  = (const float*)d_in[6];
    const float* att_W1 = (const float*)d_in[7];
    const float* att_b1 = (const float*)d_in[8];
    const float* att_W2 = (const float*)d_in[9];
    const float* att_b2 = (const float*)d_in[10];
    const float* ln_g   = (const float*)d_in[11];
    const float* ln_b   = (const float*)d_in[12];
    float* out = (float*)d_out;

    char* ws = (char*)d_ws;
    unsigned short* xv   = (unsigned short*)ws;                  // 25,600,000
    unsigned short* u_bf = (unsigned short*)(ws + 25600000);     // 12,800,000
    uint2* srec          = (uint2*)(ws + 38400000);              //  8,028,160 (245*4096*8)
    int* ofsT            = (int*)(ws + 46428160);                //    768,320 (245*784*4)

    proj_scatter<<<SC_BLOCKS + PROJ_BLOCKS, 256, 0, stream>>>(
        h, b_lin, W_lin, att_W1, edges, dist, emask, srec, ofsT, xv, u_bf);
    agg_fused<<<N_BUCKETS, 512, 0, stream>>>(srec, ofsT, xv, u_bf,
                                             att_W1, att_b1, att_W2, att_b2,
                                             ln_g, ln_b, out);
}

// Round 7
// 192.298 us; speedup vs baseline: 1.4635x; 1.0267x over previous
//
#include <hip/hip_runtime.h>
#include <hip/hip_bf16.h>

#define N_NODES 100000
#define N_EDGES 1000000
#define DIM 64
#define NORM_INV 0.01f
#define LN_EPS 1e-5f
#define N_TILES 6250          // N_NODES/16
#define PROJ_BLOCKS 1563      // ceil(6250/4)
#define N_BUCKETS 1563        // ceil(100000/64), 64 rows per bucket
#define HB_PK 784             // packed-int count: 1568 u16 bins (>=1564)
#define SC_EDGES 4096         // edges per scatter slice
#define SC_BLOCKS 245         // ceil(1e6/4096)
#define OFS_STRIDE 1568       // ints per ofsT row (1564 used, padded)
#define L2E 1.4426950408889634f
#define LN2 0.6931471805599453f
#define CAP 1280              // LDS record capacity/bucket (mean padded ~736)

typedef __attribute__((ext_vector_type(8))) short short8;
typedef __attribute__((ext_vector_type(4))) float f32x4;

__device__ __forceinline__ unsigned short f2bf(float f) {
    union { float f; unsigned u; } x; x.f = f;
    unsigned r = x.u + 0x7FFFu + ((x.u >> 16) & 1u);
    return (unsigned short)(r >> 16);
}
__device__ __forceinline__ float bf2f(unsigned short s) {
    union { unsigned u; float f; } x; x.u = ((unsigned)s) << 16; return x.f;
}

// ---------------------------------------------------------------------------
// proj_scatter fat kernel — no global atomics, no prep kernel.
// blocks [0, SC_BLOCKS): fixed-slice scatter. 1563 bins (64-row buckets),
//   two 16-bit counters packed per LDS int (counts <= 4096, no carry).
//   LDS: lh 784 ints + lofsP 784 ints + lsort 4096 uint2 = 39,040 B.
//   srec.x = col | lrow<<24 (lrow = row & 63).
// blocks [SC_BLOCKS, +PROJ_BLOCKS): MFMA projection, 1 tile/wave; weight
//   fragments built in-block into LDS (32 KB), whi/wlo region reused for lw.
// ---------------------------------------------------------------------------
__global__ __launch_bounds__(256) void proj_scatter(
    const float* __restrict__ h, const float* __restrict__ bl,
    const float* __restrict__ W, const float* __restrict__ att_W1,
    const int* __restrict__ edges, const float* __restrict__ dist,
    const float* __restrict__ emask,
    uint2* __restrict__ srec, int* __restrict__ ofsT,
    unsigned short* __restrict__ xv, unsigned short* __restrict__ u_bf) {
    __shared__ __align__(16) char pool[39168];
    __shared__ int wsum[4];

    if (blockIdx.x < SC_BLOCKS) {
        // ------------------- scatter personality -------------------
        int* lh = (int*)pool;                       // [HB_PK] packed counts
        int* lofsP = (int*)pool + HB_PK;            // [HB_PK] packed offsets
        uint2* lsort = (uint2*)(pool + 6272);       // [SC_EDGES]
        const int blk = blockIdx.x;
        const int tid = threadIdx.x;
        const int lane = tid & 63;
        const int w = tid >> 6;
        for (int i = tid; i < HB_PK; i += 256) lh[i] = 0;
        __syncthreads();

        const int eb = blk * SC_EDGES;
        const int total = min(SC_EDGES, N_EDGES - eb);

        // Phase A: load 16 edges/thread, histogram with rank capture.
        int rows[16], rank[16];
        uint2 recs[16];
        const int e0 = eb + tid * 16;
#pragma unroll
        for (int g = 0; g < 4; ++g) {
            const int e = e0 + g * 4;
            if (e + 4 <= N_EDGES) {
                const int4 rr = *(const int4*)(edges + e);
                const int4 cc = *(const int4*)(edges + N_EDGES + e);
                const float4 dd = *(const float4*)(dist + e);
                const float4 mm = *(const float4*)(emask + e);
                rows[g*4+0] = rr.x; rows[g*4+1] = rr.y; rows[g*4+2] = rr.z; rows[g*4+3] = rr.w;
                const int c4[4] = {cc.x, cc.y, cc.z, cc.w};
                const float d4[4] = {dd.x, dd.y, dd.z, dd.w};
                const float m4[4] = {mm.x, mm.y, mm.z, mm.w};
#pragma unroll
                for (int i = 0; i < 4; ++i) {
                    const int ii = g * 4 + i;
                    recs[ii].x = (unsigned)c4[i] | ((unsigned)(rows[ii] & 63) << 24);
                    recs[ii].y = (unsigned)f2bf(d4[i]) |
                                 ((unsigned)f2bf(m4[i] * NORM_INV) << 16);
                    const int bk = rows[ii] >> 6;
                    const int sh = (bk & 1) << 4;
                    rank[ii] = (atomicAdd(&lh[bk >> 1], 1 << sh) >> sh) & 0xffff;
                }
            } else {
#pragma unroll
                for (int i = 0; i < 4; ++i) {
                    const int ii = g * 4 + i;
                    const int ee = e + i;
                    if (ee < N_EDGES) {
                        rows[ii] = edges[ee];
                        recs[ii].x = (unsigned)edges[N_EDGES + ee] |
                                     ((unsigned)(rows[ii] & 63) << 24);
                        recs[ii].y = (unsigned)f2bf(dist[ee]) |
                                     ((unsigned)f2bf(emask[ee] * NORM_INV) << 16);
                        const int bk = rows[ii] >> 6;
                        const int sh = (bk & 1) << 4;
                        rank[ii] = (atomicAdd(&lh[bk >> 1], 1 << sh) >> sh) & 0xffff;
                    } else {
                        rows[ii] = -1;
                    }
                }
            }
        }
        __syncthreads();

        // Phase B: 8-bins/thread exclusive scan over 1568 packed bins.
        const int t4 = tid * 4;
        int li[4];
#pragma unroll
        for (int g = 0; g < 4; ++g) li[g] = (t4 + g < HB_PK) ? lh[t4 + g] : 0;
        int cs[8];
#pragma unroll
        for (int g = 0; g < 4; ++g) {
            cs[2*g]   = li[g] & 0xffff;
            cs[2*g+1] = (li[g] >> 16) & 0xffff;
        }
        int S = 0;
#pragma unroll
        for (int k = 0; k < 8; ++k) S += cs[k];
        int sc = S;
#pragma unroll
        for (int off = 1; off < 64; off <<= 1) {
            int u = __shfl_up(sc, off);
            if (lane >= off) sc += u;
        }
        if (lane == 63) wsum[w] = sc;
        __syncthreads();
        int wbase = 0;
        if (w > 0) wbase = wsum[0];
        if (w > 1) wbase += wsum[1];
        if (w > 2) wbase += wsum[2];
        int run = sc - S + wbase;
#pragma unroll
        for (int g = 0; g < 4; ++g) {
            const int lo = run; run += cs[2*g];
            const int hi = run; run += cs[2*g+1];
            if (t4 + g < HB_PK) lofsP[t4 + g] = (unsigned)lo | ((unsigned)hi << 16);
        }
        __syncthreads();

        // Phase C: place into LDS sorted by bucket.
#pragma unroll
        for (int i = 0; i < 16; ++i) {
            if (rows[i] >= 0) {
                const int bk = rows[i] >> 6;
                const int base = (lofsP[bk >> 1] >> ((bk & 1) << 4)) & 0xffff;
                lsort[base + rank[i]] = recs[i];
            }
        }
        __syncthreads();

        // Phase D: fully-coalesced slice write-out + ofsT row.
        for (int s = tid; s < total; s += 256)
            srec[(size_t)blk * SC_EDGES + s] = lsort[s];
        for (int b = tid; b < 1564; b += 256)
            ofsT[blk * OFS_STRIDE + b] =
                (lofsP[b >> 1] >> ((b & 1) << 4)) & 0xffff;   // [1563] == total
        return;
    }

    // ------------------- projection personality -------------------
    const int tid = threadIdx.x;
    const int lane = tid & 63;
    const int wv = tid >> 6;
    const int c = lane & 15, q = lane >> 4;

    // In-block fragment build: W hi/lo split + att_W1 a/b fragments -> LDS.
    {
        short8* Lwhi_w = (short8*)pool;
        short8* Lwlo_w = Lwhi_w + 512;
        short8* Lwa_w  = Lwhi_w + 1024;
        short8* Lwb_w  = Lwhi_w + 1536;
        const int nt_b = tid >> 6;
        const int n_b = nt_b * 16 + c;
#pragma unroll
        for (int ks = 0; ks < 2; ++ks) {
            const int k0 = ks * 32 + q * 8;
            short8 hi8, lo8, a8, b8;
#pragma unroll
            for (int jj = 0; jj < 8; ++jj) {
                float w = W[n_b * 64 + k0 + jj];
                unsigned short hh = f2bf(w);
                hi8[jj] = (short)hh;
                lo8[jj] = (short)f2bf(w - bf2f(hh));
                a8[jj] = (short)f2bf(att_W1[n_b * 129 + k0 + jj]);
                b8[jj] = (short)f2bf(att_W1[n_b * 129 + 64 + k0 + jj]);
            }
            const int idx = (nt_b * 2 + ks) * 64 + lane;
            Lwhi_w[idx] = hi8; Lwlo_w[idx] = lo8; Lwa_w[idx] = a8; Lwb_w[idx] = b8;
        }
    }
    __syncthreads();
    const short8* Lwhi = (const short8*)pool;
    const short8* Lwlo = Lwhi + 512;
    const short8* Lwa  = Lwhi + 1024;
    const short8* Lwb  = Lwhi + 1536;

    const int tile = (blockIdx.x - SC_BLOCKS) * 4 + wv;
    const bool valid = (tile < N_TILES);
    const int n0 = valid ? tile * 16 : 0;

    float bias[4];
#pragma unroll
    for (int nt = 0; nt < 4; ++nt) bias[nt] = bl[nt * 16 + c];

    short8 Ahi[2], Alo[2];
#pragma unroll
    for (int ks = 0; ks < 2; ++ks) {
        const float* hp = h + (size_t)(n0 + c) * 64 + ks * 32 + q * 8;
        f32x4 p0 = *(const f32x4*)hp;
        f32x4 p1 = *(const f32x4*)(hp + 4);
        short8 hi8, lo8;
#pragma unroll
        for (int jj = 0; jj < 4; ++jj) {
            unsigned short hh = f2bf(p0[jj]);
            hi8[jj] = (short)hh; lo8[jj] = (short)f2bf(p0[jj] - bf2f(hh));
            unsigned short h2 = f2bf(p1[jj]);
            hi8[4 + jj] = (short)h2; lo8[4 + jj] = (short)f2bf(p1[jj] - bf2f(h2));
        }
        Ahi[ks] = hi8; Alo[ks] = lo8;
    }

    f32x4 xacc[4] = {{0,0,0,0},{0,0,0,0},{0,0,0,0},{0,0,0,0}};
#pragma unroll
    for (int ks = 0; ks < 2; ++ks)
#pragma unroll
        for (int nt = 0; nt < 4; ++nt) {
            const short8 fhi = Lwhi[(nt * 2 + ks) * 64 + lane];
            const short8 flo = Lwlo[(nt * 2 + ks) * 64 + lane];
            xacc[nt] = __builtin_amdgcn_mfma_f32_16x16x32_bf16(Ahi[ks], fhi, xacc[nt], 0, 0, 0);
            xacc[nt] = __builtin_amdgcn_mfma_f32_16x16x32_bf16(Ahi[ks], flo, xacc[nt], 0, 0, 0);
            xacc[nt] = __builtin_amdgcn_mfma_f32_16x16x32_bf16(Alo[ks], fhi, xacc[nt], 0, 0, 0);
        }

    // whi/wlo fragments are dead from here; reuse [0:9216) of pool for lw.
    __syncthreads();

    unsigned short* lw = (unsigned short*)pool + wv * (16 * 72);
#pragma unroll
    for (int r = 0; r < 4; ++r) {
        const int node = n0 + q * 4 + r;
        unsigned short xb[4];
#pragma unroll
        for (int nt = 0; nt < 4; ++nt) {
            unsigned short v16 = f2bf(xacc[nt][r] + bias[nt]);
            xb[nt] = v16;
            lw[(q * 4 + r) * 72 + nt * 16 + c] = v16;
        }
        if (valid) {
            uint2 pk;
            pk.x = (unsigned)xb[0] | ((unsigned)xb[1] << 16);
            pk.y = (unsigned)xb[2] | ((unsigned)xb[3] << 16);
            *(uint2*)(xv + (size_t)node * 128 + c * 8) = pk;
        }
    }

    short8 Ax[2];
#pragma unroll
    for (int ks = 0; ks < 2; ++ks)
        Ax[ks] = *(const short8*)&lw[c * 72 + ks * 32 + q * 8];

    f32x4 uacc[4] = {{0,0,0,0},{0,0,0,0},{0,0,0,0},{0,0,0,0}};
    f32x4 vacc[4] = {{0,0,0,0},{0,0,0,0},{0,0,0,0},{0,0,0,0}};
#pragma unroll
    for (int ks = 0; ks < 2; ++ks)
#pragma unroll
        for (int nt = 0; nt < 4; ++nt) {
            const short8 fa = Lwa[(nt * 2 + ks) * 64 + lane];
            const short8 fb = Lwb[(nt * 2 + ks) * 64 + lane];
            uacc[nt] = __builtin_amdgcn_mfma_f32_16x16x32_bf16(Ax[ks], fa, uacc[nt], 0, 0, 0);
            vacc[nt] = __builtin_amdgcn_mfma_f32_16x16x32_bf16(Ax[ks], fb, vacc[nt], 0, 0, 0);
        }
    if (valid) {
#pragma unroll
        for (int r = 0; r < 4; ++r) {
            const int node = n0 + q * 4 + r;
            uint2 pu;
            pu.x = (unsigned)f2bf(uacc[0][r] * L2E) | ((unsigned)f2bf(uacc[1][r] * L2E) << 16);
            pu.y = (unsigned)f2bf(uacc[2][r] * L2E) | ((unsigned)f2bf(uacc[3][r] * L2E) << 16);
            *(uint2*)(u_bf + (size_t)node * 64 + c * 4) = pu;
            uint2 pk;
            pk.x = (unsigned)f2bf(vacc[0][r] * L2E) | ((unsigned)f2bf(vacc[1][r] * L2E) << 16);
            pk.y = (unsigned)f2bf(vacc[2][r] * L2E) | ((unsigned)f2bf(vacc[3][r] * L2E) << 16);
            *(uint2*)(xv + (size_t)node * 128 + c * 8 + 4) = pk;
        }
    }
}

// ---------------------------------------------------------------------------
// agg_fused: one block (256 thr, 4 waves) per 64-row bucket. 1563 blocks ->
// ~6 blocks/CU against an 8-resident cap (LDS ~14.5 KB, VGPR<=64).
// Phase 0: scan the 245 slice-extent lengths -> dbase[]; build ltab in LDS.
// Phase 1: distributed gather into registers (<=4/thread) + LDS histogram.
// Phase 2: single-wave padded (x4) scan over 64 rows -> LDS row starts.
// Phase 3: place held records via cur atomics.
// Phase 4: each wave aggregates 16 rows (stride 4), then LN + silu.
// ---------------------------------------------------------------------------
__global__ __launch_bounds__(256, 8) void agg_fused(
    const uint2* __restrict__ srec, const int* __restrict__ ofsT,
    const unsigned short* __restrict__ xv, const unsigned short* __restrict__ u_bf,
    const float* __restrict__ att_W1, const float* __restrict__ att_b1,
    const float* __restrict__ att_W2, const float* __restrict__ att_b2,
    const float* __restrict__ ln_g, const float* __restrict__ ln_b,
    float* __restrict__ out) {
    __shared__ __align__(16) uint2 lrecs[CAP + 16];
    __shared__ float4 ltab[64];
    __shared__ int hist[64];
    __shared__ int rst[65];
    __shared__ int cur[64];
    __shared__ int sst[256];
    __shared__ int dbase[257];
    __shared__ int wsum4[4];

    const int b = blockIdx.x;
    const int tid = threadIdx.x;
    const int lane = tid & 63;
    const int wv = tid >> 6;

    if (tid < 64) hist[tid] = 0;
    if (tid >= 192) {
        const int f = tid - 192;
        ltab[f] = make_float4(att_W2[f] * LN2, att_W1[f * 129 + 128] * L2E,
                              att_b1[f] * L2E, 0.f);
    }

    // Phase 0: extent lengths + exclusive scan over 256 threads.
    int stv = 0, len = 0, sc0 = 0;
    {
        if (tid < SC_BLOCKS) {
            stv = ofsT[tid * OFS_STRIDE + b];
            len = ofsT[tid * OFS_STRIDE + b + 1] - stv;
        }
        sst[tid] = stv;
        sc0 = len;
#pragma unroll
        for (int off = 1; off < 64; off <<= 1) {
            int u = __shfl_up(sc0, off);
            if (lane >= off) sc0 += u;
        }
        if (lane == 63) wsum4[wv] = sc0;
    }
    __syncthreads();
    {
        int wbase = 0;
        if (wv > 0) wbase = wsum4[0];
        if (wv > 1) wbase += wsum4[1];
        if (wv > 2) wbase += wsum4[2];
        dbase[tid] = wbase + sc0 - len;
        if (tid == 255) dbase[256] = wbase + sc0;
    }
    __syncthreads();
    const int cnt = dbase[245];

    // Phase 1: distributed gather into registers + histogram.
    uint2 rec0, rec1, rec2, rec3;
    int lr0 = -1, lr1 = -1, lr2 = -1, lr3 = -1;
#define GATHER(I, RC, LR)                                                     \
    {                                                                         \
        const int m = tid + I * 256;                                          \
        if (m < cnt) {                                                        \
            int lo = 0, hi = 245;                                             \
            while (hi - lo > 1) {                                             \
                const int mid = (lo + hi) >> 1;                               \
                if (dbase[mid] <= m) lo = mid; else hi = mid;                 \
            }                                                                 \
            RC = srec[(size_t)lo * SC_EDGES + sst[lo] + (m - dbase[lo])];     \
            LR = (int)(RC.x >> 24);                                           \
            RC.x &= 0x00FFFFFFu;                                              \
            atomicAdd(&hist[LR], 1);                                          \
        }                                                                     \
    }
    GATHER(0, rec0, lr0)
    GATHER(1, rec1, lr1)
    GATHER(2, rec2, lr2)
    GATHER(3, rec3, lr3)
#undef GATHER
    __syncthreads();

    // Phase 2: single-wave padded scan over 64 rows.
    if (tid < 64) {
        const int c = hist[tid];
        const int p = (c + 3) & ~3;
        int sc = p;
#pragma unroll
        for (int off = 1; off < 64; off <<= 1) {
            int u = __shfl_up(sc, off);
            if (lane >= off) sc += u;
        }
        const int excl = sc - p;
        rst[tid] = excl;
        cur[tid] = excl;
        uint2 z; z.x = 0; z.y = 0;
        for (int i = c; i < p; ++i) lrecs[excl + i] = z;
        if (tid == 63) {
            rst[64] = excl + p;
            for (int i = 0; i < 16; ++i) lrecs[excl + p + i] = z;
        }
    }
    __syncthreads();

    // Phase 3: place held records (counting-sort into LDS).
    if (lr0 >= 0) lrecs[atomicAdd(&cur[lr0], 1)] = rec0;
    if (lr1 >= 0) lrecs[atomicAdd(&cur[lr1], 1)] = rec1;
    if (lr2 >= 0) lrecs[atomicAdd(&cur[lr2], 1)] = rec2;
    if (lr3 >= 0) lrecs[atomicAdd(&cur[lr3], 1)] = rec3;
    __syncthreads();

    // Phase 4: aggregation. Wave wv handles local rows wv, wv+4, ..., wv+60.
    const int j = lane & 15;
    const int sl = lane >> 4;
    const float4 t0 = ltab[j], t1 = ltab[j + 16], t2 = ltab[j + 32], t3 = ltab[j + 48];
    const float b2L = att_b2[0] * L2E;
    const float gg = ln_g[lane], bb = ln_b[lane];
    const unsigned* xvu = (const unsigned*)xv;

#pragma unroll 1
    for (int k = 0; k < 16; ++k) {
        const int lrw = wv + 4 * k;
        const int r = b * 64 + lrw;
        if (r >= N_NODES) break;

        const uint2 uu = *(const uint2*)(u_bf + (size_t)r * 64 + j * 4);
        const float base0 = __uint_as_float(uu.x << 16) + t0.z;
        const float base1 = __uint_as_float(uu.x & 0xffff0000u) + t1.z;
        const float base2 = __uint_as_float(uu.y << 16) + t2.z;
        const float base3 = __uint_as_float(uu.y & 0xffff0000u) + t3.z;

        const int s0 = rst[lrw];
        const int e1 = rst[lrw + 1];

        float a0 = 0.f, a1 = 0.f, a2 = 0.f, a3 = 0.f;
        if (e1 > s0) {
            uint2 recA = lrecs[s0 + sl];
            uint4 xvA = *(const uint4*)(xvu + (size_t)recA.x * 64 + j * 4);
            for (int e = s0; e < e1; e += 4) {
                const uint2 recB = lrecs[e + 4 + sl];
                const uint4 xvB = *(const uint4*)(xvu + (size_t)recB.x * 64 + j * 4);

                const float dist = __uint_as_float(recA.y << 16);
                const float emN = __uint_as_float(recA.y & 0xffff0000u);
                const float x0 = __uint_as_float(xvA.x << 16);
                const float x1 = __uint_as_float(xvA.x & 0xffff0000u);
                const float x2 = __uint_as_float(xvA.y << 16);
                const float x3 = __uint_as_float(xvA.y & 0xffff0000u);
                const float v0 = __uint_as_float(xvA.z << 16);
                const float v1 = __uint_as_float(xvA.z & 0xffff0000u);
                const float v2 = __uint_as_float(xvA.w << 16);
                const float v3 = __uint_as_float(xvA.w & 0xffff0000u);
                float pv = 0.f, pre, sg;
                pre = fmaf(dist, t0.y, base0) + v0;
                sg = __builtin_amdgcn_rcpf(1.f + __builtin_amdgcn_exp2f(-pre));
                pv = fmaf(pre * sg, t0.x, pv);
                pre = fmaf(dist, t1.y, base1) + v1;
                sg = __builtin_amdgcn_rcpf(1.f + __builtin_amdgcn_exp2f(-pre));
                pv = fmaf(pre * sg, t1.x, pv);
                pre = fmaf(dist, t2.y, base2) + v2;
                sg = __builtin_amdgcn_rcpf(1.f + __builtin_amdgcn_exp2f(-pre));
                pv = fmaf(pre * sg, t2.x, pv);
                pre = fmaf(dist, t3.y, base3) + v3;
                sg = __builtin_amdgcn_rcpf(1.f + __builtin_amdgcn_exp2f(-pre));
                pv = fmaf(pre * sg, t3.x, pv);
                pv += __shfl_xor(pv, 1); pv += __shfl_xor(pv, 2);
                pv += __shfl_xor(pv, 4); pv += __shfl_xor(pv, 8);
                const float sp = fmaf(pv, L2E, b2L);
                const float att =
                    emN * __builtin_amdgcn_rcpf(1.f + __builtin_amdgcn_exp2f(-sp));
                a0 = fmaf(att, x0, a0); a1 = fmaf(att, x1, a1);
                a2 = fmaf(att, x2, a2); a3 = fmaf(att, x3, a3);
                recA = recB; xvA = xvB;
            }
        }
        a0 += __shfl_xor(a0, 16); a0 += __shfl_xor(a0, 32);
        a1 += __shfl_xor(a1, 16); a1 += __shfl_xor(a1, 32);
        a2 += __shfl_xor(a2, 16); a2 += __shfl_xor(a2, 32);
        a3 += __shfl_xor(a3, 16); a3 += __shfl_xor(a3, 32);

        const uint2 xr = *(const uint2*)(xvu + (size_t)r * 64 + j * 4);
        const float o0 = __uint_as_float(xr.x << 16) + a0;
        const float o1 = __uint_as_float(xr.x & 0xffff0000u) + a1;
        const float o2 = __uint_as_float(xr.y << 16) + a2;
        const float o3 = __uint_as_float(xr.y & 0xffff0000u) + a3;

        float ssum = o0 + o1 + o2 + o3;
        ssum += __shfl_xor(ssum, 1); ssum += __shfl_xor(ssum, 2);
        ssum += __shfl_xor(ssum, 4); ssum += __shfl_xor(ssum, 8);
        const float mu = ssum * (1.f / 64.f);
        const float d0 = o0 - mu, d1 = o1 - mu, d2 = o2 - mu, d3 = o3 - mu;
        float vs = d0 * d0 + d1 * d1 + d2 * d2 + d3 * d3;
        vs += __shfl_xor(vs, 1); vs += __shfl_xor(vs, 2);
        vs += __shfl_xor(vs, 4); vs += __shfl_xor(vs, 8);
        const float rstd = rsqrtf(vs * (1.f / 64.f) + LN_EPS);

        const float dk = (sl == 0) ? d0 : (sl == 1) ? d1 : (sl == 2) ? d2 : d3;
        const float y = fmaf(dk * rstd, gg, bb);
        out[(size_t)r * 64 + lane] =
            y * __builtin_amdgcn_rcpf(1.f + __builtin_amdgcn_exp2f(-y * L2E));
    }
}

extern "C" void kernel_launch(void* const* d_in, const int* in_sizes, int n_in,
                              void* d_out, int out_size, void* d_ws, size_t ws_size,
                              hipStream_t stream) {
    const float* h      = (const float*)d_in[0];
    const float* dist   = (const float*)d_in[1];
    const int*   edges  = (const int*)d_in[2];
    const float* emask  = (const float*)d_in[4];
    const float* W_lin  = (const float*)d_in[5];
    const float* b_lin  = (const float*)d_in[6];
    const float* att_W1 = (const float*)d_in[7];
    const float* att_b1 = (const float*)d_in[8];
    const float* att_W2 = (const float*)d_in[9];
    const float* att_b2 = (const float*)d_in[10];
    const float* ln_g   = (const float*)d_in[11];
    const float* ln_b   = (const float*)d_in[12];
    float* out = (float*)d_out;

    char* ws = (char*)d_ws;
    unsigned short* xv   = (unsigned short*)ws;                  // 25,600,000
    unsigned short* u_bf = (unsigned short*)(ws + 25600000);     // 12,800,000
    uint2* srec          = (uint2*)(ws + 38400000);              //  8,028,160 (245*4096*8)
    int* ofsT            = (int*)(ws + 46428160);                //  1,536,640 (245*1568*4)

    proj_scatter<<<SC_BLOCKS + PROJ_BLOCKS, 256, 0, stream>>>(
        h, b_lin, W_lin, att_W1, edges, dist, emask, srec, ofsT, xv, u_bf);
    agg_fused<<<N_BUCKETS, 256, 0, stream>>>(srec, ofsT, xv, u_bf,
                                             att_W1, att_b1, att_W2, att_b2,
                                             ln_g, ln_b, out);
}

// Round 8
// 192.054 us; speedup vs baseline: 1.4654x; 1.0013x over previous
//
#include <hip/hip_runtime.h>
#include <hip/hip_bf16.h>

#define N_NODES 100000
#define N_EDGES 1000000
#define DIM 64
#define NORM_INV 0.01f
#define LN_EPS 1e-5f
#define N_TILES 6250          // N_NODES/16
#define PROJ_BLOCKS 1563      // ceil(6250/4)
#define N_BUCKETS 1563        // ceil(100000/64), 64 rows per bucket
#define HB_PK 784             // packed-int count: 1568 u16 bins (>=1564)
#define SC_EDGES 4096         // edges per scatter slice
#define SC_BLOCKS 245         // ceil(1e6/4096)
#define OFS_STRIDE 1568       // u16 per ofsT row (1564 used, padded)
#define L2E 1.4426950408889634f
#define LN2 0.6931471805599453f
#define CAP 1280              // LDS record capacity/bucket (mean padded ~736)

typedef __attribute__((ext_vector_type(8))) short short8;
typedef __attribute__((ext_vector_type(4))) float f32x4;

__device__ __forceinline__ unsigned short f2bf(float f) {
    union { float f; unsigned u; } x; x.f = f;
    unsigned r = x.u + 0x7FFFu + ((x.u >> 16) & 1u);
    return (unsigned short)(r >> 16);
}
__device__ __forceinline__ float bf2f(unsigned short s) {
    union { unsigned u; float f; } x; x.u = ((unsigned)s) << 16; return x.f;
}

// ---------------------------------------------------------------------------
// proj_scatter fat kernel — no global atomics, no prep kernel.
// blocks [0, SC_BLOCKS): fixed-slice scatter. 1563 bins (64-row buckets),
//   two 16-bit counters packed per LDS int (counts <= 4096, no carry).
//   LDS: lh 784 ints + lofsP 784 ints + lsort 4096 uint2 = 39,040 B.
//   srec.x = col | lrow<<24 (lrow = row & 63). ofsT stored as u16.
// blocks [SC_BLOCKS, +PROJ_BLOCKS): MFMA projection, 1 tile/wave; weight
//   fragments built in-block into LDS (32 KB), whi/wlo region reused for lw.
// ---------------------------------------------------------------------------
__global__ __launch_bounds__(256) void proj_scatter(
    const float* __restrict__ h, const float* __restrict__ bl,
    const float* __restrict__ W, const float* __restrict__ att_W1,
    const int* __restrict__ edges, const float* __restrict__ dist,
    const float* __restrict__ emask,
    uint2* __restrict__ srec, unsigned short* __restrict__ ofsT,
    unsigned short* __restrict__ xv, unsigned short* __restrict__ u_bf) {
    __shared__ __align__(16) char pool[39168];
    __shared__ int wsum[4];

    if (blockIdx.x < SC_BLOCKS) {
        // ------------------- scatter personality -------------------
        int* lh = (int*)pool;                       // [HB_PK] packed counts
        int* lofsP = (int*)pool + HB_PK;            // [HB_PK] packed offsets
        uint2* lsort = (uint2*)(pool + 6272);       // [SC_EDGES]
        const int blk = blockIdx.x;
        const int tid = threadIdx.x;
        const int lane = tid & 63;
        const int w = tid >> 6;
        for (int i = tid; i < HB_PK; i += 256) lh[i] = 0;
        __syncthreads();

        const int eb = blk * SC_EDGES;
        const int total = min(SC_EDGES, N_EDGES - eb);

        // Phase A: load 16 edges/thread, histogram with rank capture.
        int rows[16], rank[16];
        uint2 recs[16];
        const int e0 = eb + tid * 16;
#pragma unroll
        for (int g = 0; g < 4; ++g) {
            const int e = e0 + g * 4;
            if (e + 4 <= N_EDGES) {
                const int4 rr = *(const int4*)(edges + e);
                const int4 cc = *(const int4*)(edges + N_EDGES + e);
                const float4 dd = *(const float4*)(dist + e);
                const float4 mm = *(const float4*)(emask + e);
                rows[g*4+0] = rr.x; rows[g*4+1] = rr.y; rows[g*4+2] = rr.z; rows[g*4+3] = rr.w;
                const int c4[4] = {cc.x, cc.y, cc.z, cc.w};
                const float d4[4] = {dd.x, dd.y, dd.z, dd.w};
                const float m4[4] = {mm.x, mm.y, mm.z, mm.w};
#pragma unroll
                for (int i = 0; i < 4; ++i) {
                    const int ii = g * 4 + i;
                    recs[ii].x = (unsigned)c4[i] | ((unsigned)(rows[ii] & 63) << 24);
                    recs[ii].y = (unsigned)f2bf(d4[i]) |
                                 ((unsigned)f2bf(m4[i] * NORM_INV) << 16);
                    const int bk = rows[ii] >> 6;
                    const int sh = (bk & 1) << 4;
                    rank[ii] = (atomicAdd(&lh[bk >> 1], 1 << sh) >> sh) & 0xffff;
                }
            } else {
#pragma unroll
                for (int i = 0; i < 4; ++i) {
                    const int ii = g * 4 + i;
                    const int ee = e + i;
                    if (ee < N_EDGES) {
                        rows[ii] = edges[ee];
                        recs[ii].x = (unsigned)edges[N_EDGES + ee] |
                                     ((unsigned)(rows[ii] & 63) << 24);
                        recs[ii].y = (unsigned)f2bf(dist[ee]) |
                                     ((unsigned)f2bf(emask[ee] * NORM_INV) << 16);
                        const int bk = rows[ii] >> 6;
                        const int sh = (bk & 1) << 4;
                        rank[ii] = (atomicAdd(&lh[bk >> 1], 1 << sh) >> sh) & 0xffff;
                    } else {
                        rows[ii] = -1;
                    }
                }
            }
        }
        __syncthreads();

        // Phase B: 8-bins/thread exclusive scan over 1568 packed bins.
        const int t4 = tid * 4;
        int li[4];
#pragma unroll
        for (int g = 0; g < 4; ++g) li[g] = (t4 + g < HB_PK) ? lh[t4 + g] : 0;
        int cs[8];
#pragma unroll
        for (int g = 0; g < 4; ++g) {
            cs[2*g]   = li[g] & 0xffff;
            cs[2*g+1] = (li[g] >> 16) & 0xffff;
        }
        int S = 0;
#pragma unroll
        for (int k = 0; k < 8; ++k) S += cs[k];
        int sc = S;
#pragma unroll
        for (int off = 1; off < 64; off <<= 1) {
            int u = __shfl_up(sc, off);
            if (lane >= off) sc += u;
        }
        if (lane == 63) wsum[w] = sc;
        __syncthreads();
        int wbase = 0;
        if (w > 0) wbase = wsum[0];
        if (w > 1) wbase += wsum[1];
        if (w > 2) wbase += wsum[2];
        int run = sc - S + wbase;
#pragma unroll
        for (int g = 0; g < 4; ++g) {
            const int lo = run; run += cs[2*g];
            const int hi = run; run += cs[2*g+1];
            if (t4 + g < HB_PK) lofsP[t4 + g] = (unsigned)lo | ((unsigned)hi << 16);
        }
        __syncthreads();

        // Phase C: place into LDS sorted by bucket.
#pragma unroll
        for (int i = 0; i < 16; ++i) {
            if (rows[i] >= 0) {
                const int bk = rows[i] >> 6;
                const int base = (lofsP[bk >> 1] >> ((bk & 1) << 4)) & 0xffff;
                lsort[base + rank[i]] = recs[i];
            }
        }
        __syncthreads();

        // Phase D: fully-coalesced slice write-out + u16 ofsT row.
        for (int s = tid; s < total; s += 256)
            srec[(size_t)blk * SC_EDGES + s] = lsort[s];
        for (int b = tid; b < 1564; b += 256)
            ofsT[blk * OFS_STRIDE + b] =
                (unsigned short)((lofsP[b >> 1] >> ((b & 1) << 4)) & 0xffff);
        return;
    }

    // ------------------- projection personality -------------------
    const int tid = threadIdx.x;
    const int lane = tid & 63;
    const int wv = tid >> 6;
    const int c = lane & 15, q = lane >> 4;

    // In-block fragment build: W hi/lo split + att_W1 a/b fragments -> LDS.
    {
        short8* Lwhi_w = (short8*)pool;
        short8* Lwlo_w = Lwhi_w + 512;
        short8* Lwa_w  = Lwhi_w + 1024;
        short8* Lwb_w  = Lwhi_w + 1536;
        const int nt_b = tid >> 6;
        const int n_b = nt_b * 16 + c;
#pragma unroll
        for (int ks = 0; ks < 2; ++ks) {
            const int k0 = ks * 32 + q * 8;
            short8 hi8, lo8, a8, b8;
#pragma unroll
            for (int jj = 0; jj < 8; ++jj) {
                float w = W[n_b * 64 + k0 + jj];
                unsigned short hh = f2bf(w);
                hi8[jj] = (short)hh;
                lo8[jj] = (short)f2bf(w - bf2f(hh));
                a8[jj] = (short)f2bf(att_W1[n_b * 129 + k0 + jj]);
                b8[jj] = (short)f2bf(att_W1[n_b * 129 + 64 + k0 + jj]);
            }
            const int idx = (nt_b * 2 + ks) * 64 + lane;
            Lwhi_w[idx] = hi8; Lwlo_w[idx] = lo8; Lwa_w[idx] = a8; Lwb_w[idx] = b8;
        }
    }
    __syncthreads();
    const short8* Lwhi = (const short8*)pool;
    const short8* Lwlo = Lwhi + 512;
    const short8* Lwa  = Lwhi + 1024;
    const short8* Lwb  = Lwhi + 1536;

    const int tile = (blockIdx.x - SC_BLOCKS) * 4 + wv;
    const bool valid = (tile < N_TILES);
    const int n0 = valid ? tile * 16 : 0;

    float bias[4];
#pragma unroll
    for (int nt = 0; nt < 4; ++nt) bias[nt] = bl[nt * 16 + c];

    short8 Ahi[2], Alo[2];
#pragma unroll
    for (int ks = 0; ks < 2; ++ks) {
        const float* hp = h + (size_t)(n0 + c) * 64 + ks * 32 + q * 8;
        f32x4 p0 = *(const f32x4*)hp;
        f32x4 p1 = *(const f32x4*)(hp + 4);
        short8 hi8, lo8;
#pragma unroll
        for (int jj = 0; jj < 4; ++jj) {
            unsigned short hh = f2bf(p0[jj]);
            hi8[jj] = (short)hh; lo8[jj] = (short)f2bf(p0[jj] - bf2f(hh));
            unsigned short h2 = f2bf(p1[jj]);
            hi8[4 + jj] = (short)h2; lo8[4 + jj] = (short)f2bf(p1[jj] - bf2f(h2));
        }
        Ahi[ks] = hi8; Alo[ks] = lo8;
    }

    f32x4 xacc[4] = {{0,0,0,0},{0,0,0,0},{0,0,0,0},{0,0,0,0}};
#pragma unroll
    for (int ks = 0; ks < 2; ++ks)
#pragma unroll
        for (int nt = 0; nt < 4; ++nt) {
            const short8 fhi = Lwhi[(nt * 2 + ks) * 64 + lane];
            const short8 flo = Lwlo[(nt * 2 + ks) * 64 + lane];
            xacc[nt] = __builtin_amdgcn_mfma_f32_16x16x32_bf16(Ahi[ks], fhi, xacc[nt], 0, 0, 0);
            xacc[nt] = __builtin_amdgcn_mfma_f32_16x16x32_bf16(Ahi[ks], flo, xacc[nt], 0, 0, 0);
            xacc[nt] = __builtin_amdgcn_mfma_f32_16x16x32_bf16(Alo[ks], fhi, xacc[nt], 0, 0, 0);
        }

    // whi/wlo fragments are dead from here; reuse [0:9216) of pool for lw.
    __syncthreads();

    unsigned short* lw = (unsigned short*)pool + wv * (16 * 72);
#pragma unroll
    for (int r = 0; r < 4; ++r) {
        const int node = n0 + q * 4 + r;
        unsigned short xb[4];
#pragma unroll
        for (int nt = 0; nt < 4; ++nt) {
            unsigned short v16 = f2bf(xacc[nt][r] + bias[nt]);
            xb[nt] = v16;
            lw[(q * 4 + r) * 72 + nt * 16 + c] = v16;
        }
        if (valid) {
            uint2 pk;
            pk.x = (unsigned)xb[0] | ((unsigned)xb[1] << 16);
            pk.y = (unsigned)xb[2] | ((unsigned)xb[3] << 16);
            *(uint2*)(xv + (size_t)node * 128 + c * 8) = pk;
        }
    }

    short8 Ax[2];
#pragma unroll
    for (int ks = 0; ks < 2; ++ks)
        Ax[ks] = *(const short8*)&lw[c * 72 + ks * 32 + q * 8];

    f32x4 uacc[4] = {{0,0,0,0},{0,0,0,0},{0,0,0,0},{0,0,0,0}};
    f32x4 vacc[4] = {{0,0,0,0},{0,0,0,0},{0,0,0,0},{0,0,0,0}};
#pragma unroll
    for (int ks = 0; ks < 2; ++ks)
#pragma unroll
        for (int nt = 0; nt < 4; ++nt) {
            const short8 fa = Lwa[(nt * 2 + ks) * 64 + lane];
            const short8 fb = Lwb[(nt * 2 + ks) * 64 + lane];
            uacc[nt] = __builtin_amdgcn_mfma_f32_16x16x32_bf16(Ax[ks], fa, uacc[nt], 0, 0, 0);
            vacc[nt] = __builtin_amdgcn_mfma_f32_16x16x32_bf16(Ax[ks], fb, vacc[nt], 0, 0, 0);
        }
    if (valid) {
#pragma unroll
        for (int r = 0; r < 4; ++r) {
            const int node = n0 + q * 4 + r;
            uint2 pu;
            pu.x = (unsigned)f2bf(uacc[0][r] * L2E) | ((unsigned)f2bf(uacc[1][r] * L2E) << 16);
            pu.y = (unsigned)f2bf(uacc[2][r] * L2E) | ((unsigned)f2bf(uacc[3][r] * L2E) << 16);
            *(uint2*)(u_bf + (size_t)node * 64 + c * 4) = pu;
            uint2 pk;
            pk.x = (unsigned)f2bf(vacc[0][r] * L2E) | ((unsigned)f2bf(vacc[1][r] * L2E) << 16);
            pk.y = (unsigned)f2bf(vacc[2][r] * L2E) | ((unsigned)f2bf(vacc[3][r] * L2E) << 16);
            *(uint2*)(xv + (size_t)node * 128 + c * 8 + 4) = pk;
        }
    }
}

// ---------------------------------------------------------------------------
// agg_fused: one block (256 thr, 4 waves) per 64-row bucket.
// Phase 0: scan the 245 slice-extent lengths (u16 ofsT) -> dbase[]; ltab.
// Phase 1: distributed gather into registers (<=4/thread) + LDS histogram.
// Phase 2: single-wave padded (x4) scan over 64 rows -> LDS row starts.
// Phase 3: place held records via cur atomics.
// Phase 4: each wave aggregates 16 rows (stride 4), LN + silu. The inner
//          loop runs a TRUE 3-deep pipeline: recA/xvA consumed, recB/xvB in
//          flight, recC/xvC issued — the xv gather is issued ~2 iterations
//          (~300 VALU cycles) before use.
// ---------------------------------------------------------------------------
__global__ __launch_bounds__(256, 8) void agg_fused(
    const uint2* __restrict__ srec, const unsigned short* __restrict__ ofsT,
    const unsigned short* __restrict__ xv, const unsigned short* __restrict__ u_bf,
    const float* __restrict__ att_W1, const float* __restrict__ att_b1,
    const float* __restrict__ att_W2, const float* __restrict__ att_b2,
    const float* __restrict__ ln_g, const float* __restrict__ ln_b,
    float* __restrict__ out) {
    __shared__ __align__(16) uint2 lrecs[CAP + 16];
    __shared__ float4 ltab[64];
    __shared__ int hist[64];
    __shared__ int rst[65];
    __shared__ int cur[64];
    __shared__ int sst[256];
    __shared__ int dbase[257];
    __shared__ int wsum4[4];

    const int b = blockIdx.x;
    const int tid = threadIdx.x;
    const int lane = tid & 63;
    const int wv = tid >> 6;

    if (tid < 64) hist[tid] = 0;
    if (tid >= 192) {
        const int f = tid - 192;
        ltab[f] = make_float4(att_W2[f] * LN2, att_W1[f * 129 + 128] * L2E,
                              att_b1[f] * L2E, 0.f);
    }

    // Phase 0: extent lengths + exclusive scan over 256 threads.
    int stv = 0, len = 0, sc0 = 0;
    {
        if (tid < SC_BLOCKS) {
            stv = (int)ofsT[tid * OFS_STRIDE + b];
            len = (int)ofsT[tid * OFS_STRIDE + b + 1] - stv;
        }
        sst[tid] = stv;
        sc0 = len;
#pragma unroll
        for (int off = 1; off < 64; off <<= 1) {
            int u = __shfl_up(sc0, off);
            if (lane >= off) sc0 += u;
        }
        if (lane == 63) wsum4[wv] = sc0;
    }
    __syncthreads();
    {
        int wbase = 0;
        if (wv > 0) wbase = wsum4[0];
        if (wv > 1) wbase += wsum4[1];
        if (wv > 2) wbase += wsum4[2];
        dbase[tid] = wbase + sc0 - len;
        if (tid == 255) dbase[256] = wbase + sc0;
    }
    __syncthreads();
    const int cnt = dbase[245];

    // Phase 1: distributed gather into registers + histogram.
    uint2 rec0, rec1, rec2, rec3;
    int lr0 = -1, lr1 = -1, lr2 = -1, lr3 = -1;
#define GATHER(I, RC, LR)                                                     \
    {                                                                         \
        const int m = tid + I * 256;                                          \
        if (m < cnt) {                                                        \
            int lo = 0, hi = 245;                                             \
            while (hi - lo > 1) {                                             \
                const int mid = (lo + hi) >> 1;                               \
                if (dbase[mid] <= m) lo = mid; else hi = mid;                 \
            }                                                                 \
            RC = srec[(size_t)lo * SC_EDGES + sst[lo] + (m - dbase[lo])];     \
            LR = (int)(RC.x >> 24);                                           \
            RC.x &= 0x00FFFFFFu;                                              \
            atomicAdd(&hist[LR], 1);                                          \
        }                                                                     \
    }
    GATHER(0, rec0, lr0)
    GATHER(1, rec1, lr1)
    GATHER(2, rec2, lr2)
    GATHER(3, rec3, lr3)
#undef GATHER
    __syncthreads();

    // Phase 2: single-wave padded scan over 64 rows.
    if (tid < 64) {
        const int c = hist[tid];
        const int p = (c + 3) & ~3;
        int sc = p;
#pragma unroll
        for (int off = 1; off < 64; off <<= 1) {
            int u = __shfl_up(sc, off);
            if (lane >= off) sc += u;
        }
        const int excl = sc - p;
        rst[tid] = excl;
        cur[tid] = excl;
        uint2 z; z.x = 0; z.y = 0;
        for (int i = c; i < p; ++i) lrecs[excl + i] = z;
        if (tid == 63) {
            rst[64] = excl + p;
            for (int i = 0; i < 16; ++i) lrecs[excl + p + i] = z;
        }
    }
    __syncthreads();

    // Phase 3: place held records (counting-sort into LDS).
    if (lr0 >= 0) lrecs[atomicAdd(&cur[lr0], 1)] = rec0;
    if (lr1 >= 0) lrecs[atomicAdd(&cur[lr1], 1)] = rec1;
    if (lr2 >= 0) lrecs[atomicAdd(&cur[lr2], 1)] = rec2;
    if (lr3 >= 0) lrecs[atomicAdd(&cur[lr3], 1)] = rec3;
    __syncthreads();

    // Phase 4: aggregation. Wave wv handles local rows wv, wv+4, ..., wv+60.
    const int j = lane & 15;
    const int sl = lane >> 4;
    const float4 t0 = ltab[j], t1 = ltab[j + 16], t2 = ltab[j + 32], t3 = ltab[j + 48];
    const float b2L = att_b2[0] * L2E;
    const float gg = ln_g[lane], bb = ln_b[lane];
    const unsigned* xvu = (const unsigned*)xv;

#pragma unroll 1
    for (int k = 0; k < 16; ++k) {
        const int lrw = wv + 4 * k;
        const int r = b * 64 + lrw;
        if (r >= N_NODES) break;

        const uint2 uu = *(const uint2*)(u_bf + (size_t)r * 64 + j * 4);
        const float base0 = __uint_as_float(uu.x << 16) + t0.z;
        const float base1 = __uint_as_float(uu.x & 0xffff0000u) + t1.z;
        const float base2 = __uint_as_float(uu.y << 16) + t2.z;
        const float base3 = __uint_as_float(uu.y & 0xffff0000u) + t3.z;

        const int s0 = rst[lrw];
        const int e1 = rst[lrw + 1];

        float a0 = 0.f, a1 = 0.f, a2 = 0.f, a3 = 0.f;
        if (e1 > s0) {
            uint2 recA = lrecs[s0 + sl];
            uint2 recB = lrecs[s0 + 4 + sl];
            uint4 xvA = *(const uint4*)(xvu + (size_t)recA.x * 64 + j * 4);
            uint4 xvB = *(const uint4*)(xvu + (size_t)recB.x * 64 + j * 4);
            for (int e = s0; e < e1; e += 4) {
                const uint2 recC = lrecs[e + 8 + sl];
                const uint4 xvC = *(const uint4*)(xvu + (size_t)recC.x * 64 + j * 4);

                const float dist = __uint_as_float(recA.y << 16);
                const float emN = __uint_as_float(recA.y & 0xffff0000u);
                const float x0 = __uint_as_float(xvA.x << 16);
                const float x1 = __uint_as_float(xvA.x & 0xffff0000u);
                const float x2 = __uint_as_float(xvA.y << 16);
                const float x3 = __uint_as_float(xvA.y & 0xffff0000u);
                const float v0 = __uint_as_float(xvA.z << 16);
                const float v1 = __uint_as_float(xvA.z & 0xffff0000u);
                const float v2 = __uint_as_float(xvA.w << 16);
                const float v3 = __uint_as_float(xvA.w & 0xffff0000u);
                float pv = 0.f, pre, sg;
                pre = fmaf(dist, t0.y, base0) + v0;
                sg = __builtin_amdgcn_rcpf(1.f + __builtin_amdgcn_exp2f(-pre));
                pv = fmaf(pre * sg, t0.x, pv);
                pre = fmaf(dist, t1.y, base1) + v1;
                sg = __builtin_amdgcn_rcpf(1.f + __builtin_amdgcn_exp2f(-pre));
                pv = fmaf(pre * sg, t1.x, pv);
                pre = fmaf(dist, t2.y, base2) + v2;
                sg = __builtin_amdgcn_rcpf(1.f + __builtin_amdgcn_exp2f(-pre));
                pv = fmaf(pre * sg, t2.x, pv);
                pre = fmaf(dist, t3.y, base3) + v3;
                sg = __builtin_amdgcn_rcpf(1.f + __builtin_amdgcn_exp2f(-pre));
                pv = fmaf(pre * sg, t3.x, pv);
                pv += __shfl_xor(pv, 1); pv += __shfl_xor(pv, 2);
                pv += __shfl_xor(pv, 4); pv += __shfl_xor(pv, 8);
                const float sp = fmaf(pv, L2E, b2L);
                const float att =
                    emN * __builtin_amdgcn_rcpf(1.f + __builtin_amdgcn_exp2f(-sp));
                a0 = fmaf(att, x0, a0); a1 = fmaf(att, x1, a1);
                a2 = fmaf(att, x2, a2); a3 = fmaf(att, x3, a3);
                recA = recB; xvA = xvB; recB = recC; xvB = xvC;
            }
        }
        a0 += __shfl_xor(a0, 16); a0 += __shfl_xor(a0, 32);
        a1 += __shfl_xor(a1, 16); a1 += __shfl_xor(a1, 32);
        a2 += __shfl_xor(a2, 16); a2 += __shfl_xor(a2, 32);
        a3 += __shfl_xor(a3, 16); a3 += __shfl_xor(a3, 32);

        const uint2 xr = *(const uint2*)(xvu + (size_t)r * 64 + j * 4);
        const float o0 = __uint_as_float(xr.x << 16) + a0;
        const float o1 = __uint_as_float(xr.x & 0xffff0000u) + a1;
        const float o2 = __uint_as_float(xr.y << 16) + a2;
        const float o3 = __uint_as_float(xr.y & 0xffff0000u) + a3;

        float ssum = o0 + o1 + o2 + o3;
        ssum += __shfl_xor(ssum, 1); ssum += __shfl_xor(ssum, 2);
        ssum += __shfl_xor(ssum, 4); ssum += __shfl_xor(ssum, 8);
        const float mu = ssum * (1.f / 64.f);
        const float d0 = o0 - mu, d1 = o1 - mu, d2 = o2 - mu, d3 = o3 - mu;
        float vs = d0 * d0 + d1 * d1 + d2 * d2 + d3 * d3;
        vs += __shfl_xor(vs, 1); vs += __shfl_xor(vs, 2);
        vs += __shfl_xor(vs, 4); vs += __shfl_xor(vs, 8);
        const float rstd = rsqrtf(vs * (1.f / 64.f) + LN_EPS);

        const float dk = (sl == 0) ? d0 : (sl == 1) ? d1 : (sl == 2) ? d2 : d3;
        const float y = fmaf(dk * rstd, gg, bb);
        out[(size_t)r * 64 + lane] =
            y * __builtin_amdgcn_rcpf(1.f + __builtin_amdgcn_exp2f(-y * L2E));
    }
}

extern "C" void kernel_launch(void* const* d_in, const int* in_sizes, int n_in,
                              void* d_out, int out_size, void* d_ws, size_t ws_size,
                              hipStream_t stream) {
    const float* h      = (const float*)d_in[0];
    const float* dist   = (const float*)d_in[1];
    const int*   edges  = (const int*)d_in[2];
    const float* emask  = (const float*)d_in[4];
    const float* W_lin  = (const float*)d_in[5];
    const float* b_lin  = (const float*)d_in[6];
    const float* att_W1 = (const float*)d_in[7];
    const float* att_b1 = (const float*)d_in[8];
    const float* att_W2 = (const float*)d_in[9];
    const float* att_b2 = (const float*)d_in[10];
    const float* ln_g   = (const float*)d_in[11];
    const float* ln_b   = (const float*)d_in[12];
    float* out = (float*)d_out;

    char* ws = (char*)d_ws;
    unsigned short* xv   = (unsigned short*)ws;                  // 25,600,000
    unsigned short* u_bf = (unsigned short*)(ws + 25600000);     // 12,800,000
    uint2* srec          = (uint2*)(ws + 38400000);              //  8,028,160 (245*4096*8)
    unsigned short* ofsT = (unsigned short*)(ws + 46428160);     //    768,320 (245*1568*2)

    proj_scatter<<<SC_BLOCKS + PROJ_BLOCKS, 256, 0, stream>>>(
        h, b_lin, W_lin, att_W1, edges, dist, emask, srec, ofsT, xv, u_bf);
    agg_fused<<<N_BUCKETS, 256, 0, stream>>>(srec, ofsT, xv, u_bf,
                                             att_W1, att_b1, att_W2, att_b2,
                                             ln_g, ln_b, out);
}